// Round 8
// baseline (2269.374 us; speedup 1.0000x reference)
//
#include <hip/hip_runtime.h>
#include <hip/hip_bf16.h>

#define TPB 256

typedef __attribute__((ext_vector_type(8))) short short8;
typedef __attribute__((ext_vector_type(4))) float f32x4;

__device__ __forceinline__ unsigned short f2bf(float x) {
    union { float f; unsigned int u; } c; c.f = x;
    unsigned int u = c.u;
    unsigned int r = (u + 0x7fffu + ((u >> 16) & 1u)) >> 16;
    return (unsigned short)r;
}
__device__ __forceinline__ float bf2f(unsigned short h) {
    union { unsigned int u; float f; } c; c.u = ((unsigned int)h) << 16;
    return c.f;
}

// ======================= small prologue kernels ==============================

__global__ void conv1_k(const float* __restrict__ x, const float* __restrict__ w,
                        const float* __restrict__ b, float* __restrict__ out) {
    int idx = blockIdx.x * TPB + threadIdx.x;
    const int total = 512 * 64 * 26 * 26;
    if (idx >= total) return;
    int ox = idx % 26; int t = idx / 26;
    int oy = t % 26;   t /= 26;
    int co = t % 64;   int n = t / 64;
    const float* xp = x + (size_t)n * 784 + oy * 28 + ox;
    const float* wp = w + co * 9;
    float s = b[co];
#pragma unroll
    for (int ky = 0; ky < 3; ky++)
#pragma unroll
        for (int kx = 0; kx < 3; kx++)
            s += xp[ky * 28 + kx] * wp[ky * 3 + kx];
    out[idx] = s;
}

__global__ void gn_stats_k(const float* __restrict__ x, float* __restrict__ mean,
                           float* __restrict__ rstd, int N, int C, int HW, int G) {
    int gid  = (blockIdx.x * blockDim.x + threadIdx.x) >> 6;
    int lane = threadIdx.x & 63;
    int total = N * G;
    if (gid >= total) return;
    int n = gid / G, g = gid % G;
    int cpg = C / G;
    int gsize = cpg * HW;
    const float* p = x + ((size_t)n * C + (size_t)g * cpg) * HW;
    float s = 0.f, s2 = 0.f;
    for (int i = lane; i < gsize; i += 64) { float v = p[i]; s += v; s2 += v * v; }
#pragma unroll
    for (int off = 32; off; off >>= 1) {
        s  += __shfl_down(s,  off);
        s2 += __shfl_down(s2, off);
    }
    if (lane == 0) {
        float m = s / gsize;
        float var = s2 / gsize - m * m;
        mean[gid] = m;
        rstd[gid] = rsqrtf(var + 1e-5f);
    }
}

__global__ void gn_apply_relu_k(const float* __restrict__ x, float* __restrict__ out,
                                const float* __restrict__ mean, const float* __restrict__ rstd,
                                const float* __restrict__ gw, const float* __restrict__ gb,
                                int N, int C, int HW, int G) {
    int idx = blockIdx.x * TPB + threadIdx.x;
    int total = N * C * HW;
    if (idx >= total) return;
    int c = (idx / HW) % C;
    int n = idx / (HW * C);
    int cpg = C / G;
    int g = c / cpg;
    float m = mean[n * G + g], r = rstd[n * G + g];
    float v = (x[idx] - m) * r * gw[c] + gb[c];
    out[idx] = v > 0.f ? v : 0.f;
}

// prologue weight transpose: w[co][ci][3][3] -> wT[wave][ci][col16][12]
__global__ void wprep_k(const float* __restrict__ w, float* __restrict__ wT) {
    int i = blockIdx.x * TPB + threadIdx.x;
    if (i >= 64 * 64 * 12) return;
    int k = i % 12; int r = i / 12;
    int col = r % 16; r /= 16;
    int ci = r % 64; int wave = r / 64;
    int co = wave * 16 + col;
    wT[i] = (k < 9) ? w[(co * 64 + ci) * 9 + k] : 0.f;
}

// ODE weight split: w[co][ci][3][3] -> hi/lo bf16 B-frag tables
// layout [t:9][ks:2][nt:4][lane:64][8]: lane holds B[k=ks*32+(l>>4)*8+j][co=nt*16+(l&15)]
__global__ void wsplit_k(const float* __restrict__ w, unsigned short* __restrict__ hiT,
                         unsigned short* __restrict__ loT) {
    int i = blockIdx.x * TPB + threadIdx.x;
    if (i >= 9 * 2 * 4 * 64 * 8) return;
    int j = i & 7, l = (i >> 3) & 63, nt = (i >> 9) & 3, ks = (i >> 11) & 1, t = i >> 12;
    int co = nt * 16 + (l & 15);
    int ci = ks * 32 + (l >> 4) * 8 + j;
    float wv = w[(co * 64 + ci) * 9 + t];
    unsigned short hi = f2bf(wv);
    hiT[i] = hi;
    loT[i] = f2bf(wv - bf2f(hi));
}

// ======================= tiled 3x3 conv (prologue) ===========================

#define KC 2
#define WCHUNK (KC * 16 * 12)
#define WREGION (64 * 16 * 12)

template<int STRIDE, bool SKIP>
__global__ __launch_bounds__(256)
void conv_tile_k(const float* __restrict__ in, const float* __restrict__ wT,
                 const float* __restrict__ dw, const float* __restrict__ addend,
                 float* __restrict__ out, float* __restrict__ skipout,
                 int H, int W, int OH, int OW, int TX, int TY) {
    constexpr int IHT = 6 * STRIDE + 3;
    constexpr int IWT = 6 * STRIDE + 3;
    constexpr int IPITCH = (STRIDE == 1) ? 12 : 16;
    constexpr int RSPAN = 4 * STRIDE + 2;

    __shared__ float sin_[64 * IHT * IPITCH];
    __shared__ float wl[4 * WCHUNK];

    int b = blockIdx.x;
    int tx = b % TX; b /= TX;
    int ty = b % TY; int n = b / TY;
    int oy0 = ty * 7, ox0 = tx * 7;
    int iy0 = oy0 * STRIDE - 1, ix0 = ox0 * STRIDE - 1;

    const int t = threadIdx.x;
    const int wave = t >> 6, lane = t & 63;
    const int cb = t >> 4, cbl = cb & 3, slot = t & 15;
    const int row = slot >> 1, half = slot & 1;
    const int crow = (row < 7) ? row : 0;
    const int co0 = cb * 4;
    float* wlw = wl + wave * WCHUNK;

    const float* ip = in + (size_t)n * 64 * H * W;
    for (int i = t; i < 64 * IHT * IPITCH; i += 256) {
        int c = i % IPITCH; int r = (i / IPITCH) % IHT; int ch = i / (IPITCH * IHT);
        int gy = iy0 + r, gx = ix0 + c;
        float v = 0.f;
        if (c < IWT && (unsigned)gy < (unsigned)H && (unsigned)gx < (unsigned)W)
            v = ip[(size_t)ch * H * W + gy * W + gx];
        sin_[i] = v;
    }
    __syncthreads();

    const float* wg = wT + (size_t)wave * WREGION;
    float acc[4][4];
#pragma unroll
    for (int j = 0; j < 4; j++)
#pragma unroll
        for (int px = 0; px < 4; px++) acc[j][px] = 0.f;

    float2 s0, s1, s2v;
    {
        const float2* gp = (const float2*)wg + lane * 3;
        s0 = gp[0]; s1 = gp[1]; s2v = gp[2];
    }
    for (int ch = 0; ch < 64 / KC; ch++) {
        {
            float2* wp = (float2*)wlw + lane * 3;
            wp[0] = s0; wp[1] = s1; wp[2] = s2v;
        }
        if (ch < 64 / KC - 1) {
            const float2* gp = (const float2*)(wg + (ch + 1) * WCHUNK) + lane * 3;
            s0 = gp[0]; s1 = gp[1]; s2v = gp[2];
        }
        float wr[KC][4][9];
#pragma unroll
        for (int c2 = 0; c2 < KC; c2++)
#pragma unroll
            for (int j = 0; j < 4; j++) {
                const float* wp2 = wlw + (c2 * 16 + cbl * 4 + j) * 12;
                float4 wa = *(const float4*)wp2;
                float4 wb = *(const float4*)(wp2 + 4);
                wr[c2][j][0] = wa.x; wr[c2][j][1] = wa.y; wr[c2][j][2] = wa.z;
                wr[c2][j][3] = wa.w; wr[c2][j][4] = wb.x; wr[c2][j][5] = wb.y;
                wr[c2][j][6] = wb.z; wr[c2][j][7] = wb.w; wr[c2][j][8] = wp2[8];
            }
#pragma unroll
        for (int c2 = 0; c2 < KC; c2++) {
            const float* hc = sin_ + ((ch * KC + c2) * IHT + crow * STRIDE) * IPITCH
                            + half * 4 * STRIDE;
            float rr[3][RSPAN];
#pragma unroll
            for (int ky = 0; ky < 3; ky++) {
                const float* bp = hc + ky * IPITCH;
                if constexpr (STRIDE == 1) {
                    float4 a = *(const float4*)bp; float2 bb = *(const float2*)(bp + 4);
                    rr[ky][0] = a.x; rr[ky][1] = a.y; rr[ky][2] = a.z; rr[ky][3] = a.w;
                    rr[ky][4] = bb.x; rr[ky][5] = bb.y;
                } else {
                    float4 a = *(const float4*)bp; float4 bb = *(const float4*)(bp + 4);
                    float2 cc = *(const float2*)(bp + 8);
                    rr[ky][0] = a.x; rr[ky][1] = a.y; rr[ky][2] = a.z; rr[ky][3] = a.w;
                    rr[ky][4] = bb.x; rr[ky][5] = bb.y; rr[ky][6] = bb.z; rr[ky][7] = bb.w;
                    rr[ky][8] = cc.x; rr[ky][9] = cc.y;
                }
            }
#pragma unroll
            for (int j = 0; j < 4; j++)
#pragma unroll
                for (int px = 0; px < 4; px++) {
                    float s = acc[j][px];
#pragma unroll
                    for (int ky = 0; ky < 3; ky++) {
                        s = fmaf(rr[ky][px * STRIDE + 0], wr[c2][j][ky * 3 + 0], s);
                        s = fmaf(rr[ky][px * STRIDE + 1], wr[c2][j][ky * 3 + 1], s);
                        s = fmaf(rr[ky][px * STRIDE + 2], wr[c2][j][ky * 3 + 2], s);
                    }
                    acc[j][px] = s;
                }
        }
    }

    if constexpr (SKIP) {
        if (slot < 14) {
            float sk[4][4];
#pragma unroll
            for (int j = 0; j < 4; j++)
#pragma unroll
                for (int px = 0; px < 4; px++) sk[j][px] = 0.f;
            for (int ci = 0; ci < 64; ci++) {
                const float* sp = sin_ + (ci * IHT + 2 * row + 1) * IPITCH + half * 8 + 1;
                float xv[4];
#pragma unroll
                for (int px = 0; px < 4; px++) xv[px] = sp[px * 2];
#pragma unroll
                for (int j = 0; j < 4; j++) {
                    float wv = dw[(co0 + j) * 64 + ci];
#pragma unroll
                    for (int px = 0; px < 4; px++) sk[j][px] = fmaf(xv[px], wv, sk[j][px]);
                }
            }
#pragma unroll
            for (int j = 0; j < 4; j++)
#pragma unroll
                for (int px = 0; px < 4; px++) {
                    int oy = oy0 + row, ox = ox0 + half * 4 + px;
                    if (oy < OH && ox < OW && half * 4 + px < 7)
                        skipout[(((size_t)n * 64 + co0 + j) * OH + oy) * OW + ox] = sk[j][px];
                }
        }
    }

    if (slot < 14) {
#pragma unroll
        for (int j = 0; j < 4; j++)
#pragma unroll
            for (int px = 0; px < 4; px++) {
                int oy = oy0 + row, ox = ox0 + half * 4 + px;
                if (oy < OH && ox < OW && half * 4 + px < 7) {
                    size_t idx = (((size_t)n * 64 + co0 + j) * OH + oy) * OW + ox;
                    float v = acc[j][px];
                    if (addend) v += addend[idx];
                    out[idx] = v;
                }
            }
    }
}

// ======================= ODE MFMA mega-kernel ================================
// R8: REGISTER-RESIDENT ODE STATE. Each lane owns channel co = nt*16+(lane&15)
// at pixels p = m*16 + q*4 + j (the MFMA C/D layout), so z / z-accum / u live
// in 12 named f32x4 regs. GN1 is fully in-register (shfl_xor over q like GN2).
// LDS = hp1/hp2 activation planes only (23.9 KB) -> 4 blocks/CU at VGPR<=128
// (__launch_bounds__(256,4)). 2 barriers/eval (hp1, hp2 are the only
// cross-wave flows). Invalid pixel slots read the zeroed sentinel row so the
// epilogue needs no masking (k=0 there).

#define HP_PITCH 72          // ushorts per pixel-slot (144 B)

// one tap-GEMM pair (hi+lo) for one m-tile accumulator
#define CONV_TAP(areg, hbase)                                                   \
    {                                                                           \
        int hr_ = min((hbase) + toff, 81);                                      \
        short8 a_ = *(const short8*)(hp + hr_ * HP_PITCH + kq);                 \
        areg = __builtin_amdgcn_mfma_f32_16x16x32_bf16(a_, vbh, areg, 0, 0, 0); \
        areg = __builtin_amdgcn_mfma_f32_16x16x32_bf16(a_, vbl, areg, 0, 0, 0); \
    }

// full 3x3x64->16co conv for this wave: leaves results in a0..a3
#define CONV_MFMA(hpsrc, bhT, blT)                                              \
    a0 = (f32x4){0.f, 0.f, 0.f, 0.f}; a1 = a0; a2 = a0; a3 = a0;                \
    {                                                                           \
        const unsigned short* hp = (hpsrc);                                     \
        const short8* bh_ = (const short8*)(bhT);                               \
        const short8* bl_ = (const short8*)(blT);                               \
        _Pragma("unroll")                                                       \
        for (int t9 = 0; t9 < 9; t9++) {                                        \
            const int toff = (t9 / 3) * 9 + (t9 % 3) - 10;                      \
            _Pragma("unroll")                                                   \
            for (int ks = 0; ks < 2; ks++) {                                    \
                int fidx = ((t9 * 2 + ks) * 4 + nt) * 64 + lane;                \
                short8 vbh = bh_[fidx];                                         \
                short8 vbl = bl_[fidx];                                         \
                int kq = ks * 32 + kq0;                                         \
                CONV_TAP(a0, h0)                                                \
                CONV_TAP(a1, h1)                                                \
                CONV_TAP(a2, h2)                                                \
                CONV_TAP(a3, h3)                                                \
            }                                                                   \
        }                                                                       \
    }

// masked GN stat accumulation over one m-tile f32x4 (pixels p = mm*16+q*4+j)
#define GN_ACCUM(areg, mm)                                                      \
    _Pragma("unroll")                                                           \
    for (int j = 0; j < 4; j++) {                                               \
        int p_ = (mm) * 16 + q * 4 + j;                                         \
        if (p_ < 49) { float x_ = areg[j]; s += x_; s2 += x_ * x_; }            \
    }

// masked GN apply+ReLU+bf16-store to an hp plane
#define GN_STORE(dst, areg, mm)                                                 \
    _Pragma("unroll")                                                           \
    for (int j = 0; j < 4; j++) {                                               \
        int p_ = (mm) * 16 + q * 4 + j;                                         \
        if (p_ < 49) {                                                          \
            float y_ = fmaxf(areg[j] * sc + sh, 0.f);                           \
            int hr_ = (p_ / 7 + 1) * 9 + (p_ % 7) + 1;                          \
            (dst)[hr_ * HP_PITCH + co] = f2bf(y_);                              \
        }                                                                       \
    }

// RK4 update for one m-tile: k = a + u;  za (+)= ck*k;  u = z + cu*k (e<3)
#define RK4_REG(areg, zm, zam, um)                                              \
    {                                                                           \
        f32x4 kv = areg + um;                                                   \
        zam = (e == 0) ? (zm + ck * kv) : (zam + ck * kv);                      \
        if (e < 3) um = zm + cu * kv;                                           \
    }

__global__ __launch_bounds__(256, 4)
void ode_mfma_k(const float* __restrict__ z0g,
                const unsigned short* __restrict__ wb1h, const unsigned short* __restrict__ wb1l,
                const unsigned short* __restrict__ wb2h, const unsigned short* __restrict__ wb2l,
                const float* __restrict__ g1w, const float* __restrict__ g1b,
                const float* __restrict__ g2w, const float* __restrict__ g2b,
                const float* __restrict__ fgw, const float* __restrict__ fgb,
                const float* __restrict__ fcw, const float* __restrict__ fcb,
                float* __restrict__ out) {
    __shared__ unsigned short hp1[82 * HP_PITCH], hp2[82 * HP_PITCH];
    __shared__ float pooled[64];

    const int t = threadIdx.x;
    const int n = blockIdx.x;
    const int lane = t & 63;
    const int nt = t >> 6;                 // wave = N-tile
    const int colL = lane & 15, q = lane >> 4;
    const int co = nt * 16 + colL;

    const float g1wv = g1w[co], g1bv = g1b[co];
    const float g2wv = g2w[co], g2bv = g2b[co];

    // A-fragment row bases: pixel pA = m*16 + colL (sentinel 1000 -> row 81)
    const int pA0 = colL,      h0 = (pA0 < 49) ? ((pA0 / 7 + 1) * 9 + (pA0 % 7) + 1) : 1000;
    const int pA1 = 16 + colL, h1 = (pA1 < 49) ? ((pA1 / 7 + 1) * 9 + (pA1 % 7) + 1) : 1000;
    const int pA2 = 32 + colL, h2 = (pA2 < 49) ? ((pA2 / 7 + 1) * 9 + (pA2 % 7) + 1) : 1000;
    const int pA3 = 48 + colL, h3 = (pA3 < 49) ? ((pA3 / 7 + 1) * 9 + (pA3 % 7) + 1) : 1000;
    const int kq0 = q * 8;

    // ---- init LDS planes (halo + sentinel row stay 0 forever) ----
    for (int i = t; i < 82 * HP_PITCH; i += 256) { hp1[i] = 0; hp2[i] = 0; }

    // ---- load state into registers: z[m][j] = z0[co][m*16+q*4+j] ----
    f32x4 zr0, zr1, zr2, zr3;          // z_n
    f32x4 za0, za1, za2, za3;          // accumulating z_{n+1}
    f32x4 ur0, ur1, ur2, ur3;          // current eval input (u); ur==zr at e=0
    {
        const float* zb = z0g + (size_t)n * 3136 + co * 49;
#define LOADZ(zm, mm)                                                           \
        _Pragma("unroll")                                                       \
        for (int j = 0; j < 4; j++) {                                           \
            int p_ = (mm) * 16 + q * 4 + j;                                     \
            zm[j] = (p_ < 49) ? zb[p_] : 0.f;                                   \
        }
        LOADZ(zr0, 0) LOADZ(zr1, 1) LOADZ(zr2, 2) LOADZ(zr3, 3)
#undef LOADZ
    }
    ur0 = zr0; ur1 = zr1; ur2 = zr2; ur3 = zr3;
    __syncthreads();

    const float dt = 0.5f;

#pragma unroll 1
    for (int step = 0; step < 12; step++) {
#pragma unroll 1
        for (int e = 0; e < 4; e++) {
            const float ck = (e == 0 || e == 3) ? dt / 6.f : dt / 3.f;
            const float cu = (e == 2) ? dt : 0.5f * dt;

            // ---- GN1(groups=64)+ReLU on u (registers) -> hp1 ----
            {
                float s = 0.f, s2 = 0.f;
                GN_ACCUM(ur0, 0) GN_ACCUM(ur1, 1) GN_ACCUM(ur2, 2) GN_ACCUM(ur3, 3)
                s += __shfl_xor(s, 16); s2 += __shfl_xor(s2, 16);
                s += __shfl_xor(s, 32); s2 += __shfl_xor(s2, 32);
                float mu = s * (1.f / 49.f);
                float r = rsqrtf(s2 * (1.f / 49.f) - mu * mu + 1e-5f);
                float sc = r * g1wv, sh = g1bv - mu * sc;
                GN_STORE(hp1, ur0, 0) GN_STORE(hp1, ur1, 1)
                GN_STORE(hp1, ur2, 2) GN_STORE(hp1, ur3, 3)
            }
            __syncthreads();   // B1: hp1 complete

            // ---- conv1 + in-register GN2(groups=64)+ReLU -> hp2 ----
            {
                f32x4 a0, a1, a2, a3;
                CONV_MFMA(hp1, wb1h, wb1l)

                float s = 0.f, s2 = 0.f;
                GN_ACCUM(a0, 0) GN_ACCUM(a1, 1) GN_ACCUM(a2, 2) GN_ACCUM(a3, 3)
                s += __shfl_xor(s, 16); s2 += __shfl_xor(s2, 16);
                s += __shfl_xor(s, 32); s2 += __shfl_xor(s2, 32);
                float mu = s * (1.f / 49.f);
                float r = rsqrtf(s2 * (1.f / 49.f) - mu * mu + 1e-5f);
                float sc = r * g2wv, sh = g2bv - mu * sc;
                GN_STORE(hp2, a0, 0) GN_STORE(hp2, a1, 1)
                GN_STORE(hp2, a2, 2) GN_STORE(hp2, a3, 3)
            }
            __syncthreads();   // B2: hp2 complete (also: all hp1 reads done)

            // ---- conv2 + RK4 epilogue (all registers) ----
            {
                f32x4 a0, a1, a2, a3;
                CONV_MFMA(hp2, wb2h, wb2l)

                RK4_REG(a0, zr0, za0, ur0) RK4_REG(a1, zr1, za1, ur1)
                RK4_REG(a2, zr2, za2, ur2) RK4_REG(a3, zr3, za3, ur3)
                if (e == 3) {
                    zr0 = za0; zr1 = za1; zr2 = za2; zr3 = za3;
                    ur0 = zr0; ur1 = zr1; ur2 = zr2; ur3 = zr3;
                }
            }
            // no barrier needed: next GN1 writes hp1, whose readers finished
            // before B2; state flow is wave-private (registers).
        }
    }

    // ---- final GN(groups=32)+ReLU + mean-pool (registers) ----
    {
        float s = 0.f, s2 = 0.f;
        GN_ACCUM(zr0, 0) GN_ACCUM(zr1, 1) GN_ACCUM(zr2, 2) GN_ACCUM(zr3, 3)
        s += __shfl_xor(s, 16); s2 += __shfl_xor(s2, 16);
        s += __shfl_xor(s, 32); s2 += __shfl_xor(s2, 32);
        s += __shfl_xor(s, 1);  s2 += __shfl_xor(s2, 1);   // pair channels (G=32)
        float mu = s * (1.f / 98.f);
        float r = rsqrtf(s2 * (1.f / 98.f) - mu * mu + 1e-5f);
        float sc = r * fgw[co], sh = fgb[co] - mu * sc;
        float ps = 0.f;
#pragma unroll
        for (int mm = 0; mm < 4; mm++) {
            f32x4 zz = (mm == 0) ? zr0 : (mm == 1) ? zr1 : (mm == 2) ? zr2 : zr3;
#pragma unroll
            for (int j = 0; j < 4; j++) {
                int p_ = mm * 16 + q * 4 + j;
                if (p_ < 49) ps += fmaxf(zz[j] * sc + sh, 0.f);
            }
        }
        ps += __shfl_xor(ps, 16);
        ps += __shfl_xor(ps, 32);
        if (q == 0) pooled[co] = ps * (1.f / 49.f);
    }
    __syncthreads();
    if (t < 10) {
        float a = fcb[t];
#pragma unroll
        for (int k = 0; k < 64; k++) a += pooled[k] * fcw[t * 64 + k];
        out[(size_t)n * 10 + t] = a;
    }
}

static inline int nblk(long long total) { return (int)((total + TPB - 1) / TPB); }

extern "C" void kernel_launch(void* const* d_in, const int* in_sizes, int n_in,
                              void* d_out, int out_size, void* d_ws, size_t ws_size,
                              hipStream_t stream) {
    const float* x       = (const float*)d_in[0];
    const float* conv1_w = (const float*)d_in[1];
    const float* conv1_b = (const float*)d_in[2];
    const float* r1_g1w  = (const float*)d_in[3];
    const float* r1_g1b  = (const float*)d_in[4];
    const float* r1_c1w  = (const float*)d_in[5];
    const float* r1_g2w  = (const float*)d_in[6];
    const float* r1_g2b  = (const float*)d_in[7];
    const float* r1_c2w  = (const float*)d_in[8];
    const float* r1_dw   = (const float*)d_in[9];
    const float* r2_g1w  = (const float*)d_in[10];
    const float* r2_g1b  = (const float*)d_in[11];
    const float* r2_c1w  = (const float*)d_in[12];
    const float* r2_g2w  = (const float*)d_in[13];
    const float* r2_g2b  = (const float*)d_in[14];
    const float* r2_c2w  = (const float*)d_in[15];
    const float* r2_dw   = (const float*)d_in[16];
    const float* o_g1w   = (const float*)d_in[17];
    const float* o_g1b   = (const float*)d_in[18];
    const float* o_c1w   = (const float*)d_in[19];
    const float* o_g2w   = (const float*)d_in[20];
    const float* o_g2b   = (const float*)d_in[21];
    const float* o_c2w   = (const float*)d_in[22];
    const float* fin_gw  = (const float*)d_in[23];
    const float* fin_gb  = (const float*)d_in[24];
    const float* fc_w    = (const float*)d_in[25];
    const float* fc_b    = (const float*)d_in[26];
    float* out = (float*)d_out;

    const int N = 512;
    const long long SZ26 = 512LL * 64 * 26 * 26;
    const long long SZ13 = 512LL * 64 * 13 * 13;
    const long long SZ7  = 512LL * 64 * 7 * 7;
    const long long WTS  = 64 * 64 * 12;
    const long long WBS  = 9 * 2 * 4 * 64 * 8;     // 36864 ushorts per table

    float* B26   = (float*)d_ws;
    float* A13   = B26 + SZ26;
    float* B13   = A13 + SZ13;
    float* Z7    = B13 + SZ13;
    float* U7    = Z7 + SZ7;
    float* MEAN  = U7 + SZ7;
    float* RSTD  = MEAN + 512 * 64;
    float* WTr11 = RSTD + 512 * 64;
    float* WTr12 = WTr11 + WTS;
    float* WTr21 = WTr12 + WTS;
    float* WTr22 = WTr21 + WTS;
    unsigned short* WB1h = (unsigned short*)(WTr22 + WTS);
    unsigned short* WB1l = WB1h + WBS;
    unsigned short* WB2h = WB1l + WBS;
    unsigned short* WB2l = WB2h + WBS;

    auto gn = [&](const float* src, float* dst, int HW, int G,
                  const float* gw, const float* gb) {
        int waves = N * G;
        gn_stats_k<<<nblk((long long)waves * 64), TPB, 0, stream>>>(src, MEAN, RSTD, N, 64, HW, G);
        gn_apply_relu_k<<<nblk((long long)N * 64 * HW), TPB, 0, stream>>>(
            src, dst, MEAN, RSTD, gw, gb, N, 64, HW, G);
    };

    // ---- weight prep ----
    wprep_k<<<nblk(WTS), TPB, 0, stream>>>(r1_c1w, WTr11);
    wprep_k<<<nblk(WTS), TPB, 0, stream>>>(r1_c2w, WTr12);
    wprep_k<<<nblk(WTS), TPB, 0, stream>>>(r2_c1w, WTr21);
    wprep_k<<<nblk(WTS), TPB, 0, stream>>>(r2_c2w, WTr22);
    wsplit_k<<<nblk(WBS), TPB, 0, stream>>>(o_c1w, WB1h, WB1l);
    wsplit_k<<<nblk(WBS), TPB, 0, stream>>>(o_c2w, WB2h, WB2l);

    // ---- stage 0: conv1 ----
    conv1_k<<<nblk(SZ26), TPB, 0, stream>>>(x, conv1_w, conv1_b, B26);

    // ---- residual block 1: 26x26 -> 13x13 ----
    gn(B26, B26, 676, 32, r1_g1w, r1_g1b);
    conv_tile_k<2, true><<<512 * 4, 256, 0, stream>>>(B26, WTr11, r1_dw, nullptr,
                                                      A13, B13, 26, 26, 13, 13, 2, 2);
    gn(A13, A13, 169, 32, r1_g2w, r1_g2b);
    conv_tile_k<1, false><<<512 * 4, 256, 0, stream>>>(A13, WTr12, nullptr, B13,
                                                       B13, nullptr, 13, 13, 13, 13, 2, 2);

    // ---- residual block 2: 13x13 -> 7x7 ----
    gn(B13, B13, 169, 32, r2_g1w, r2_g1b);
    conv_tile_k<2, true><<<512, 256, 0, stream>>>(B13, WTr21, r2_dw, nullptr,
                                                  U7, Z7, 13, 13, 7, 7, 1, 1);
    gn(U7, U7, 49, 32, r2_g2w, r2_g2b);
    conv_tile_k<1, false><<<512, 256, 0, stream>>>(U7, WTr22, nullptr, Z7,
                                                   Z7, nullptr, 7, 7, 7, 7, 1, 1);

    // ---- fused MFMA ODE (12 RK4 steps) + final GN + pool + FC ----
    ode_mfma_k<<<512, 256, 0, stream>>>(Z7, WB1h, WB1l, WB2h, WB2l,
                                        o_g1w, o_g1b, o_g2w, o_g2b,
                                        fin_gw, fin_gb, fc_w, fc_b, out);
}

// Round 9
// 1957.186 us; speedup vs baseline: 1.1595x; 1.1595x over previous
//
#include <hip/hip_runtime.h>
#include <hip/hip_bf16.h>

#define TPB 256

typedef __attribute__((ext_vector_type(8))) short short8;
typedef __attribute__((ext_vector_type(4))) float f32x4;

__device__ __forceinline__ unsigned short f2bf(float x) {
    union { float f; unsigned int u; } c; c.f = x;
    unsigned int u = c.u;
    unsigned int r = (u + 0x7fffu + ((u >> 16) & 1u)) >> 16;
    return (unsigned short)r;
}
__device__ __forceinline__ float bf2f(unsigned short h) {
    union { unsigned int u; float f; } c; c.u = ((unsigned int)h) << 16;
    return c.f;
}

// ======================= small prologue kernels ==============================

__global__ void conv1_k(const float* __restrict__ x, const float* __restrict__ w,
                        const float* __restrict__ b, float* __restrict__ out) {
    int idx = blockIdx.x * TPB + threadIdx.x;
    const int total = 512 * 64 * 26 * 26;
    if (idx >= total) return;
    int ox = idx % 26; int t = idx / 26;
    int oy = t % 26;   t /= 26;
    int co = t % 64;   int n = t / 64;
    const float* xp = x + (size_t)n * 784 + oy * 28 + ox;
    const float* wp = w + co * 9;
    float s = b[co];
#pragma unroll
    for (int ky = 0; ky < 3; ky++)
#pragma unroll
        for (int kx = 0; kx < 3; kx++)
            s += xp[ky * 28 + kx] * wp[ky * 3 + kx];
    out[idx] = s;
}

__global__ void gn_stats_k(const float* __restrict__ x, float* __restrict__ mean,
                           float* __restrict__ rstd, int N, int C, int HW, int G) {
    int gid  = (blockIdx.x * blockDim.x + threadIdx.x) >> 6;
    int lane = threadIdx.x & 63;
    int total = N * G;
    if (gid >= total) return;
    int n = gid / G, g = gid % G;
    int cpg = C / G;
    int gsize = cpg * HW;
    const float* p = x + ((size_t)n * C + (size_t)g * cpg) * HW;
    float s = 0.f, s2 = 0.f;
    for (int i = lane; i < gsize; i += 64) { float v = p[i]; s += v; s2 += v * v; }
#pragma unroll
    for (int off = 32; off; off >>= 1) {
        s  += __shfl_down(s,  off);
        s2 += __shfl_down(s2, off);
    }
    if (lane == 0) {
        float m = s / gsize;
        float var = s2 / gsize - m * m;
        mean[gid] = m;
        rstd[gid] = rsqrtf(var + 1e-5f);
    }
}

__global__ void gn_apply_relu_k(const float* __restrict__ x, float* __restrict__ out,
                                const float* __restrict__ mean, const float* __restrict__ rstd,
                                const float* __restrict__ gw, const float* __restrict__ gb,
                                int N, int C, int HW, int G) {
    int idx = blockIdx.x * TPB + threadIdx.x;
    int total = N * C * HW;
    if (idx >= total) return;
    int c = (idx / HW) % C;
    int n = idx / (HW * C);
    int cpg = C / G;
    int g = c / cpg;
    float m = mean[n * G + g], r = rstd[n * G + g];
    float v = (x[idx] - m) * r * gw[c] + gb[c];
    out[idx] = v > 0.f ? v : 0.f;
}

// prologue weight transpose: w[co][ci][3][3] -> wT[wave][ci][col16][12]
__global__ void wprep_k(const float* __restrict__ w, float* __restrict__ wT) {
    int i = blockIdx.x * TPB + threadIdx.x;
    if (i >= 64 * 64 * 12) return;
    int k = i % 12; int r = i / 12;
    int col = r % 16; r /= 16;
    int ci = r % 64; int wave = r / 64;
    int co = wave * 16 + col;
    wT[i] = (k < 9) ? w[(co * 64 + ci) * 9 + k] : 0.f;
}

// ODE weight split: w[co][ci][3][3] -> hi/lo bf16 B-frag tables
// layout [t:9][ks:2][nt:4][lane:64][8]: lane holds B[k=ks*32+(l>>4)*8+j][co=nt*16+(l&15)]
__global__ void wsplit_k(const float* __restrict__ w, unsigned short* __restrict__ hiT,
                         unsigned short* __restrict__ loT) {
    int i = blockIdx.x * TPB + threadIdx.x;
    if (i >= 9 * 2 * 4 * 64 * 8) return;
    int j = i & 7, l = (i >> 3) & 63, nt = (i >> 9) & 3, ks = (i >> 11) & 1, t = i >> 12;
    int co = nt * 16 + (l & 15);
    int ci = ks * 32 + (l >> 4) * 8 + j;
    float wv = w[(co * 64 + ci) * 9 + t];
    unsigned short hi = f2bf(wv);
    hiT[i] = hi;
    loT[i] = f2bf(wv - bf2f(hi));
}

// ======================= tiled 3x3 conv (prologue) ===========================

#define KC 2
#define WCHUNK (KC * 16 * 12)
#define WREGION (64 * 16 * 12)

template<int STRIDE, bool SKIP>
__global__ __launch_bounds__(256)
void conv_tile_k(const float* __restrict__ in, const float* __restrict__ wT,
                 const float* __restrict__ dw, const float* __restrict__ addend,
                 float* __restrict__ out, float* __restrict__ skipout,
                 int H, int W, int OH, int OW, int TX, int TY) {
    constexpr int IHT = 6 * STRIDE + 3;
    constexpr int IWT = 6 * STRIDE + 3;
    constexpr int IPITCH = (STRIDE == 1) ? 12 : 16;
    constexpr int RSPAN = 4 * STRIDE + 2;

    __shared__ float sin_[64 * IHT * IPITCH];
    __shared__ float wl[4 * WCHUNK];

    int b = blockIdx.x;
    int tx = b % TX; b /= TX;
    int ty = b % TY; int n = b / TY;
    int oy0 = ty * 7, ox0 = tx * 7;
    int iy0 = oy0 * STRIDE - 1, ix0 = ox0 * STRIDE - 1;

    const int t = threadIdx.x;
    const int wave = t >> 6, lane = t & 63;
    const int cb = t >> 4, cbl = cb & 3, slot = t & 15;
    const int row = slot >> 1, half = slot & 1;
    const int crow = (row < 7) ? row : 0;
    const int co0 = cb * 4;
    float* wlw = wl + wave * WCHUNK;

    const float* ip = in + (size_t)n * 64 * H * W;
    for (int i = t; i < 64 * IHT * IPITCH; i += 256) {
        int c = i % IPITCH; int r = (i / IPITCH) % IHT; int ch = i / (IPITCH * IHT);
        int gy = iy0 + r, gx = ix0 + c;
        float v = 0.f;
        if (c < IWT && (unsigned)gy < (unsigned)H && (unsigned)gx < (unsigned)W)
            v = ip[(size_t)ch * H * W + gy * W + gx];
        sin_[i] = v;
    }
    __syncthreads();

    const float* wg = wT + (size_t)wave * WREGION;
    float acc[4][4];
#pragma unroll
    for (int j = 0; j < 4; j++)
#pragma unroll
        for (int px = 0; px < 4; px++) acc[j][px] = 0.f;

    float2 s0, s1, s2v;
    {
        const float2* gp = (const float2*)wg + lane * 3;
        s0 = gp[0]; s1 = gp[1]; s2v = gp[2];
    }
    for (int ch = 0; ch < 64 / KC; ch++) {
        {
            float2* wp = (float2*)wlw + lane * 3;
            wp[0] = s0; wp[1] = s1; wp[2] = s2v;
        }
        if (ch < 64 / KC - 1) {
            const float2* gp = (const float2*)(wg + (ch + 1) * WCHUNK) + lane * 3;
            s0 = gp[0]; s1 = gp[1]; s2v = gp[2];
        }
        float wr[KC][4][9];
#pragma unroll
        for (int c2 = 0; c2 < KC; c2++)
#pragma unroll
            for (int j = 0; j < 4; j++) {
                const float* wp2 = wlw + (c2 * 16 + cbl * 4 + j) * 12;
                float4 wa = *(const float4*)wp2;
                float4 wb = *(const float4*)(wp2 + 4);
                wr[c2][j][0] = wa.x; wr[c2][j][1] = wa.y; wr[c2][j][2] = wa.z;
                wr[c2][j][3] = wa.w; wr[c2][j][4] = wb.x; wr[c2][j][5] = wb.y;
                wr[c2][j][6] = wb.z; wr[c2][j][7] = wb.w; wr[c2][j][8] = wp2[8];
            }
#pragma unroll
        for (int c2 = 0; c2 < KC; c2++) {
            const float* hc = sin_ + ((ch * KC + c2) * IHT + crow * STRIDE) * IPITCH
                            + half * 4 * STRIDE;
            float rr[3][RSPAN];
#pragma unroll
            for (int ky = 0; ky < 3; ky++) {
                const float* bp = hc + ky * IPITCH;
                if constexpr (STRIDE == 1) {
                    float4 a = *(const float4*)bp; float2 bb = *(const float2*)(bp + 4);
                    rr[ky][0] = a.x; rr[ky][1] = a.y; rr[ky][2] = a.z; rr[ky][3] = a.w;
                    rr[ky][4] = bb.x; rr[ky][5] = bb.y;
                } else {
                    float4 a = *(const float4*)bp; float4 bb = *(const float4*)(bp + 4);
                    float2 cc = *(const float2*)(bp + 8);
                    rr[ky][0] = a.x; rr[ky][1] = a.y; rr[ky][2] = a.z; rr[ky][3] = a.w;
                    rr[ky][4] = bb.x; rr[ky][5] = bb.y; rr[ky][6] = bb.z; rr[ky][7] = bb.w;
                    rr[ky][8] = cc.x; rr[ky][9] = cc.y;
                }
            }
#pragma unroll
            for (int j = 0; j < 4; j++)
#pragma unroll
                for (int px = 0; px < 4; px++) {
                    float s = acc[j][px];
#pragma unroll
                    for (int ky = 0; ky < 3; ky++) {
                        s = fmaf(rr[ky][px * STRIDE + 0], wr[c2][j][ky * 3 + 0], s);
                        s = fmaf(rr[ky][px * STRIDE + 1], wr[c2][j][ky * 3 + 1], s);
                        s = fmaf(rr[ky][px * STRIDE + 2], wr[c2][j][ky * 3 + 2], s);
                    }
                    acc[j][px] = s;
                }
        }
    }

    if constexpr (SKIP) {
        if (slot < 14) {
            float sk[4][4];
#pragma unroll
            for (int j = 0; j < 4; j++)
#pragma unroll
                for (int px = 0; px < 4; px++) sk[j][px] = 0.f;
            for (int ci = 0; ci < 64; ci++) {
                const float* sp = sin_ + (ci * IHT + 2 * row + 1) * IPITCH + half * 8 + 1;
                float xv[4];
#pragma unroll
                for (int px = 0; px < 4; px++) xv[px] = sp[px * 2];
#pragma unroll
                for (int j = 0; j < 4; j++) {
                    float wv = dw[(co0 + j) * 64 + ci];
#pragma unroll
                    for (int px = 0; px < 4; px++) sk[j][px] = fmaf(xv[px], wv, sk[j][px]);
                }
            }
#pragma unroll
            for (int j = 0; j < 4; j++)
#pragma unroll
                for (int px = 0; px < 4; px++) {
                    int oy = oy0 + row, ox = ox0 + half * 4 + px;
                    if (oy < OH && ox < OW && half * 4 + px < 7)
                        skipout[(((size_t)n * 64 + co0 + j) * OH + oy) * OW + ox] = sk[j][px];
                }
        }
    }

    if (slot < 14) {
#pragma unroll
        for (int j = 0; j < 4; j++)
#pragma unroll
            for (int px = 0; px < 4; px++) {
                int oy = oy0 + row, ox = ox0 + half * 4 + px;
                if (oy < OH && ox < OW && half * 4 + px < 7) {
                    size_t idx = (((size_t)n * 64 + co0 + j) * OH + oy) * OW + ox;
                    float v = acc[j][px];
                    if (addend) v += addend[idx];
                    out[idx] = v;
                }
            }
    }
}

// ======================= ODE MFMA mega-kernel ================================
// R9: TWO IMAGES PER BLOCK. 512 threads = 8 waves; waves 0-3 -> image A,
// waves 4-7 -> image B (same nt per pair). Same-nt wave pairs read IDENTICAL
// weight addresses in lockstep -> L1/L2 reuse; block-level weight request
// volume halves. VGPR cap relaxed to 256 (__launch_bounds__(512,2)) so the
// compiler can pipeline the 144 weight loads per conv (R8's 64-VGPR cap
// strangled this). State stays register-resident per R8.

#define HP_PITCH 72          // ushorts per pixel-slot (144 B)
#define HP_PLANE (82 * HP_PITCH)

// one tap-GEMM pair (hi+lo) for one m-tile accumulator
#define CONV_TAP(areg, hbase)                                                   \
    {                                                                           \
        int hr_ = min((hbase) + toff, 81);                                      \
        short8 a_ = *(const short8*)(hp + hr_ * HP_PITCH + kq);                 \
        areg = __builtin_amdgcn_mfma_f32_16x16x32_bf16(a_, vbh, areg, 0, 0, 0); \
        areg = __builtin_amdgcn_mfma_f32_16x16x32_bf16(a_, vbl, areg, 0, 0, 0); \
    }

// full 3x3x64->16co conv for this wave: leaves results in a0..a3
#define CONV_MFMA(hpsrc, bhT, blT)                                              \
    a0 = (f32x4){0.f, 0.f, 0.f, 0.f}; a1 = a0; a2 = a0; a3 = a0;                \
    {                                                                           \
        const unsigned short* hp = (hpsrc);                                     \
        const short8* bh_ = (const short8*)(bhT);                               \
        const short8* bl_ = (const short8*)(blT);                               \
        _Pragma("unroll")                                                       \
        for (int t9 = 0; t9 < 9; t9++) {                                        \
            const int toff = (t9 / 3) * 9 + (t9 % 3) - 10;                      \
            _Pragma("unroll")                                                   \
            for (int ks = 0; ks < 2; ks++) {                                    \
                int fidx = ((t9 * 2 + ks) * 4 + nt) * 64 + lane;                \
                short8 vbh = bh_[fidx];                                         \
                short8 vbl = bl_[fidx];                                         \
                int kq = ks * 32 + kq0;                                         \
                CONV_TAP(a0, h0)                                                \
                CONV_TAP(a1, h1)                                                \
                CONV_TAP(a2, h2)                                                \
                CONV_TAP(a3, h3)                                                \
            }                                                                   \
        }                                                                       \
    }

// masked GN stat accumulation over one m-tile f32x4 (pixels p = mm*16+q*4+j)
#define GN_ACCUM(areg, mm)                                                      \
    _Pragma("unroll")                                                           \
    for (int j = 0; j < 4; j++) {                                               \
        int p_ = (mm) * 16 + q * 4 + j;                                         \
        if (p_ < 49) { float x_ = areg[j]; s += x_; s2 += x_ * x_; }            \
    }

// masked GN apply+ReLU+bf16-store to an hp plane
#define GN_STORE(dst, areg, mm)                                                 \
    _Pragma("unroll")                                                           \
    for (int j = 0; j < 4; j++) {                                               \
        int p_ = (mm) * 16 + q * 4 + j;                                         \
        if (p_ < 49) {                                                          \
            float y_ = fmaxf(areg[j] * sc + sh, 0.f);                           \
            int hr_ = (p_ / 7 + 1) * 9 + (p_ % 7) + 1;                          \
            (dst)[hr_ * HP_PITCH + co] = f2bf(y_);                              \
        }                                                                       \
    }

// RK4 update for one m-tile: k = a + u;  za (+)= ck*k;  u = z + cu*k (e<3)
#define RK4_REG(areg, zm, zam, um)                                              \
    {                                                                           \
        f32x4 kv = areg + um;                                                   \
        zam = (e == 0) ? (zm + ck * kv) : (zam + ck * kv);                      \
        if (e < 3) um = zm + cu * kv;                                           \
    }

__global__ __launch_bounds__(512, 2)
void ode_mfma_k(const float* __restrict__ z0g,
                const unsigned short* __restrict__ wb1h, const unsigned short* __restrict__ wb1l,
                const unsigned short* __restrict__ wb2h, const unsigned short* __restrict__ wb2l,
                const float* __restrict__ g1w, const float* __restrict__ g1b,
                const float* __restrict__ g2w, const float* __restrict__ g2b,
                const float* __restrict__ fgw, const float* __restrict__ fgb,
                const float* __restrict__ fcw, const float* __restrict__ fcb,
                float* __restrict__ out) {
    __shared__ unsigned short hp1[2][HP_PLANE], hp2[2][HP_PLANE];
    __shared__ float pooled[2][64];

    const int t = threadIdx.x;
    const int iw = t >> 8;                 // image within block (0/1)
    const int lane = t & 63;
    const int nt = (t >> 6) & 3;           // n-tile within image
    const int colL = lane & 15, q = lane >> 4;
    const int co = nt * 16 + colL;
    const int n = blockIdx.x * 2 + iw;

    unsigned short* hp1p = hp1[iw];
    unsigned short* hp2p = hp2[iw];

    const float g1wv = g1w[co], g1bv = g1b[co];
    const float g2wv = g2w[co], g2bv = g2b[co];

    // A-fragment row bases: pixel pA = m*16 + colL (sentinel 1000 -> row 81)
    const int pA0 = colL,      h0 = (pA0 < 49) ? ((pA0 / 7 + 1) * 9 + (pA0 % 7) + 1) : 1000;
    const int pA1 = 16 + colL, h1 = (pA1 < 49) ? ((pA1 / 7 + 1) * 9 + (pA1 % 7) + 1) : 1000;
    const int pA2 = 32 + colL, h2 = (pA2 < 49) ? ((pA2 / 7 + 1) * 9 + (pA2 % 7) + 1) : 1000;
    const int pA3 = 48 + colL, h3 = (pA3 < 49) ? ((pA3 / 7 + 1) * 9 + (pA3 % 7) + 1) : 1000;
    const int kq0 = q * 8;

    // ---- init LDS planes (halo + sentinel row stay 0 forever) ----
    for (int i = t; i < 2 * HP_PLANE; i += 512) {
        ((unsigned short*)hp1)[i] = 0;
        ((unsigned short*)hp2)[i] = 0;
    }

    // ---- load state into registers: z[m][j] = z0[co][m*16+q*4+j] ----
    f32x4 zr0, zr1, zr2, zr3;          // z_n
    f32x4 za0, za1, za2, za3;          // accumulating z_{n+1}
    f32x4 ur0, ur1, ur2, ur3;          // current eval input (u); ur==zr at e=0
    {
        const float* zb = z0g + (size_t)n * 3136 + co * 49;
#define LOADZ(zm, mm)                                                           \
        _Pragma("unroll")                                                       \
        for (int j = 0; j < 4; j++) {                                           \
            int p_ = (mm) * 16 + q * 4 + j;                                     \
            zm[j] = (p_ < 49) ? zb[p_] : 0.f;                                   \
        }
        LOADZ(zr0, 0) LOADZ(zr1, 1) LOADZ(zr2, 2) LOADZ(zr3, 3)
#undef LOADZ
    }
    ur0 = zr0; ur1 = zr1; ur2 = zr2; ur3 = zr3;
    __syncthreads();

    const float dt = 0.5f;

#pragma unroll 1
    for (int step = 0; step < 12; step++) {
#pragma unroll 1
        for (int e = 0; e < 4; e++) {
            const float ck = (e == 0 || e == 3) ? dt / 6.f : dt / 3.f;
            const float cu = (e == 2) ? dt : 0.5f * dt;

            // ---- GN1(groups=64)+ReLU on u (registers) -> hp1 ----
            {
                float s = 0.f, s2 = 0.f;
                GN_ACCUM(ur0, 0) GN_ACCUM(ur1, 1) GN_ACCUM(ur2, 2) GN_ACCUM(ur3, 3)
                s += __shfl_xor(s, 16); s2 += __shfl_xor(s2, 16);
                s += __shfl_xor(s, 32); s2 += __shfl_xor(s2, 32);
                float mu = s * (1.f / 49.f);
                float r = rsqrtf(s2 * (1.f / 49.f) - mu * mu + 1e-5f);
                float sc = r * g1wv, sh = g1bv - mu * sc;
                GN_STORE(hp1p, ur0, 0) GN_STORE(hp1p, ur1, 1)
                GN_STORE(hp1p, ur2, 2) GN_STORE(hp1p, ur3, 3)
            }
            __syncthreads();   // B1: hp1 complete

            // ---- conv1 + in-register GN2(groups=64)+ReLU -> hp2 ----
            {
                f32x4 a0, a1, a2, a3;
                CONV_MFMA(hp1p, wb1h, wb1l)

                float s = 0.f, s2 = 0.f;
                GN_ACCUM(a0, 0) GN_ACCUM(a1, 1) GN_ACCUM(a2, 2) GN_ACCUM(a3, 3)
                s += __shfl_xor(s, 16); s2 += __shfl_xor(s2, 16);
                s += __shfl_xor(s, 32); s2 += __shfl_xor(s2, 32);
                float mu = s * (1.f / 49.f);
                float r = rsqrtf(s2 * (1.f / 49.f) - mu * mu + 1e-5f);
                float sc = r * g2wv, sh = g2bv - mu * sc;
                GN_STORE(hp2p, a0, 0) GN_STORE(hp2p, a1, 1)
                GN_STORE(hp2p, a2, 2) GN_STORE(hp2p, a3, 3)
            }
            __syncthreads();   // B2: hp2 complete (also: all hp1 reads done)

            // ---- conv2 + RK4 epilogue (all registers) ----
            {
                f32x4 a0, a1, a2, a3;
                CONV_MFMA(hp2p, wb2h, wb2l)

                RK4_REG(a0, zr0, za0, ur0) RK4_REG(a1, zr1, za1, ur1)
                RK4_REG(a2, zr2, za2, ur2) RK4_REG(a3, zr3, za3, ur3)
                if (e == 3) {
                    zr0 = za0; zr1 = za1; zr2 = za2; zr3 = za3;
                    ur0 = zr0; ur1 = zr1; ur2 = zr2; ur3 = zr3;
                }
            }
            // no barrier needed: next GN1 writes hp1, whose readers finished
            // before B2; state flow is wave-private (registers).
        }
    }

    // ---- final GN(groups=32)+ReLU + mean-pool (registers) ----
    {
        float s = 0.f, s2 = 0.f;
        GN_ACCUM(zr0, 0) GN_ACCUM(zr1, 1) GN_ACCUM(zr2, 2) GN_ACCUM(zr3, 3)
        s += __shfl_xor(s, 16); s2 += __shfl_xor(s2, 16);
        s += __shfl_xor(s, 32); s2 += __shfl_xor(s2, 32);
        s += __shfl_xor(s, 1);  s2 += __shfl_xor(s2, 1);   // pair channels (G=32)
        float mu = s * (1.f / 98.f);
        float r = rsqrtf(s2 * (1.f / 98.f) - mu * mu + 1e-5f);
        float sc = r * fgw[co], sh = fgb[co] - mu * sc;
        float ps = 0.f;
#pragma unroll
        for (int mm = 0; mm < 4; mm++) {
            f32x4 zz = (mm == 0) ? zr0 : (mm == 1) ? zr1 : (mm == 2) ? zr2 : zr3;
#pragma unroll
            for (int j = 0; j < 4; j++) {
                int p_ = mm * 16 + q * 4 + j;
                if (p_ < 49) ps += fmaxf(zz[j] * sc + sh, 0.f);
            }
        }
        ps += __shfl_xor(ps, 16);
        ps += __shfl_xor(ps, 32);
        if (q == 0) pooled[iw][co] = ps * (1.f / 49.f);
    }
    __syncthreads();
    {
        int tl = t & 255;
        if (tl < 10) {
            float a = fcb[tl];
#pragma unroll
            for (int k = 0; k < 64; k++) a += pooled[iw][k] * fcw[tl * 64 + k];
            out[(size_t)n * 10 + tl] = a;
        }
    }
}

static inline int nblk(long long total) { return (int)((total + TPB - 1) / TPB); }

extern "C" void kernel_launch(void* const* d_in, const int* in_sizes, int n_in,
                              void* d_out, int out_size, void* d_ws, size_t ws_size,
                              hipStream_t stream) {
    const float* x       = (const float*)d_in[0];
    const float* conv1_w = (const float*)d_in[1];
    const float* conv1_b = (const float*)d_in[2];
    const float* r1_g1w  = (const float*)d_in[3];
    const float* r1_g1b  = (const float*)d_in[4];
    const float* r1_c1w  = (const float*)d_in[5];
    const float* r1_g2w  = (const float*)d_in[6];
    const float* r1_g2b  = (const float*)d_in[7];
    const float* r1_c2w  = (const float*)d_in[8];
    const float* r1_dw   = (const float*)d_in[9];
    const float* r2_g1w  = (const float*)d_in[10];
    const float* r2_g1b  = (const float*)d_in[11];
    const float* r2_c1w  = (const float*)d_in[12];
    const float* r2_g2w  = (const float*)d_in[13];
    const float* r2_g2b  = (const float*)d_in[14];
    const float* r2_c2w  = (const float*)d_in[15];
    const float* r2_dw   = (const float*)d_in[16];
    const float* o_g1w   = (const float*)d_in[17];
    const float* o_g1b   = (const float*)d_in[18];
    const float* o_c1w   = (const float*)d_in[19];
    const float* o_g2w   = (const float*)d_in[20];
    const float* o_g2b   = (const float*)d_in[21];
    const float* o_c2w   = (const float*)d_in[22];
    const float* fin_gw  = (const float*)d_in[23];
    const float* fin_gb  = (const float*)d_in[24];
    const float* fc_w    = (const float*)d_in[25];
    const float* fc_b    = (const float*)d_in[26];
    float* out = (float*)d_out;

    const int N = 512;
    const long long SZ26 = 512LL * 64 * 26 * 26;
    const long long SZ13 = 512LL * 64 * 13 * 13;
    const long long SZ7  = 512LL * 64 * 7 * 7;
    const long long WTS  = 64 * 64 * 12;
    const long long WBS  = 9 * 2 * 4 * 64 * 8;     // 36864 ushorts per table

    float* B26   = (float*)d_ws;
    float* A13   = B26 + SZ26;
    float* B13   = A13 + SZ13;
    float* Z7    = B13 + SZ13;
    float* U7    = Z7 + SZ7;
    float* MEAN  = U7 + SZ7;
    float* RSTD  = MEAN + 512 * 64;
    float* WTr11 = RSTD + 512 * 64;
    float* WTr12 = WTr11 + WTS;
    float* WTr21 = WTr12 + WTS;
    float* WTr22 = WTr21 + WTS;
    unsigned short* WB1h = (unsigned short*)(WTr22 + WTS);
    unsigned short* WB1l = WB1h + WBS;
    unsigned short* WB2h = WB1l + WBS;
    unsigned short* WB2l = WB2h + WBS;

    auto gn = [&](const float* src, float* dst, int HW, int G,
                  const float* gw, const float* gb) {
        int waves = N * G;
        gn_stats_k<<<nblk((long long)waves * 64), TPB, 0, stream>>>(src, MEAN, RSTD, N, 64, HW, G);
        gn_apply_relu_k<<<nblk((long long)N * 64 * HW), TPB, 0, stream>>>(
            src, dst, MEAN, RSTD, gw, gb, N, 64, HW, G);
    };

    // ---- weight prep ----
    wprep_k<<<nblk(WTS), TPB, 0, stream>>>(r1_c1w, WTr11);
    wprep_k<<<nblk(WTS), TPB, 0, stream>>>(r1_c2w, WTr12);
    wprep_k<<<nblk(WTS), TPB, 0, stream>>>(r2_c1w, WTr21);
    wprep_k<<<nblk(WTS), TPB, 0, stream>>>(r2_c2w, WTr22);
    wsplit_k<<<nblk(WBS), TPB, 0, stream>>>(o_c1w, WB1h, WB1l);
    wsplit_k<<<nblk(WBS), TPB, 0, stream>>>(o_c2w, WB2h, WB2l);

    // ---- stage 0: conv1 ----
    conv1_k<<<nblk(SZ26), TPB, 0, stream>>>(x, conv1_w, conv1_b, B26);

    // ---- residual block 1: 26x26 -> 13x13 ----
    gn(B26, B26, 676, 32, r1_g1w, r1_g1b);
    conv_tile_k<2, true><<<512 * 4, 256, 0, stream>>>(B26, WTr11, r1_dw, nullptr,
                                                      A13, B13, 26, 26, 13, 13, 2, 2);
    gn(A13, A13, 169, 32, r1_g2w, r1_g2b);
    conv_tile_k<1, false><<<512 * 4, 256, 0, stream>>>(A13, WTr12, nullptr, B13,
                                                       B13, nullptr, 13, 13, 13, 13, 2, 2);

    // ---- residual block 2: 13x13 -> 7x7 ----
    gn(B13, B13, 169, 32, r2_g1w, r2_g1b);
    conv_tile_k<2, true><<<512, 256, 0, stream>>>(B13, WTr21, r2_dw, nullptr,
                                                  U7, Z7, 13, 13, 7, 7, 1, 1);
    gn(U7, U7, 49, 32, r2_g2w, r2_g2b);
    conv_tile_k<1, false><<<512, 256, 0, stream>>>(U7, WTr22, nullptr, Z7,
                                                   Z7, nullptr, 7, 7, 7, 7, 1, 1);

    // ---- fused MFMA ODE (12 RK4 steps) + final GN + pool + FC ----
    // 2 images per block: grid 256 x 512 threads
    ode_mfma_k<<<256, 512, 0, stream>>>(Z7, WB1h, WB1l, WB2h, WB2l,
                                        o_g1w, o_g1b, o_g2w, o_g2b,
                                        fin_gw, fin_gb, fc_w, fc_b, out);
}

// Round 10
// 1275.329 us; speedup vs baseline: 1.7794x; 1.5347x over previous
//
#include <hip/hip_runtime.h>
#include <hip/hip_bf16.h>

#define TPB 256

typedef __attribute__((ext_vector_type(8))) short short8;
typedef __attribute__((ext_vector_type(4))) float f32x4;

__device__ __forceinline__ unsigned short f2bf(float x) {
    union { float f; unsigned int u; } c; c.f = x;
    unsigned int u = c.u;
    unsigned int r = (u + 0x7fffu + ((u >> 16) & 1u)) >> 16;
    return (unsigned short)r;
}
__device__ __forceinline__ float bf2f(unsigned short h) {
    union { unsigned int u; float f; } c; c.u = ((unsigned int)h) << 16;
    return c.f;
}

// ======================= small prologue kernels ==============================

__global__ void conv1_k(const float* __restrict__ x, const float* __restrict__ w,
                        const float* __restrict__ b, float* __restrict__ out) {
    int idx = blockIdx.x * TPB + threadIdx.x;
    const int total = 512 * 64 * 26 * 26;
    if (idx >= total) return;
    int ox = idx % 26; int t = idx / 26;
    int oy = t % 26;   t /= 26;
    int co = t % 64;   int n = t / 64;
    const float* xp = x + (size_t)n * 784 + oy * 28 + ox;
    const float* wp = w + co * 9;
    float s = b[co];
#pragma unroll
    for (int ky = 0; ky < 3; ky++)
#pragma unroll
        for (int kx = 0; kx < 3; kx++)
            s += xp[ky * 28 + kx] * wp[ky * 3 + kx];
    out[idx] = s;
}

__global__ void gn_stats_k(const float* __restrict__ x, float* __restrict__ mean,
                           float* __restrict__ rstd, int N, int C, int HW, int G) {
    int gid  = (blockIdx.x * blockDim.x + threadIdx.x) >> 6;
    int lane = threadIdx.x & 63;
    int total = N * G;
    if (gid >= total) return;
    int n = gid / G, g = gid % G;
    int cpg = C / G;
    int gsize = cpg * HW;
    const float* p = x + ((size_t)n * C + (size_t)g * cpg) * HW;
    float s = 0.f, s2 = 0.f;
    for (int i = lane; i < gsize; i += 64) { float v = p[i]; s += v; s2 += v * v; }
#pragma unroll
    for (int off = 32; off; off >>= 1) {
        s  += __shfl_down(s,  off);
        s2 += __shfl_down(s2, off);
    }
    if (lane == 0) {
        float m = s / gsize;
        float var = s2 / gsize - m * m;
        mean[gid] = m;
        rstd[gid] = rsqrtf(var + 1e-5f);
    }
}

__global__ void gn_apply_relu_k(const float* __restrict__ x, float* __restrict__ out,
                                const float* __restrict__ mean, const float* __restrict__ rstd,
                                const float* __restrict__ gw, const float* __restrict__ gb,
                                int N, int C, int HW, int G) {
    int idx = blockIdx.x * TPB + threadIdx.x;
    int total = N * C * HW;
    if (idx >= total) return;
    int c = (idx / HW) % C;
    int n = idx / (HW * C);
    int cpg = C / G;
    int g = c / cpg;
    float m = mean[n * G + g], r = rstd[n * G + g];
    float v = (x[idx] - m) * r * gw[c] + gb[c];
    out[idx] = v > 0.f ? v : 0.f;
}

// prologue weight transpose: w[co][ci][3][3] -> wT[wave][ci][col16][12]
__global__ void wprep_k(const float* __restrict__ w, float* __restrict__ wT) {
    int i = blockIdx.x * TPB + threadIdx.x;
    if (i >= 64 * 64 * 12) return;
    int k = i % 12; int r = i / 12;
    int col = r % 16; r /= 16;
    int ci = r % 64; int wave = r / 64;
    int co = wave * 16 + col;
    wT[i] = (k < 9) ? w[(co * 64 + ci) * 9 + k] : 0.f;
}

// ODE weight: w[co][ci][3][3] -> bf16 B-frag table (round-to-nearest)
// layout [t:9][ks:2][nt:4][lane:64][8]: lane holds B[k=ks*32+(l>>4)*8+j][co=nt*16+(l&15)]
__global__ void wsplit_k(const float* __restrict__ w, unsigned short* __restrict__ hiT) {
    int i = blockIdx.x * TPB + threadIdx.x;
    if (i >= 9 * 2 * 4 * 64 * 8) return;
    int j = i & 7, l = (i >> 3) & 63, nt = (i >> 9) & 3, ks = (i >> 11) & 1, t = i >> 12;
    int co = nt * 16 + (l & 15);
    int ci = ks * 32 + (l >> 4) * 8 + j;
    hiT[i] = f2bf(w[(co * 64 + ci) * 9 + t]);
}

// ======================= tiled 3x3 conv (prologue) ===========================

#define KC 2
#define WCHUNK (KC * 16 * 12)
#define WREGION (64 * 16 * 12)

template<int STRIDE, bool SKIP>
__global__ __launch_bounds__(256)
void conv_tile_k(const float* __restrict__ in, const float* __restrict__ wT,
                 const float* __restrict__ dw, const float* __restrict__ addend,
                 float* __restrict__ out, float* __restrict__ skipout,
                 int H, int W, int OH, int OW, int TX, int TY) {
    constexpr int IHT = 6 * STRIDE + 3;
    constexpr int IWT = 6 * STRIDE + 3;
    constexpr int IPITCH = (STRIDE == 1) ? 12 : 16;
    constexpr int RSPAN = 4 * STRIDE + 2;

    __shared__ float sin_[64 * IHT * IPITCH];
    __shared__ float wl[4 * WCHUNK];

    int b = blockIdx.x;
    int tx = b % TX; b /= TX;
    int ty = b % TY; int n = b / TY;
    int oy0 = ty * 7, ox0 = tx * 7;
    int iy0 = oy0 * STRIDE - 1, ix0 = ox0 * STRIDE - 1;

    const int t = threadIdx.x;
    const int wave = t >> 6, lane = t & 63;
    const int cb = t >> 4, cbl = cb & 3, slot = t & 15;
    const int row = slot >> 1, half = slot & 1;
    const int crow = (row < 7) ? row : 0;
    const int co0 = cb * 4;
    float* wlw = wl + wave * WCHUNK;

    const float* ip = in + (size_t)n * 64 * H * W;
    for (int i = t; i < 64 * IHT * IPITCH; i += 256) {
        int c = i % IPITCH; int r = (i / IPITCH) % IHT; int ch = i / (IPITCH * IHT);
        int gy = iy0 + r, gx = ix0 + c;
        float v = 0.f;
        if (c < IWT && (unsigned)gy < (unsigned)H && (unsigned)gx < (unsigned)W)
            v = ip[(size_t)ch * H * W + gy * W + gx];
        sin_[i] = v;
    }
    __syncthreads();

    const float* wg = wT + (size_t)wave * WREGION;
    float acc[4][4];
#pragma unroll
    for (int j = 0; j < 4; j++)
#pragma unroll
        for (int px = 0; px < 4; px++) acc[j][px] = 0.f;

    float2 s0, s1, s2v;
    {
        const float2* gp = (const float2*)wg + lane * 3;
        s0 = gp[0]; s1 = gp[1]; s2v = gp[2];
    }
    for (int ch = 0; ch < 64 / KC; ch++) {
        {
            float2* wp = (float2*)wlw + lane * 3;
            wp[0] = s0; wp[1] = s1; wp[2] = s2v;
        }
        if (ch < 64 / KC - 1) {
            const float2* gp = (const float2*)(wg + (ch + 1) * WCHUNK) + lane * 3;
            s0 = gp[0]; s1 = gp[1]; s2v = gp[2];
        }
        float wr[KC][4][9];
#pragma unroll
        for (int c2 = 0; c2 < KC; c2++)
#pragma unroll
            for (int j = 0; j < 4; j++) {
                const float* wp2 = wlw + (c2 * 16 + cbl * 4 + j) * 12;
                float4 wa = *(const float4*)wp2;
                float4 wb = *(const float4*)(wp2 + 4);
                wr[c2][j][0] = wa.x; wr[c2][j][1] = wa.y; wr[c2][j][2] = wa.z;
                wr[c2][j][3] = wa.w; wr[c2][j][4] = wb.x; wr[c2][j][5] = wb.y;
                wr[c2][j][6] = wb.z; wr[c2][j][7] = wb.w; wr[c2][j][8] = wp2[8];
            }
#pragma unroll
        for (int c2 = 0; c2 < KC; c2++) {
            const float* hc = sin_ + ((ch * KC + c2) * IHT + crow * STRIDE) * IPITCH
                            + half * 4 * STRIDE;
            float rr[3][RSPAN];
#pragma unroll
            for (int ky = 0; ky < 3; ky++) {
                const float* bp = hc + ky * IPITCH;
                if constexpr (STRIDE == 1) {
                    float4 a = *(const float4*)bp; float2 bb = *(const float2*)(bp + 4);
                    rr[ky][0] = a.x; rr[ky][1] = a.y; rr[ky][2] = a.z; rr[ky][3] = a.w;
                    rr[ky][4] = bb.x; rr[ky][5] = bb.y;
                } else {
                    float4 a = *(const float4*)bp; float4 bb = *(const float4*)(bp + 4);
                    float2 cc = *(const float2*)(bp + 8);
                    rr[ky][0] = a.x; rr[ky][1] = a.y; rr[ky][2] = a.z; rr[ky][3] = a.w;
                    rr[ky][4] = bb.x; rr[ky][5] = bb.y; rr[ky][6] = bb.z; rr[ky][7] = bb.w;
                    rr[ky][8] = cc.x; rr[ky][9] = cc.y;
                }
            }
#pragma unroll
            for (int j = 0; j < 4; j++)
#pragma unroll
                for (int px = 0; px < 4; px++) {
                    float s = acc[j][px];
#pragma unroll
                    for (int ky = 0; ky < 3; ky++) {
                        s = fmaf(rr[ky][px * STRIDE + 0], wr[c2][j][ky * 3 + 0], s);
                        s = fmaf(rr[ky][px * STRIDE + 1], wr[c2][j][ky * 3 + 1], s);
                        s = fmaf(rr[ky][px * STRIDE + 2], wr[c2][j][ky * 3 + 2], s);
                    }
                    acc[j][px] = s;
                }
        }
    }

    if constexpr (SKIP) {
        if (slot < 14) {
            float sk[4][4];
#pragma unroll
            for (int j = 0; j < 4; j++)
#pragma unroll
                for (int px = 0; px < 4; px++) sk[j][px] = 0.f;
            for (int ci = 0; ci < 64; ci++) {
                const float* sp = sin_ + (ci * IHT + 2 * row + 1) * IPITCH + half * 8 + 1;
                float xv[4];
#pragma unroll
                for (int px = 0; px < 4; px++) xv[px] = sp[px * 2];
#pragma unroll
                for (int j = 0; j < 4; j++) {
                    float wv = dw[(co0 + j) * 64 + ci];
#pragma unroll
                    for (int px = 0; px < 4; px++) sk[j][px] = fmaf(xv[px], wv, sk[j][px]);
                }
            }
#pragma unroll
            for (int j = 0; j < 4; j++)
#pragma unroll
                for (int px = 0; px < 4; px++) {
                    int oy = oy0 + row, ox = ox0 + half * 4 + px;
                    if (oy < OH && ox < OW && half * 4 + px < 7)
                        skipout[(((size_t)n * 64 + co0 + j) * OH + oy) * OW + ox] = sk[j][px];
                }
        }
    }

    if (slot < 14) {
#pragma unroll
        for (int j = 0; j < 4; j++)
#pragma unroll
            for (int px = 0; px < 4; px++) {
                int oy = oy0 + row, ox = ox0 + half * 4 + px;
                if (oy < OH && ox < OW && half * 4 + px < 7) {
                    size_t idx = (((size_t)n * 64 + co0 + j) * OH + oy) * OW + ox;
                    float v = acc[j][px];
                    if (addend) v += addend[idx];
                    out[idx] = v;
                }
            }
    }
}

// ======================= ODE MFMA mega-kernel ================================
// R10: WEIGHTS IN REGISTERS. Each wave preloads its nt-slice of both conv
// tables ONCE: 2 x 18 short8 = 144 VGPRs (single bf16, lo-table dropped;
// absmax headroom 3.9e-3 vs 17.3e-3 absorbs the extra rounding term).
// The 96-conv loop then touches only LDS + registers: 72 ds_read_b128 +
// 72 MFMA per conv per wave. This removes the 2.4 GB/dispatch L2-miss weight
// stream that bounded R9 (dur == FETCH/2.27TB/s). w1r/w2r are arrays but all
// indices are compile-time constants after full unroll (rule #20 safe).

#define HP_PITCH 72          // ushorts per pixel-slot (144 B)
#define HP_PLANE (82 * HP_PITCH)

// one tap-GEMM for one m-tile accumulator
#define CONV_TAP(areg, hbase)                                                   \
    {                                                                           \
        int hr_ = min((hbase) + toff, 81);                                      \
        short8 a_ = *(const short8*)(hp + hr_ * HP_PITCH + kq);                 \
        areg = __builtin_amdgcn_mfma_f32_16x16x32_bf16(a_, vb, areg, 0, 0, 0);  \
    }

// full 3x3x64->16co conv for this wave from register weights: results a0..a3
#define CONV_MFMA(hpsrc, wreg)                                                  \
    a0 = (f32x4){0.f, 0.f, 0.f, 0.f}; a1 = a0; a2 = a0; a3 = a0;                \
    {                                                                           \
        const unsigned short* hp = (hpsrc);                                     \
        _Pragma("unroll")                                                       \
        for (int t9 = 0; t9 < 9; t9++) {                                        \
            const int toff = (t9 / 3) * 9 + (t9 % 3) - 10;                      \
            _Pragma("unroll")                                                   \
            for (int ks = 0; ks < 2; ks++) {                                    \
                short8 vb = wreg[t9 * 2 + ks];                                  \
                int kq = ks * 32 + kq0;                                         \
                CONV_TAP(a0, h0)                                                \
                CONV_TAP(a1, h1)                                                \
                CONV_TAP(a2, h2)                                                \
                CONV_TAP(a3, h3)                                                \
            }                                                                   \
        }                                                                       \
    }

// masked GN stat accumulation over one m-tile f32x4 (pixels p = mm*16+q*4+j)
#define GN_ACCUM(areg, mm)                                                      \
    _Pragma("unroll")                                                           \
    for (int j = 0; j < 4; j++) {                                               \
        int p_ = (mm) * 16 + q * 4 + j;                                         \
        if (p_ < 49) { float x_ = areg[j]; s += x_; s2 += x_ * x_; }            \
    }

// masked GN apply+ReLU+bf16-store to an hp plane
#define GN_STORE(dst, areg, mm)                                                 \
    _Pragma("unroll")                                                           \
    for (int j = 0; j < 4; j++) {                                               \
        int p_ = (mm) * 16 + q * 4 + j;                                         \
        if (p_ < 49) {                                                          \
            float y_ = fmaxf(areg[j] * sc + sh, 0.f);                           \
            int hr_ = (p_ / 7 + 1) * 9 + (p_ % 7) + 1;                          \
            (dst)[hr_ * HP_PITCH + co] = f2bf(y_);                              \
        }                                                                       \
    }

// RK4 update for one m-tile: k = a + u;  za (+)= ck*k;  u = z + cu*k (e<3)
#define RK4_REG(areg, zm, zam, um)                                              \
    {                                                                           \
        f32x4 kv = areg + um;                                                   \
        zam = (e == 0) ? (zm + ck * kv) : (zam + ck * kv);                      \
        if (e < 3) um = zm + cu * kv;                                           \
    }

__global__ __launch_bounds__(512, 2)
void ode_mfma_k(const float* __restrict__ z0g,
                const unsigned short* __restrict__ wb1h,
                const unsigned short* __restrict__ wb2h,
                const float* __restrict__ g1w, const float* __restrict__ g1b,
                const float* __restrict__ g2w, const float* __restrict__ g2b,
                const float* __restrict__ fgw, const float* __restrict__ fgb,
                const float* __restrict__ fcw, const float* __restrict__ fcb,
                float* __restrict__ out) {
    __shared__ unsigned short hp1[2][HP_PLANE], hp2[2][HP_PLANE];
    __shared__ float pooled[2][64];

    const int t = threadIdx.x;
    const int iw = t >> 8;                 // image within block (0/1)
    const int lane = t & 63;
    const int nt = (t >> 6) & 3;           // n-tile within image
    const int colL = lane & 15, q = lane >> 4;
    const int co = nt * 16 + colL;
    const int n = blockIdx.x * 2 + iw;

    unsigned short* hp1p = hp1[iw];
    unsigned short* hp2p = hp2[iw];

    const float g1wv = g1w[co], g1bv = g1b[co];
    const float g2wv = g2w[co], g2bv = g2b[co];

    // A-fragment row bases: pixel pA = m*16 + colL (sentinel 1000 -> row 81)
    const int pA0 = colL,      h0 = (pA0 < 49) ? ((pA0 / 7 + 1) * 9 + (pA0 % 7) + 1) : 1000;
    const int pA1 = 16 + colL, h1 = (pA1 < 49) ? ((pA1 / 7 + 1) * 9 + (pA1 % 7) + 1) : 1000;
    const int pA2 = 32 + colL, h2 = (pA2 < 49) ? ((pA2 / 7 + 1) * 9 + (pA2 % 7) + 1) : 1000;
    const int pA3 = 48 + colL, h3 = (pA3 < 49) ? ((pA3 / 7 + 1) * 9 + (pA3 % 7) + 1) : 1000;
    const int kq0 = q * 8;

    // ---- preload this wave's weight slices into registers (once) ----
    short8 w1r[18], w2r[18];
#pragma unroll
    for (int i = 0; i < 18; i++) {
        int fidx = (i * 4 + nt) * 64 + lane;
        w1r[i] = ((const short8*)wb1h)[fidx];
        w2r[i] = ((const short8*)wb2h)[fidx];
    }

    // ---- init LDS planes (halo + sentinel row stay 0 forever) ----
    for (int i = t; i < 2 * HP_PLANE; i += 512) {
        ((unsigned short*)hp1)[i] = 0;
        ((unsigned short*)hp2)[i] = 0;
    }

    // ---- load state into registers: z[m][j] = z0[co][m*16+q*4+j] ----
    f32x4 zr0, zr1, zr2, zr3;          // z_n
    f32x4 za0, za1, za2, za3;          // accumulating z_{n+1}
    f32x4 ur0, ur1, ur2, ur3;          // current eval input (u); ur==zr at e=0
    {
        const float* zb = z0g + (size_t)n * 3136 + co * 49;
#define LOADZ(zm, mm)                                                           \
        _Pragma("unroll")                                                       \
        for (int j = 0; j < 4; j++) {                                           \
            int p_ = (mm) * 16 + q * 4 + j;                                     \
            zm[j] = (p_ < 49) ? zb[p_] : 0.f;                                   \
        }
        LOADZ(zr0, 0) LOADZ(zr1, 1) LOADZ(zr2, 2) LOADZ(zr3, 3)
#undef LOADZ
    }
    ur0 = zr0; ur1 = zr1; ur2 = zr2; ur3 = zr3;
    __syncthreads();

    const float dt = 0.5f;

#pragma unroll 1
    for (int step = 0; step < 12; step++) {
#pragma unroll 1
        for (int e = 0; e < 4; e++) {
            const float ck = (e == 0 || e == 3) ? dt / 6.f : dt / 3.f;
            const float cu = (e == 2) ? dt : 0.5f * dt;

            // ---- GN1(groups=64)+ReLU on u (registers) -> hp1 ----
            {
                float s = 0.f, s2 = 0.f;
                GN_ACCUM(ur0, 0) GN_ACCUM(ur1, 1) GN_ACCUM(ur2, 2) GN_ACCUM(ur3, 3)
                s += __shfl_xor(s, 16); s2 += __shfl_xor(s2, 16);
                s += __shfl_xor(s, 32); s2 += __shfl_xor(s2, 32);
                float mu = s * (1.f / 49.f);
                float r = rsqrtf(s2 * (1.f / 49.f) - mu * mu + 1e-5f);
                float sc = r * g1wv, sh = g1bv - mu * sc;
                GN_STORE(hp1p, ur0, 0) GN_STORE(hp1p, ur1, 1)
                GN_STORE(hp1p, ur2, 2) GN_STORE(hp1p, ur3, 3)
            }
            __syncthreads();   // B1: hp1 complete

            // ---- conv1 + in-register GN2(groups=64)+ReLU -> hp2 ----
            {
                f32x4 a0, a1, a2, a3;
                CONV_MFMA(hp1p, w1r)

                float s = 0.f, s2 = 0.f;
                GN_ACCUM(a0, 0) GN_ACCUM(a1, 1) GN_ACCUM(a2, 2) GN_ACCUM(a3, 3)
                s += __shfl_xor(s, 16); s2 += __shfl_xor(s2, 16);
                s += __shfl_xor(s, 32); s2 += __shfl_xor(s2, 32);
                float mu = s * (1.f / 49.f);
                float r = rsqrtf(s2 * (1.f / 49.f) - mu * mu + 1e-5f);
                float sc = r * g2wv, sh = g2bv - mu * sc;
                GN_STORE(hp2p, a0, 0) GN_STORE(hp2p, a1, 1)
                GN_STORE(hp2p, a2, 2) GN_STORE(hp2p, a3, 3)
            }
            __syncthreads();   // B2: hp2 complete (also: all hp1 reads done)

            // ---- conv2 + RK4 epilogue (all registers) ----
            {
                f32x4 a0, a1, a2, a3;
                CONV_MFMA(hp2p, w2r)

                RK4_REG(a0, zr0, za0, ur0) RK4_REG(a1, zr1, za1, ur1)
                RK4_REG(a2, zr2, za2, ur2) RK4_REG(a3, zr3, za3, ur3)
                if (e == 3) {
                    zr0 = za0; zr1 = za1; zr2 = za2; zr3 = za3;
                    ur0 = zr0; ur1 = zr1; ur2 = zr2; ur3 = zr3;
                }
            }
            // no barrier needed: next GN1 writes hp1, whose readers finished
            // before B2; state flow is wave-private (registers).
        }
    }

    // ---- final GN(groups=32)+ReLU + mean-pool (registers) ----
    {
        float s = 0.f, s2 = 0.f;
        GN_ACCUM(zr0, 0) GN_ACCUM(zr1, 1) GN_ACCUM(zr2, 2) GN_ACCUM(zr3, 3)
        s += __shfl_xor(s, 16); s2 += __shfl_xor(s2, 16);
        s += __shfl_xor(s, 32); s2 += __shfl_xor(s2, 32);
        s += __shfl_xor(s, 1);  s2 += __shfl_xor(s2, 1);   // pair channels (G=32)
        float mu = s * (1.f / 98.f);
        float r = rsqrtf(s2 * (1.f / 98.f) - mu * mu + 1e-5f);
        float sc = r * fgw[co], sh = fgb[co] - mu * sc;
        float ps = 0.f;
#pragma unroll
        for (int mm = 0; mm < 4; mm++) {
            f32x4 zz = (mm == 0) ? zr0 : (mm == 1) ? zr1 : (mm == 2) ? zr2 : zr3;
#pragma unroll
            for (int j = 0; j < 4; j++) {
                int p_ = mm * 16 + q * 4 + j;
                if (p_ < 49) ps += fmaxf(zz[j] * sc + sh, 0.f);
            }
        }
        ps += __shfl_xor(ps, 16);
        ps += __shfl_xor(ps, 32);
        if (q == 0) pooled[iw][co] = ps * (1.f / 49.f);
    }
    __syncthreads();
    {
        int tl = t & 255;
        if (tl < 10) {
            float a = fcb[tl];
#pragma unroll
            for (int k = 0; k < 64; k++) a += pooled[iw][k] * fcw[tl * 64 + k];
            out[(size_t)n * 10 + tl] = a;
        }
    }
}

static inline int nblk(long long total) { return (int)((total + TPB - 1) / TPB); }

extern "C" void kernel_launch(void* const* d_in, const int* in_sizes, int n_in,
                              void* d_out, int out_size, void* d_ws, size_t ws_size,
                              hipStream_t stream) {
    const float* x       = (const float*)d_in[0];
    const float* conv1_w = (const float*)d_in[1];
    const float* conv1_b = (const float*)d_in[2];
    const float* r1_g1w  = (const float*)d_in[3];
    const float* r1_g1b  = (const float*)d_in[4];
    const float* r1_c1w  = (const float*)d_in[5];
    const float* r1_g2w  = (const float*)d_in[6];
    const float* r1_g2b  = (const float*)d_in[7];
    const float* r1_c2w  = (const float*)d_in[8];
    const float* r1_dw   = (const float*)d_in[9];
    const float* r2_g1w  = (const float*)d_in[10];
    const float* r2_g1b  = (const float*)d_in[11];
    const float* r2_c1w  = (const float*)d_in[12];
    const float* r2_g2w  = (const float*)d_in[13];
    const float* r2_g2b  = (const float*)d_in[14];
    const float* r2_c2w  = (const float*)d_in[15];
    const float* r2_dw   = (const float*)d_in[16];
    const float* o_g1w   = (const float*)d_in[17];
    const float* o_g1b   = (const float*)d_in[18];
    const float* o_c1w   = (const float*)d_in[19];
    const float* o_g2w   = (const float*)d_in[20];
    const float* o_g2b   = (const float*)d_in[21];
    const float* o_c2w   = (const float*)d_in[22];
    const float* fin_gw  = (const float*)d_in[23];
    const float* fin_gb  = (const float*)d_in[24];
    const float* fc_w    = (const float*)d_in[25];
    const float* fc_b    = (const float*)d_in[26];
    float* out = (float*)d_out;

    const int N = 512;
    const long long SZ26 = 512LL * 64 * 26 * 26;
    const long long SZ13 = 512LL * 64 * 13 * 13;
    const long long SZ7  = 512LL * 64 * 7 * 7;
    const long long WTS  = 64 * 64 * 12;
    const long long WBS  = 9 * 2 * 4 * 64 * 8;     // 36864 ushorts per table

    float* B26   = (float*)d_ws;
    float* A13   = B26 + SZ26;
    float* B13   = A13 + SZ13;
    float* Z7    = B13 + SZ13;
    float* U7    = Z7 + SZ7;
    float* MEAN  = U7 + SZ7;
    float* RSTD  = MEAN + 512 * 64;
    float* WTr11 = RSTD + 512 * 64;
    float* WTr12 = WTr11 + WTS;
    float* WTr21 = WTr12 + WTS;
    float* WTr22 = WTr21 + WTS;
    unsigned short* WB1h = (unsigned short*)(WTr22 + WTS);
    unsigned short* WB2h = WB1h + WBS;

    auto gn = [&](const float* src, float* dst, int HW, int G,
                  const float* gw, const float* gb) {
        int waves = N * G;
        gn_stats_k<<<nblk((long long)waves * 64), TPB, 0, stream>>>(src, MEAN, RSTD, N, 64, HW, G);
        gn_apply_relu_k<<<nblk((long long)N * 64 * HW), TPB, 0, stream>>>(
            src, dst, MEAN, RSTD, gw, gb, N, 64, HW, G);
    };

    // ---- weight prep ----
    wprep_k<<<nblk(WTS), TPB, 0, stream>>>(r1_c1w, WTr11);
    wprep_k<<<nblk(WTS), TPB, 0, stream>>>(r1_c2w, WTr12);
    wprep_k<<<nblk(WTS), TPB, 0, stream>>>(r2_c1w, WTr21);
    wprep_k<<<nblk(WTS), TPB, 0, stream>>>(r2_c2w, WTr22);
    wsplit_k<<<nblk(WBS), TPB, 0, stream>>>(o_c1w, WB1h);
    wsplit_k<<<nblk(WBS), TPB, 0, stream>>>(o_c2w, WB2h);

    // ---- stage 0: conv1 ----
    conv1_k<<<nblk(SZ26), TPB, 0, stream>>>(x, conv1_w, conv1_b, B26);

    // ---- residual block 1: 26x26 -> 13x13 ----
    gn(B26, B26, 676, 32, r1_g1w, r1_g1b);
    conv_tile_k<2, true><<<512 * 4, 256, 0, stream>>>(B26, WTr11, r1_dw, nullptr,
                                                      A13, B13, 26, 26, 13, 13, 2, 2);
    gn(A13, A13, 169, 32, r1_g2w, r1_g2b);
    conv_tile_k<1, false><<<512 * 4, 256, 0, stream>>>(A13, WTr12, nullptr, B13,
                                                       B13, nullptr, 13, 13, 13, 13, 2, 2);

    // ---- residual block 2: 13x13 -> 7x7 ----
    gn(B13, B13, 169, 32, r2_g1w, r2_g1b);
    conv_tile_k<2, true><<<512, 256, 0, stream>>>(B13, WTr21, r2_dw, nullptr,
                                                  U7, Z7, 13, 13, 7, 7, 1, 1);
    gn(U7, U7, 49, 32, r2_g2w, r2_g2b);
    conv_tile_k<1, false><<<512, 256, 0, stream>>>(U7, WTr22, nullptr, Z7,
                                                   Z7, nullptr, 7, 7, 7, 7, 1, 1);

    // ---- fused MFMA ODE (12 RK4 steps) + final GN + pool + FC ----
    // 2 images per block: grid 256 x 512 threads; weights live in registers
    ode_mfma_k<<<256, 512, 0, stream>>>(Z7, WB1h, WB2h,
                                        o_g1w, o_g1b, o_g2w, o_g2b,
                                        fin_gw, fin_gb, fc_w, fc_b, out);
}

// Round 11
// 1182.278 us; speedup vs baseline: 1.9195x; 1.0787x over previous
//
#include <hip/hip_runtime.h>
#include <hip/hip_bf16.h>

#define TPB 256

typedef __attribute__((ext_vector_type(8))) short short8;
typedef __attribute__((ext_vector_type(4))) float f32x4;

__device__ __forceinline__ unsigned short f2bf(float x) {
    union { float f; unsigned int u; } c; c.f = x;
    unsigned int u = c.u;
    unsigned int r = (u + 0x7fffu + ((u >> 16) & 1u)) >> 16;
    return (unsigned short)r;
}

// ======================= small prologue kernels ==============================

__global__ void conv1_k(const float* __restrict__ x, const float* __restrict__ w,
                        const float* __restrict__ b, float* __restrict__ out) {
    int idx = blockIdx.x * TPB + threadIdx.x;
    const int total = 512 * 64 * 26 * 26;
    if (idx >= total) return;
    int ox = idx % 26; int t = idx / 26;
    int oy = t % 26;   t /= 26;
    int co = t % 64;   int n = t / 64;
    const float* xp = x + (size_t)n * 784 + oy * 28 + ox;
    const float* wp = w + co * 9;
    float s = b[co];
#pragma unroll
    for (int ky = 0; ky < 3; ky++)
#pragma unroll
        for (int kx = 0; kx < 3; kx++)
            s += xp[ky * 28 + kx] * wp[ky * 3 + kx];
    out[idx] = s;
}

__global__ void gn_stats_k(const float* __restrict__ x, float* __restrict__ mean,
                           float* __restrict__ rstd, int N, int C, int HW, int G) {
    int gid  = (blockIdx.x * blockDim.x + threadIdx.x) >> 6;
    int lane = threadIdx.x & 63;
    int total = N * G;
    if (gid >= total) return;
    int n = gid / G, g = gid % G;
    int cpg = C / G;
    int gsize = cpg * HW;
    const float* p = x + ((size_t)n * C + (size_t)g * cpg) * HW;
    float s = 0.f, s2 = 0.f;
    for (int i = lane; i < gsize; i += 64) { float v = p[i]; s += v; s2 += v * v; }
#pragma unroll
    for (int off = 32; off; off >>= 1) {
        s  += __shfl_down(s,  off);
        s2 += __shfl_down(s2, off);
    }
    if (lane == 0) {
        float m = s / gsize;
        float var = s2 / gsize - m * m;
        mean[gid] = m;
        rstd[gid] = rsqrtf(var + 1e-5f);
    }
}

__global__ void gn_apply_relu_k(const float* __restrict__ x, float* __restrict__ out,
                                const float* __restrict__ mean, const float* __restrict__ rstd,
                                const float* __restrict__ gw, const float* __restrict__ gb,
                                int N, int C, int HW, int G) {
    int idx = blockIdx.x * TPB + threadIdx.x;
    int total = N * C * HW;
    if (idx >= total) return;
    int c = (idx / HW) % C;
    int n = idx / (HW * C);
    int cpg = C / G;
    int g = c / cpg;
    float m = mean[n * G + g], r = rstd[n * G + g];
    float v = (x[idx] - m) * r * gw[c] + gb[c];
    out[idx] = v > 0.f ? v : 0.f;
}

// prologue weight transpose: w[co][ci][3][3] -> wT[wave][ci][col16][12]
__global__ void wprep_k(const float* __restrict__ w, float* __restrict__ wT) {
    int i = blockIdx.x * TPB + threadIdx.x;
    if (i >= 64 * 64 * 12) return;
    int k = i % 12; int r = i / 12;
    int col = r % 16; r /= 16;
    int ci = r % 64; int wave = r / 64;
    int co = wave * 16 + col;
    wT[i] = (k < 9) ? w[(co * 64 + ci) * 9 + k] : 0.f;
}

// ODE weight: w[co][ci][3][3] -> bf16 B-frag table
// layout [t:9][ks:2][nt:4][lane:64][8]: lane holds B[k=ks*32+(l>>4)*8+j][co=nt*16+(l&15)]
__global__ void wsplit_k(const float* __restrict__ w, unsigned short* __restrict__ hiT) {
    int i = blockIdx.x * TPB + threadIdx.x;
    if (i >= 9 * 2 * 4 * 64 * 8) return;
    int j = i & 7, l = (i >> 3) & 63, nt = (i >> 9) & 3, ks = (i >> 11) & 1, t = i >> 12;
    int co = nt * 16 + (l & 15);
    int ci = ks * 32 + (l >> 4) * 8 + j;
    hiT[i] = f2bf(w[(co * 64 + ci) * 9 + t]);
}

// ======================= tiled 3x3 conv (prologue) ===========================

#define KC 2
#define WCHUNK (KC * 16 * 12)
#define WREGION (64 * 16 * 12)

template<int STRIDE, bool SKIP>
__global__ __launch_bounds__(256)
void conv_tile_k(const float* __restrict__ in, const float* __restrict__ wT,
                 const float* __restrict__ dw, const float* __restrict__ addend,
                 float* __restrict__ out, float* __restrict__ skipout,
                 int H, int W, int OH, int OW, int TX, int TY) {
    constexpr int IHT = 6 * STRIDE + 3;
    constexpr int IWT = 6 * STRIDE + 3;
    constexpr int IPITCH = (STRIDE == 1) ? 12 : 16;
    constexpr int RSPAN = 4 * STRIDE + 2;

    __shared__ float sin_[64 * IHT * IPITCH];
    __shared__ float wl[4 * WCHUNK];

    int b = blockIdx.x;
    int tx = b % TX; b /= TX;
    int ty = b % TY; int n = b / TY;
    int oy0 = ty * 7, ox0 = tx * 7;
    int iy0 = oy0 * STRIDE - 1, ix0 = ox0 * STRIDE - 1;

    const int t = threadIdx.x;
    const int wave = t >> 6, lane = t & 63;
    const int cb = t >> 4, cbl = cb & 3, slot = t & 15;
    const int row = slot >> 1, half = slot & 1;
    const int crow = (row < 7) ? row : 0;
    const int co0 = cb * 4;
    float* wlw = wl + wave * WCHUNK;

    const float* ip = in + (size_t)n * 64 * H * W;
    for (int i = t; i < 64 * IHT * IPITCH; i += 256) {
        int c = i % IPITCH; int r = (i / IPITCH) % IHT; int ch = i / (IPITCH * IHT);
        int gy = iy0 + r, gx = ix0 + c;
        float v = 0.f;
        if (c < IWT && (unsigned)gy < (unsigned)H && (unsigned)gx < (unsigned)W)
            v = ip[(size_t)ch * H * W + gy * W + gx];
        sin_[i] = v;
    }
    __syncthreads();

    const float* wg = wT + (size_t)wave * WREGION;
    float acc[4][4];
#pragma unroll
    for (int j = 0; j < 4; j++)
#pragma unroll
        for (int px = 0; px < 4; px++) acc[j][px] = 0.f;

    float2 s0, s1, s2v;
    {
        const float2* gp = (const float2*)wg + lane * 3;
        s0 = gp[0]; s1 = gp[1]; s2v = gp[2];
    }
    for (int ch = 0; ch < 64 / KC; ch++) {
        {
            float2* wp = (float2*)wlw + lane * 3;
            wp[0] = s0; wp[1] = s1; wp[2] = s2v;
        }
        if (ch < 64 / KC - 1) {
            const float2* gp = (const float2*)(wg + (ch + 1) * WCHUNK) + lane * 3;
            s0 = gp[0]; s1 = gp[1]; s2v = gp[2];
        }
        float wr[KC][4][9];
#pragma unroll
        for (int c2 = 0; c2 < KC; c2++)
#pragma unroll
            for (int j = 0; j < 4; j++) {
                const float* wp2 = wlw + (c2 * 16 + cbl * 4 + j) * 12;
                float4 wa = *(const float4*)wp2;
                float4 wb = *(const float4*)(wp2 + 4);
                wr[c2][j][0] = wa.x; wr[c2][j][1] = wa.y; wr[c2][j][2] = wa.z;
                wr[c2][j][3] = wa.w; wr[c2][j][4] = wb.x; wr[c2][j][5] = wb.y;
                wr[c2][j][6] = wb.z; wr[c2][j][7] = wb.w; wr[c2][j][8] = wp2[8];
            }
#pragma unroll
        for (int c2 = 0; c2 < KC; c2++) {
            const float* hc = sin_ + ((ch * KC + c2) * IHT + crow * STRIDE) * IPITCH
                            + half * 4 * STRIDE;
            float rr[3][RSPAN];
#pragma unroll
            for (int ky = 0; ky < 3; ky++) {
                const float* bp = hc + ky * IPITCH;
                if constexpr (STRIDE == 1) {
                    float4 a = *(const float4*)bp; float2 bb = *(const float2*)(bp + 4);
                    rr[ky][0] = a.x; rr[ky][1] = a.y; rr[ky][2] = a.z; rr[ky][3] = a.w;
                    rr[ky][4] = bb.x; rr[ky][5] = bb.y;
                } else {
                    float4 a = *(const float4*)bp; float4 bb = *(const float4*)(bp + 4);
                    float2 cc = *(const float2*)(bp + 8);
                    rr[ky][0] = a.x; rr[ky][1] = a.y; rr[ky][2] = a.z; rr[ky][3] = a.w;
                    rr[ky][4] = bb.x; rr[ky][5] = bb.y; rr[ky][6] = bb.z; rr[ky][7] = bb.w;
                    rr[ky][8] = cc.x; rr[ky][9] = cc.y;
                }
            }
#pragma unroll
            for (int j = 0; j < 4; j++)
#pragma unroll
                for (int px = 0; px < 4; px++) {
                    float s = acc[j][px];
#pragma unroll
                    for (int ky = 0; ky < 3; ky++) {
                        s = fmaf(rr[ky][px * STRIDE + 0], wr[c2][j][ky * 3 + 0], s);
                        s = fmaf(rr[ky][px * STRIDE + 1], wr[c2][j][ky * 3 + 1], s);
                        s = fmaf(rr[ky][px * STRIDE + 2], wr[c2][j][ky * 3 + 2], s);
                    }
                    acc[j][px] = s;
                }
        }
    }

    if constexpr (SKIP) {
        if (slot < 14) {
            float sk[4][4];
#pragma unroll
            for (int j = 0; j < 4; j++)
#pragma unroll
                for (int px = 0; px < 4; px++) sk[j][px] = 0.f;
            for (int ci = 0; ci < 64; ci++) {
                const float* sp = sin_ + (ci * IHT + 2 * row + 1) * IPITCH + half * 8 + 1;
                float xv[4];
#pragma unroll
                for (int px = 0; px < 4; px++) xv[px] = sp[px * 2];
#pragma unroll
                for (int j = 0; j < 4; j++) {
                    float wv = dw[(co0 + j) * 64 + ci];
#pragma unroll
                    for (int px = 0; px < 4; px++) sk[j][px] = fmaf(xv[px], wv, sk[j][px]);
                }
            }
#pragma unroll
            for (int j = 0; j < 4; j++)
#pragma unroll
                for (int px = 0; px < 4; px++) {
                    int oy = oy0 + row, ox = ox0 + half * 4 + px;
                    if (oy < OH && ox < OW && half * 4 + px < 7)
                        skipout[(((size_t)n * 64 + co0 + j) * OH + oy) * OW + ox] = sk[j][px];
                }
        }
    }

    if (slot < 14) {
#pragma unroll
        for (int j = 0; j < 4; j++)
#pragma unroll
            for (int px = 0; px < 4; px++) {
                int oy = oy0 + row, ox = ox0 + half * 4 + px;
                if (oy < OH && ox < OW && half * 4 + px < 7) {
                    size_t idx = (((size_t)n * 64 + co0 + j) * OH + oy) * OW + ox;
                    float v = acc[j][px];
                    if (addend) v += addend[idx];
                    out[idx] = v;
                }
            }
    }
}

// ======================= ODE MFMA mega-kernel ================================
// R11: CONFLICT-FREE LDS LAYOUT + 1 IMAGE/BLOCK.
// Pixel grid padded to 8 wide: p = y*8+x (valid x<7, y<7). Halo slot =
// (y+1)*10 + (x+1), 100 slots x 72 ushorts (144 B). Bank-quad index =
// (slot + 4ks + q) mod 8; every tap read has each y-row's 8 lanes sweep
// x=0..7 -> all 8 quads exactly once -> uniform 8 lanes/quad = wave64
// minimum (R10's 9-slot pitch with 7-wide rows gave max-10/quad -> ~25%
// conflict overhead, SQ_LDS_BANK_CONFLICT 8.5e7). All tap slots in-range
// [0,100) so the sentinel min() clamp is gone. 1 image per 256-thread
// block (grid 512, 2 blocks/CU): barriers no longer couple two images.

#define HP_PITCH 72              // ushorts per pixel-slot (144 B)
#define HP_PLANE (100 * HP_PITCH)

#define PVALID(p) ((((p) & 7) < 7) && (((p) >> 3) < 7))
#define PSLOT(p)  (((((p) >> 3) + 1) * 10) + (((p) & 7) + 1))

// one tap-GEMM for one m-tile accumulator (no clamp: slots always in range)
#define CONV_TAP(areg, hbase)                                                   \
    {                                                                           \
        short8 a_ = *(const short8*)(hp + ((hbase) + toff) * HP_PITCH + kq);    \
        areg = __builtin_amdgcn_mfma_f32_16x16x32_bf16(a_, vb, areg, 0, 0, 0);  \
    }

// full 3x3x64->16co conv for this wave from register weights: results a0..a3
#define CONV_MFMA(hpsrc, wreg)                                                  \
    a0 = (f32x4){0.f, 0.f, 0.f, 0.f}; a1 = a0; a2 = a0; a3 = a0;                \
    {                                                                           \
        const unsigned short* hp = (hpsrc);                                     \
        _Pragma("unroll")                                                       \
        for (int t9 = 0; t9 < 9; t9++) {                                        \
            const int toff = (t9 / 3) * 10 + (t9 % 3) - 11;                     \
            _Pragma("unroll")                                                   \
            for (int ks = 0; ks < 2; ks++) {                                    \
                short8 vb = wreg[t9 * 2 + ks];                                  \
                int kq = ks * 32 + kq0;                                         \
                CONV_TAP(a0, h0)                                                \
                CONV_TAP(a1, h1)                                                \
                CONV_TAP(a2, h2)                                                \
                CONV_TAP(a3, h3)                                                \
            }                                                                   \
        }                                                                       \
    }

// masked GN stat accumulation over one m-tile f32x4 (pixels p = mm*16+q*4+j)
#define GN_ACCUM(areg, mm)                                                      \
    _Pragma("unroll")                                                           \
    for (int j = 0; j < 4; j++) {                                               \
        int p_ = (mm) * 16 + q * 4 + j;                                         \
        if (PVALID(p_)) { float x_ = areg[j]; s += x_; s2 += x_ * x_; }         \
    }

// masked GN apply+ReLU+bf16-store to an hp plane
#define GN_STORE(dst, areg, mm)                                                 \
    _Pragma("unroll")                                                           \
    for (int j = 0; j < 4; j++) {                                               \
        int p_ = (mm) * 16 + q * 4 + j;                                         \
        if (PVALID(p_)) {                                                       \
            float y_ = fmaxf(areg[j] * sc + sh, 0.f);                           \
            (dst)[PSLOT(p_) * HP_PITCH + co] = f2bf(y_);                        \
        }                                                                       \
    }

// RK4 update for one m-tile: k = a + u;  za (+)= ck*k;  u = z + cu*k (e<3)
#define RK4_REG(areg, zm, zam, um)                                              \
    {                                                                           \
        f32x4 kv = areg + um;                                                   \
        zam = (e == 0) ? (zm + ck * kv) : (zam + ck * kv);                      \
        if (e < 3) um = zm + cu * kv;                                           \
    }

__global__ __launch_bounds__(256, 2)
void ode_mfma_k(const float* __restrict__ z0g,
                const unsigned short* __restrict__ wb1h,
                const unsigned short* __restrict__ wb2h,
                const float* __restrict__ g1w, const float* __restrict__ g1b,
                const float* __restrict__ g2w, const float* __restrict__ g2b,
                const float* __restrict__ fgw, const float* __restrict__ fgb,
                const float* __restrict__ fcw, const float* __restrict__ fcb,
                float* __restrict__ out) {
    __shared__ unsigned short hp1[HP_PLANE], hp2[HP_PLANE];
    __shared__ float pooled[64];

    const int t = threadIdx.x;
    const int n = blockIdx.x;
    const int lane = t & 63;
    const int nt = t >> 6;                 // wave = N-tile
    const int colL = lane & 15, q = lane >> 4;
    const int co = nt * 16 + colL;

    const float g1wv = g1w[co], g1bv = g1b[co];
    const float g2wv = g2w[co], g2bv = g2b[co];

    // A-fragment row bases (center slot; invalid pixels point at zero halo)
    const int h0 = PSLOT(colL);
    const int h1 = PSLOT(16 + colL);
    const int h2 = PSLOT(32 + colL);
    const int h3 = PSLOT(48 + colL);
    const int kq0 = q * 8;

    // ---- preload this wave's weight slices into registers (once) ----
    short8 w1r[18], w2r[18];
#pragma unroll
    for (int i = 0; i < 18; i++) {
        int fidx = (i * 4 + nt) * 64 + lane;
        w1r[i] = ((const short8*)wb1h)[fidx];
        w2r[i] = ((const short8*)wb2h)[fidx];
    }

    // ---- init LDS planes (halo + padding slots stay 0 forever) ----
    for (int i = t; i < HP_PLANE; i += 256) { hp1[i] = 0; hp2[i] = 0; }

    // ---- load state into registers: z[m][j] at pixel p = m*16+q*4+j ----
    f32x4 zr0, zr1, zr2, zr3;          // z_n
    f32x4 za0, za1, za2, za3;          // accumulating z_{n+1}
    f32x4 ur0, ur1, ur2, ur3;          // current eval input (u); ur==zr at e=0
    {
        const float* zb = z0g + (size_t)n * 3136 + co * 49;
#define LOADZ(zm, mm)                                                           \
        _Pragma("unroll")                                                       \
        for (int j = 0; j < 4; j++) {                                           \
            int p_ = (mm) * 16 + q * 4 + j;                                     \
            zm[j] = PVALID(p_) ? zb[(p_ >> 3) * 7 + (p_ & 7)] : 0.f;            \
        }
        LOADZ(zr0, 0) LOADZ(zr1, 1) LOADZ(zr2, 2) LOADZ(zr3, 3)
#undef LOADZ
    }
    ur0 = zr0; ur1 = zr1; ur2 = zr2; ur3 = zr3;
    __syncthreads();

    const float dt = 0.5f;

#pragma unroll 1
    for (int step = 0; step < 12; step++) {
#pragma unroll 1
        for (int e = 0; e < 4; e++) {
            const float ck = (e == 0 || e == 3) ? dt / 6.f : dt / 3.f;
            const float cu = (e == 2) ? dt : 0.5f * dt;

            // ---- GN1(groups=64)+ReLU on u (registers) -> hp1 ----
            {
                float s = 0.f, s2 = 0.f;
                GN_ACCUM(ur0, 0) GN_ACCUM(ur1, 1) GN_ACCUM(ur2, 2) GN_ACCUM(ur3, 3)
                s += __shfl_xor(s, 16); s2 += __shfl_xor(s2, 16);
                s += __shfl_xor(s, 32); s2 += __shfl_xor(s2, 32);
                float mu = s * (1.f / 49.f);
                float r = rsqrtf(s2 * (1.f / 49.f) - mu * mu + 1e-5f);
                float sc = r * g1wv, sh = g1bv - mu * sc;
                GN_STORE(hp1, ur0, 0) GN_STORE(hp1, ur1, 1)
                GN_STORE(hp1, ur2, 2) GN_STORE(hp1, ur3, 3)
            }
            __syncthreads();   // B1: hp1 complete

            // ---- conv1 + in-register GN2(groups=64)+ReLU -> hp2 ----
            {
                f32x4 a0, a1, a2, a3;
                CONV_MFMA(hp1, w1r)

                float s = 0.f, s2 = 0.f;
                GN_ACCUM(a0, 0) GN_ACCUM(a1, 1) GN_ACCUM(a2, 2) GN_ACCUM(a3, 3)
                s += __shfl_xor(s, 16); s2 += __shfl_xor(s2, 16);
                s += __shfl_xor(s, 32); s2 += __shfl_xor(s2, 32);
                float mu = s * (1.f / 49.f);
                float r = rsqrtf(s2 * (1.f / 49.f) - mu * mu + 1e-5f);
                float sc = r * g2wv, sh = g2bv - mu * sc;
                GN_STORE(hp2, a0, 0) GN_STORE(hp2, a1, 1)
                GN_STORE(hp2, a2, 2) GN_STORE(hp2, a3, 3)
            }
            __syncthreads();   // B2: hp2 complete (also: all hp1 reads done)

            // ---- conv2 + RK4 epilogue (all registers) ----
            {
                f32x4 a0, a1, a2, a3;
                CONV_MFMA(hp2, w2r)

                RK4_REG(a0, zr0, za0, ur0) RK4_REG(a1, zr1, za1, ur1)
                RK4_REG(a2, zr2, za2, ur2) RK4_REG(a3, zr3, za3, ur3)
                if (e == 3) {
                    zr0 = za0; zr1 = za1; zr2 = za2; zr3 = za3;
                    ur0 = zr0; ur1 = zr1; ur2 = zr2; ur3 = zr3;
                }
            }
            // no barrier needed: next GN1 writes hp1, whose readers finished
            // before B2; state flow is wave-private (registers).
        }
    }

    // ---- final GN(groups=32)+ReLU + mean-pool (registers) ----
    {
        float s = 0.f, s2 = 0.f;
        GN_ACCUM(zr0, 0) GN_ACCUM(zr1, 1) GN_ACCUM(zr2, 2) GN_ACCUM(zr3, 3)
        s += __shfl_xor(s, 16); s2 += __shfl_xor(s2, 16);
        s += __shfl_xor(s, 32); s2 += __shfl_xor(s2, 32);
        s += __shfl_xor(s, 1);  s2 += __shfl_xor(s2, 1);   // pair channels (G=32)
        float mu = s * (1.f / 98.f);
        float r = rsqrtf(s2 * (1.f / 98.f) - mu * mu + 1e-5f);
        float sc = r * fgw[co], sh = fgb[co] - mu * sc;
        float ps = 0.f;
#pragma unroll
        for (int mm = 0; mm < 4; mm++) {
            f32x4 zz = (mm == 0) ? zr0 : (mm == 1) ? zr1 : (mm == 2) ? zr2 : zr3;
#pragma unroll
            for (int j = 0; j < 4; j++) {
                int p_ = mm * 16 + q * 4 + j;
                if (PVALID(p_)) ps += fmaxf(zz[j] * sc + sh, 0.f);
            }
        }
        ps += __shfl_xor(ps, 16);
        ps += __shfl_xor(ps, 32);
        if (q == 0) pooled[co] = ps * (1.f / 49.f);
    }
    __syncthreads();
    if (t < 10) {
        float a = fcb[t];
#pragma unroll
        for (int k = 0; k < 64; k++) a += pooled[k] * fcw[t * 64 + k];
        out[(size_t)n * 10 + t] = a;
    }
}

static inline int nblk(long long total) { return (int)((total + TPB - 1) / TPB); }

extern "C" void kernel_launch(void* const* d_in, const int* in_sizes, int n_in,
                              void* d_out, int out_size, void* d_ws, size_t ws_size,
                              hipStream_t stream) {
    const float* x       = (const float*)d_in[0];
    const float* conv1_w = (const float*)d_in[1];
    const float* conv1_b = (const float*)d_in[2];
    const float* r1_g1w  = (const float*)d_in[3];
    const float* r1_g1b  = (const float*)d_in[4];
    const float* r1_c1w  = (const float*)d_in[5];
    const float* r1_g2w  = (const float*)d_in[6];
    const float* r1_g2b  = (const float*)d_in[7];
    const float* r1_c2w  = (const float*)d_in[8];
    const float* r1_dw   = (const float*)d_in[9];
    const float* r2_g1w  = (const float*)d_in[10];
    const float* r2_g1b  = (const float*)d_in[11];
    const float* r2_c1w  = (const float*)d_in[12];
    const float* r2_g2w  = (const float*)d_in[13];
    const float* r2_g2b  = (const float*)d_in[14];
    const float* r2_c2w  = (const float*)d_in[15];
    const float* r2_dw   = (const float*)d_in[16];
    const float* o_g1w   = (const float*)d_in[17];
    const float* o_g1b   = (const float*)d_in[18];
    const float* o_c1w   = (const float*)d_in[19];
    const float* o_g2w   = (const float*)d_in[20];
    const float* o_g2b   = (const float*)d_in[21];
    const float* o_c2w   = (const float*)d_in[22];
    const float* fin_gw  = (const float*)d_in[23];
    const float* fin_gb  = (const float*)d_in[24];
    const float* fc_w    = (const float*)d_in[25];
    const float* fc_b    = (const float*)d_in[26];
    float* out = (float*)d_out;

    const int N = 512;
    const long long SZ26 = 512LL * 64 * 26 * 26;
    const long long SZ13 = 512LL * 64 * 13 * 13;
    const long long SZ7  = 512LL * 64 * 7 * 7;
    const long long WTS  = 64 * 64 * 12;
    const long long WBS  = 9 * 2 * 4 * 64 * 8;     // 36864 ushorts per table

    float* B26   = (float*)d_ws;
    float* A13   = B26 + SZ26;
    float* B13   = A13 + SZ13;
    float* Z7    = B13 + SZ13;
    float* U7    = Z7 + SZ7;
    float* MEAN  = U7 + SZ7;
    float* RSTD  = MEAN + 512 * 64;
    float* WTr11 = RSTD + 512 * 64;
    float* WTr12 = WTr11 + WTS;
    float* WTr21 = WTr12 + WTS;
    float* WTr22 = WTr21 + WTS;
    unsigned short* WB1h = (unsigned short*)(WTr22 + WTS);
    unsigned short* WB2h = WB1h + WBS;

    auto gn = [&](const float* src, float* dst, int HW, int G,
                  const float* gw, const float* gb) {
        int waves = N * G;
        gn_stats_k<<<nblk((long long)waves * 64), TPB, 0, stream>>>(src, MEAN, RSTD, N, 64, HW, G);
        gn_apply_relu_k<<<nblk((long long)N * 64 * HW), TPB, 0, stream>>>(
            src, dst, MEAN, RSTD, gw, gb, N, 64, HW, G);
    };

    // ---- weight prep ----
    wprep_k<<<nblk(WTS), TPB, 0, stream>>>(r1_c1w, WTr11);
    wprep_k<<<nblk(WTS), TPB, 0, stream>>>(r1_c2w, WTr12);
    wprep_k<<<nblk(WTS), TPB, 0, stream>>>(r2_c1w, WTr21);
    wprep_k<<<nblk(WTS), TPB, 0, stream>>>(r2_c2w, WTr22);
    wsplit_k<<<nblk(WBS), TPB, 0, stream>>>(o_c1w, WB1h);
    wsplit_k<<<nblk(WBS), TPB, 0, stream>>>(o_c2w, WB2h);

    // ---- stage 0: conv1 ----
    conv1_k<<<nblk(SZ26), TPB, 0, stream>>>(x, conv1_w, conv1_b, B26);

    // ---- residual block 1: 26x26 -> 13x13 ----
    gn(B26, B26, 676, 32, r1_g1w, r1_g1b);
    conv_tile_k<2, true><<<512 * 4, 256, 0, stream>>>(B26, WTr11, r1_dw, nullptr,
                                                      A13, B13, 26, 26, 13, 13, 2, 2);
    gn(A13, A13, 169, 32, r1_g2w, r1_g2b);
    conv_tile_k<1, false><<<512 * 4, 256, 0, stream>>>(A13, WTr12, nullptr, B13,
                                                       B13, nullptr, 13, 13, 13, 13, 2, 2);

    // ---- residual block 2: 13x13 -> 7x7 ----
    gn(B13, B13, 169, 32, r2_g1w, r2_g1b);
    conv_tile_k<2, true><<<512, 256, 0, stream>>>(B13, WTr21, r2_dw, nullptr,
                                                  U7, Z7, 13, 13, 7, 7, 1, 1);
    gn(U7, U7, 49, 32, r2_g2w, r2_g2b);
    conv_tile_k<1, false><<<512, 256, 0, stream>>>(U7, WTr22, nullptr, Z7,
                                                   Z7, nullptr, 7, 7, 7, 7, 1, 1);

    // ---- fused MFMA ODE (12 RK4 steps) + final GN + pool + FC ----
    // 1 image per block: grid 512 x 256 threads; weights in registers
    ode_mfma_k<<<512, 256, 0, stream>>>(Z7, WB1h, WB2h,
                                        o_g1w, o_g1b, o_g2w, o_g2b,
                                        fin_gw, fin_gb, fc_w, fc_b, out);
}

// Round 12
// 972.444 us; speedup vs baseline: 2.3337x; 1.2158x over previous
//
#include <hip/hip_runtime.h>
#include <hip/hip_bf16.h>

#define TPB 256

typedef __attribute__((ext_vector_type(8))) short short8;
typedef __attribute__((ext_vector_type(4))) float f32x4;

__device__ __forceinline__ unsigned short f2bf(float x) {
    union { float f; unsigned int u; } c; c.f = x;
    unsigned int u = c.u;
    unsigned int r = (u + 0x7fffu + ((u >> 16) & 1u)) >> 16;
    return (unsigned short)r;
}

// ======================= small prologue kernels ==============================

__global__ void conv1_k(const float* __restrict__ x, const float* __restrict__ w,
                        const float* __restrict__ b, float* __restrict__ out) {
    int idx = blockIdx.x * TPB + threadIdx.x;
    const int total = 512 * 64 * 26 * 26;
    if (idx >= total) return;
    int ox = idx % 26; int t = idx / 26;
    int oy = t % 26;   t /= 26;
    int co = t % 64;   int n = t / 64;
    const float* xp = x + (size_t)n * 784 + oy * 28 + ox;
    const float* wp = w + co * 9;
    float s = b[co];
#pragma unroll
    for (int ky = 0; ky < 3; ky++)
#pragma unroll
        for (int kx = 0; kx < 3; kx++)
            s += xp[ky * 28 + kx] * wp[ky * 3 + kx];
    out[idx] = s;
}

__global__ void gn_stats_k(const float* __restrict__ x, float* __restrict__ mean,
                           float* __restrict__ rstd, int N, int C, int HW, int G) {
    int gid  = (blockIdx.x * blockDim.x + threadIdx.x) >> 6;
    int lane = threadIdx.x & 63;
    int total = N * G;
    if (gid >= total) return;
    int n = gid / G, g = gid % G;
    int cpg = C / G;
    int gsize = cpg * HW;
    const float* p = x + ((size_t)n * C + (size_t)g * cpg) * HW;
    float s = 0.f, s2 = 0.f;
    for (int i = lane; i < gsize; i += 64) { float v = p[i]; s += v; s2 += v * v; }
#pragma unroll
    for (int off = 32; off; off >>= 1) {
        s  += __shfl_down(s,  off);
        s2 += __shfl_down(s2, off);
    }
    if (lane == 0) {
        float m = s / gsize;
        float var = s2 / gsize - m * m;
        mean[gid] = m;
        rstd[gid] = rsqrtf(var + 1e-5f);
    }
}

__global__ void gn_apply_relu_k(const float* __restrict__ x, float* __restrict__ out,
                                const float* __restrict__ mean, const float* __restrict__ rstd,
                                const float* __restrict__ gw, const float* __restrict__ gb,
                                int N, int C, int HW, int G) {
    int idx = blockIdx.x * TPB + threadIdx.x;
    int total = N * C * HW;
    if (idx >= total) return;
    int c = (idx / HW) % C;
    int n = idx / (HW * C);
    int cpg = C / G;
    int g = c / cpg;
    float m = mean[n * G + g], r = rstd[n * G + g];
    float v = (x[idx] - m) * r * gw[c] + gb[c];
    out[idx] = v > 0.f ? v : 0.f;
}

// prologue weight transpose: w[co][ci][3][3] -> wT[wave][ci][col16][12]
__global__ void wprep_k(const float* __restrict__ w, float* __restrict__ wT) {
    int i = blockIdx.x * TPB + threadIdx.x;
    if (i >= 64 * 64 * 12) return;
    int k = i % 12; int r = i / 12;
    int col = r % 16; r /= 16;
    int ci = r % 64; int wave = r / 64;
    int co = wave * 16 + col;
    wT[i] = (k < 9) ? w[(co * 64 + ci) * 9 + k] : 0.f;
}

// bf16 B-frag table: layout [t:9][ks:2][nt:4][lane:64][8]
// lane holds B[k=ks*32+(l>>4)*8+j][co=nt*16+(l&15)]
__global__ void wsplit_k(const float* __restrict__ w, unsigned short* __restrict__ hiT) {
    int i = blockIdx.x * TPB + threadIdx.x;
    if (i >= 9 * 2 * 4 * 64 * 8) return;
    int j = i & 7, l = (i >> 3) & 63, nt = (i >> 9) & 3, ks = (i >> 11) & 1, t = i >> 12;
    int co = nt * 16 + (l & 15);
    int ci = ks * 32 + (l >> 4) * 8 + j;
    hiT[i] = f2bf(w[(co * 64 + ci) * 9 + t]);
}

// ======================= tiled 3x3 conv (stride-2 prologue) ==================

#define KC 2
#define WCHUNK (KC * 16 * 12)
#define WREGION (64 * 16 * 12)

template<int STRIDE, bool SKIP>
__global__ __launch_bounds__(256)
void conv_tile_k(const float* __restrict__ in, const float* __restrict__ wT,
                 const float* __restrict__ dw, const float* __restrict__ addend,
                 float* __restrict__ out, float* __restrict__ skipout,
                 int H, int W, int OH, int OW, int TX, int TY) {
    constexpr int IHT = 6 * STRIDE + 3;
    constexpr int IWT = 6 * STRIDE + 3;
    constexpr int IPITCH = (STRIDE == 1) ? 12 : 16;
    constexpr int RSPAN = 4 * STRIDE + 2;

    __shared__ float sin_[64 * IHT * IPITCH];
    __shared__ float wl[4 * WCHUNK];

    int b = blockIdx.x;
    int tx = b % TX; b /= TX;
    int ty = b % TY; int n = b / TY;
    int oy0 = ty * 7, ox0 = tx * 7;
    int iy0 = oy0 * STRIDE - 1, ix0 = ox0 * STRIDE - 1;

    const int t = threadIdx.x;
    const int wave = t >> 6, lane = t & 63;
    const int cb = t >> 4, cbl = cb & 3, slot = t & 15;
    const int row = slot >> 1, half = slot & 1;
    const int crow = (row < 7) ? row : 0;
    const int co0 = cb * 4;
    float* wlw = wl + wave * WCHUNK;

    const float* ip = in + (size_t)n * 64 * H * W;
    for (int i = t; i < 64 * IHT * IPITCH; i += 256) {
        int c = i % IPITCH; int r = (i / IPITCH) % IHT; int ch = i / (IPITCH * IHT);
        int gy = iy0 + r, gx = ix0 + c;
        float v = 0.f;
        if (c < IWT && (unsigned)gy < (unsigned)H && (unsigned)gx < (unsigned)W)
            v = ip[(size_t)ch * H * W + gy * W + gx];
        sin_[i] = v;
    }
    __syncthreads();

    const float* wg = wT + (size_t)wave * WREGION;
    float acc[4][4];
#pragma unroll
    for (int j = 0; j < 4; j++)
#pragma unroll
        for (int px = 0; px < 4; px++) acc[j][px] = 0.f;

    float2 s0, s1, s2v;
    {
        const float2* gp = (const float2*)wg + lane * 3;
        s0 = gp[0]; s1 = gp[1]; s2v = gp[2];
    }
    for (int ch = 0; ch < 64 / KC; ch++) {
        {
            float2* wp = (float2*)wlw + lane * 3;
            wp[0] = s0; wp[1] = s1; wp[2] = s2v;
        }
        if (ch < 64 / KC - 1) {
            const float2* gp = (const float2*)(wg + (ch + 1) * WCHUNK) + lane * 3;
            s0 = gp[0]; s1 = gp[1]; s2v = gp[2];
        }
        float wr[KC][4][9];
#pragma unroll
        for (int c2 = 0; c2 < KC; c2++)
#pragma unroll
            for (int j = 0; j < 4; j++) {
                const float* wp2 = wlw + (c2 * 16 + cbl * 4 + j) * 12;
                float4 wa = *(const float4*)wp2;
                float4 wb = *(const float4*)(wp2 + 4);
                wr[c2][j][0] = wa.x; wr[c2][j][1] = wa.y; wr[c2][j][2] = wa.z;
                wr[c2][j][3] = wa.w; wr[c2][j][4] = wb.x; wr[c2][j][5] = wb.y;
                wr[c2][j][6] = wb.z; wr[c2][j][7] = wb.w; wr[c2][j][8] = wp2[8];
            }
#pragma unroll
        for (int c2 = 0; c2 < KC; c2++) {
            const float* hc = sin_ + ((ch * KC + c2) * IHT + crow * STRIDE) * IPITCH
                            + half * 4 * STRIDE;
            float rr[3][RSPAN];
#pragma unroll
            for (int ky = 0; ky < 3; ky++) {
                const float* bp = hc + ky * IPITCH;
                if constexpr (STRIDE == 1) {
                    float4 a = *(const float4*)bp; float2 bb = *(const float2*)(bp + 4);
                    rr[ky][0] = a.x; rr[ky][1] = a.y; rr[ky][2] = a.z; rr[ky][3] = a.w;
                    rr[ky][4] = bb.x; rr[ky][5] = bb.y;
                } else {
                    float4 a = *(const float4*)bp; float4 bb = *(const float4*)(bp + 4);
                    float2 cc = *(const float2*)(bp + 8);
                    rr[ky][0] = a.x; rr[ky][1] = a.y; rr[ky][2] = a.z; rr[ky][3] = a.w;
                    rr[ky][4] = bb.x; rr[ky][5] = bb.y; rr[ky][6] = bb.z; rr[ky][7] = bb.w;
                    rr[ky][8] = cc.x; rr[ky][9] = cc.y;
                }
            }
#pragma unroll
            for (int j = 0; j < 4; j++)
#pragma unroll
                for (int px = 0; px < 4; px++) {
                    float s = acc[j][px];
#pragma unroll
                    for (int ky = 0; ky < 3; ky++) {
                        s = fmaf(rr[ky][px * STRIDE + 0], wr[c2][j][ky * 3 + 0], s);
                        s = fmaf(rr[ky][px * STRIDE + 1], wr[c2][j][ky * 3 + 1], s);
                        s = fmaf(rr[ky][px * STRIDE + 2], wr[c2][j][ky * 3 + 2], s);
                    }
                    acc[j][px] = s;
                }
        }
    }

    if constexpr (SKIP) {
        if (slot < 14) {
            float sk[4][4];
#pragma unroll
            for (int j = 0; j < 4; j++)
#pragma unroll
                for (int px = 0; px < 4; px++) sk[j][px] = 0.f;
            for (int ci = 0; ci < 64; ci++) {
                const float* sp = sin_ + (ci * IHT + 2 * row + 1) * IPITCH + half * 8 + 1;
                float xv[4];
#pragma unroll
                for (int px = 0; px < 4; px++) xv[px] = sp[px * 2];
#pragma unroll
                for (int j = 0; j < 4; j++) {
                    float wv = dw[(co0 + j) * 64 + ci];
#pragma unroll
                    for (int px = 0; px < 4; px++) sk[j][px] = fmaf(xv[px], wv, sk[j][px]);
                }
            }
#pragma unroll
            for (int j = 0; j < 4; j++)
#pragma unroll
                for (int px = 0; px < 4; px++) {
                    int oy = oy0 + row, ox = ox0 + half * 4 + px;
                    if (oy < OH && ox < OW && half * 4 + px < 7)
                        skipout[(((size_t)n * 64 + co0 + j) * OH + oy) * OW + ox] = sk[j][px];
                }
        }
    }

    if (slot < 14) {
#pragma unroll
        for (int j = 0; j < 4; j++)
#pragma unroll
            for (int px = 0; px < 4; px++) {
                int oy = oy0 + row, ox = ox0 + half * 4 + px;
                if (oy < OH && ox < OW && half * 4 + px < 7) {
                    size_t idx = (((size_t)n * 64 + co0 + j) * OH + oy) * OW + ox;
                    float v = acc[j][px];
                    if (addend) v += addend[idx];
                    out[idx] = v;
                }
            }
    }
}

// ======================= 13x13 MFMA conv (r1_c2) =============================
// Block = image, 4 waves (nt = 16-co slice). Plane: 13x13 + halo, pitch 16,
// 256 slots x 72 ush = 36.9 KB. 11 m-tiles of 16 px. Weights bf16 hi-only,
// register-preloaded (18 short8). In-place io[p] += conv.

__global__ __launch_bounds__(256, 2)
void conv13_mfma_k(const float* __restrict__ in, const unsigned short* __restrict__ bhT,
                   float* __restrict__ io) {
    __shared__ unsigned short hp[256 * 72];
    const int t = threadIdx.x;
    const int n = blockIdx.x;
    const int lane = t & 63;
    const int nt = t >> 6;
    const int colL = lane & 15, q = lane >> 4;
    const int co = nt * 16 + colL;
    const int kq0 = q * 8;

    short8 wr[18];
#pragma unroll
    for (int i = 0; i < 18; i++) wr[i] = ((const short8*)bhT)[(i * 4 + nt) * 64 + lane];

    for (int i = t; i < 256 * 72 / 2; i += 256) ((unsigned int*)hp)[i] = 0u;
    __syncthreads();
    const float* ip = in + (size_t)n * 64 * 169;
    for (int i = t; i < 64 * 169; i += 256) {
        int ch = i / 169, p = i - ch * 169;
        int y = p / 13, x = p - y * 13;
        hp[((y + 1) * 16 + (x + 1)) * 72 + ch] = f2bf(ip[i]);
    }
    __syncthreads();

    int hb[11];
#pragma unroll
    for (int m = 0; m < 11; m++) {
        int p = m * 16 + colL;
        int y = p / 13, x = p - y * 13;
        hb[m] = (y + 1) * 16 + (x + 1);     // invalid p>=169 -> bottom halo rows (zero)
    }
    f32x4 acc[11];
#pragma unroll
    for (int m = 0; m < 11; m++) acc[m] = (f32x4){0.f, 0.f, 0.f, 0.f};

#pragma unroll
    for (int t9 = 0; t9 < 9; t9++) {
        const int toff = (t9 / 3) * 16 + (t9 % 3) - 17;   // (dy)*16 + dx
#pragma unroll
        for (int ks = 0; ks < 2; ks++) {
            short8 vb = wr[t9 * 2 + ks];
            int kq = ks * 32 + kq0;
#pragma unroll
            for (int m = 0; m < 11; m++) {
                short8 a_ = *(const short8*)(hp + (hb[m] + toff) * 72 + kq);
                acc[m] = __builtin_amdgcn_mfma_f32_16x16x32_bf16(a_, vb, acc[m], 0, 0, 0);
            }
        }
    }

    float* op = io + (size_t)n * 64 * 169 + (size_t)co * 169;
#pragma unroll
    for (int m = 0; m < 11; m++) {
        int p0 = m * 16 + q * 4;
#pragma unroll
        for (int j = 0; j < 4; j++) {
            int p = p0 + j;
            if (p < 169) op[p] += acc[m][j];
        }
    }
}

// ======================= ODE MFMA mega-kernel ================================
// R12: r2_c2 conv FOLDED into init (staged U7 -> plane -> streamed-weight conv
// -> + Z7 skip -> z regs). RK4 loop unchanged from R11 (conflict-free plane,
// register weights/state, 2 barriers/eval).

#define HP_PITCH 72              // ushorts per pixel-slot (144 B)
#define HP_PLANE (100 * HP_PITCH)

#define PVALID(p) ((((p) & 7) < 7) && (((p) >> 3) < 7))
#define PSLOT(p)  (((((p) >> 3) + 1) * 10) + (((p) & 7) + 1))

// one tap-GEMM for one m-tile accumulator
#define CONV_TAP(areg, hbase)                                                   \
    {                                                                           \
        short8 a_ = *(const short8*)(hp + ((hbase) + toff) * HP_PITCH + kq);    \
        areg = __builtin_amdgcn_mfma_f32_16x16x32_bf16(a_, vb, areg, 0, 0, 0);  \
    }

// conv from register weights
#define CONV_MFMA(hpsrc, wreg)                                                  \
    a0 = (f32x4){0.f, 0.f, 0.f, 0.f}; a1 = a0; a2 = a0; a3 = a0;                \
    {                                                                           \
        const unsigned short* hp = (hpsrc);                                     \
        _Pragma("unroll")                                                       \
        for (int t9 = 0; t9 < 9; t9++) {                                        \
            const int toff = (t9 / 3) * 10 + (t9 % 3) - 11;                     \
            _Pragma("unroll")                                                   \
            for (int ks = 0; ks < 2; ks++) {                                    \
                short8 vb = wreg[t9 * 2 + ks];                                  \
                int kq = ks * 32 + kq0;                                         \
                CONV_TAP(a0, h0)                                                \
                CONV_TAP(a1, h1)                                                \
                CONV_TAP(a2, h2)                                                \
                CONV_TAP(a3, h3)                                                \
            }                                                                   \
        }                                                                       \
    }

// conv from streamed (global) weights — used once for the folded r2_c2
#define CONV_MFMA_G(hpsrc, bhT)                                                 \
    a0 = (f32x4){0.f, 0.f, 0.f, 0.f}; a1 = a0; a2 = a0; a3 = a0;                \
    {                                                                           \
        const unsigned short* hp = (hpsrc);                                     \
        const short8* bh_ = (const short8*)(bhT);                               \
        _Pragma("unroll")                                                       \
        for (int t9 = 0; t9 < 9; t9++) {                                        \
            const int toff = (t9 / 3) * 10 + (t9 % 3) - 11;                     \
            _Pragma("unroll")                                                   \
            for (int ks = 0; ks < 2; ks++) {                                    \
                short8 vb = bh_[((t9 * 2 + ks) * 4 + nt) * 64 + lane];          \
                int kq = ks * 32 + kq0;                                         \
                CONV_TAP(a0, h0)                                                \
                CONV_TAP(a1, h1)                                                \
                CONV_TAP(a2, h2)                                                \
                CONV_TAP(a3, h3)                                                \
            }                                                                   \
        }                                                                       \
    }

#define GN_ACCUM(areg, mm)                                                      \
    _Pragma("unroll")                                                           \
    for (int j = 0; j < 4; j++) {                                               \
        int p_ = (mm) * 16 + q * 4 + j;                                         \
        if (PVALID(p_)) { float x_ = areg[j]; s += x_; s2 += x_ * x_; }         \
    }

#define GN_STORE(dst, areg, mm)                                                 \
    _Pragma("unroll")                                                           \
    for (int j = 0; j < 4; j++) {                                               \
        int p_ = (mm) * 16 + q * 4 + j;                                         \
        if (PVALID(p_)) {                                                       \
            float y_ = fmaxf(areg[j] * sc + sh, 0.f);                           \
            (dst)[PSLOT(p_) * HP_PITCH + co] = f2bf(y_);                        \
        }                                                                       \
    }

#define RK4_REG(areg, zm, zam, um)                                              \
    {                                                                           \
        f32x4 kv = areg + um;                                                   \
        zam = (e == 0) ? (zm + ck * kv) : (zam + ck * kv);                      \
        if (e < 3) um = zm + cu * kv;                                           \
    }

__global__ __launch_bounds__(256, 2)
void ode_mfma_k(const float* __restrict__ u7, const float* __restrict__ z7,
                const unsigned short* __restrict__ wr2h,
                const unsigned short* __restrict__ wb1h,
                const unsigned short* __restrict__ wb2h,
                const float* __restrict__ g1w, const float* __restrict__ g1b,
                const float* __restrict__ g2w, const float* __restrict__ g2b,
                const float* __restrict__ fgw, const float* __restrict__ fgb,
                const float* __restrict__ fcw, const float* __restrict__ fcb,
                float* __restrict__ out) {
    __shared__ unsigned short hp1[HP_PLANE], hp2[HP_PLANE];
    __shared__ float pooled[64];

    const int t = threadIdx.x;
    const int n = blockIdx.x;
    const int lane = t & 63;
    const int nt = t >> 6;
    const int colL = lane & 15, q = lane >> 4;
    const int co = nt * 16 + colL;

    const float g1wv = g1w[co], g1bv = g1b[co];
    const float g2wv = g2w[co], g2bv = g2b[co];

    const int h0 = PSLOT(colL);
    const int h1 = PSLOT(16 + colL);
    const int h2 = PSLOT(32 + colL);
    const int h3 = PSLOT(48 + colL);
    const int kq0 = q * 8;

    // ---- preload RK4 conv weights into registers ----
    short8 w1r[18], w2r[18];
#pragma unroll
    for (int i = 0; i < 18; i++) {
        int fidx = (i * 4 + nt) * 64 + lane;
        w1r[i] = ((const short8*)wb1h)[fidx];
        w2r[i] = ((const short8*)wb2h)[fidx];
    }

    // ---- init LDS planes ----
    for (int i = t; i < HP_PLANE; i += 256) { hp1[i] = 0; hp2[i] = 0; }
    __syncthreads();

    // ---- stage U7 (post-GN, fp32) -> hp1 bf16 ----
    {
        const float* up = u7 + (size_t)n * 3136;
        for (int i = t; i < 3136; i += 256) {
            int ch = i / 49, r = i - ch * 49;
            int y = r / 7, x = r - y * 7;
            hp1[((y + 1) * 10 + (x + 1)) * HP_PITCH + ch] = f2bf(up[i]);
        }
    }
    __syncthreads();

    // ---- folded r2_c2 conv + Z7 skip -> register state ----
    f32x4 zr0, zr1, zr2, zr3;
    f32x4 za0, za1, za2, za3;
    f32x4 ur0, ur1, ur2, ur3;
    {
        f32x4 a0, a1, a2, a3;
        CONV_MFMA_G(hp1, wr2h)
        const float* zb = z7 + (size_t)n * 3136 + (size_t)co * 49;
#define INITZ(zm, areg, mm)                                                     \
        _Pragma("unroll")                                                       \
        for (int j = 0; j < 4; j++) {                                           \
            int p_ = (mm) * 16 + q * 4 + j;                                     \
            zm[j] = PVALID(p_) ? (areg[j] + zb[(p_ >> 3) * 7 + (p_ & 7)]) : 0.f;\
        }
        INITZ(zr0, a0, 0) INITZ(zr1, a1, 1) INITZ(zr2, a2, 2) INITZ(zr3, a3, 3)
#undef INITZ
    }
    ur0 = zr0; ur1 = zr1; ur2 = zr2; ur3 = zr3;
    __syncthreads();   // hp1 init-conv reads done before loop's GN1 writes

    const float dt = 0.5f;

#pragma unroll 1
    for (int step = 0; step < 12; step++) {
#pragma unroll 1
        for (int e = 0; e < 4; e++) {
            const float ck = (e == 0 || e == 3) ? dt / 6.f : dt / 3.f;
            const float cu = (e == 2) ? dt : 0.5f * dt;

            // ---- GN1(groups=64)+ReLU on u (registers) -> hp1 ----
            {
                float s = 0.f, s2 = 0.f;
                GN_ACCUM(ur0, 0) GN_ACCUM(ur1, 1) GN_ACCUM(ur2, 2) GN_ACCUM(ur3, 3)
                s += __shfl_xor(s, 16); s2 += __shfl_xor(s2, 16);
                s += __shfl_xor(s, 32); s2 += __shfl_xor(s2, 32);
                float mu = s * (1.f / 49.f);
                float r = rsqrtf(s2 * (1.f / 49.f) - mu * mu + 1e-5f);
                float sc = r * g1wv, sh = g1bv - mu * sc;
                GN_STORE(hp1, ur0, 0) GN_STORE(hp1, ur1, 1)
                GN_STORE(hp1, ur2, 2) GN_STORE(hp1, ur3, 3)
            }
            __syncthreads();   // B1

            // ---- conv1 + in-register GN2(groups=64)+ReLU -> hp2 ----
            {
                f32x4 a0, a1, a2, a3;
                CONV_MFMA(hp1, w1r)

                float s = 0.f, s2 = 0.f;
                GN_ACCUM(a0, 0) GN_ACCUM(a1, 1) GN_ACCUM(a2, 2) GN_ACCUM(a3, 3)
                s += __shfl_xor(s, 16); s2 += __shfl_xor(s2, 16);
                s += __shfl_xor(s, 32); s2 += __shfl_xor(s2, 32);
                float mu = s * (1.f / 49.f);
                float r = rsqrtf(s2 * (1.f / 49.f) - mu * mu + 1e-5f);
                float sc = r * g2wv, sh = g2bv - mu * sc;
                GN_STORE(hp2, a0, 0) GN_STORE(hp2, a1, 1)
                GN_STORE(hp2, a2, 2) GN_STORE(hp2, a3, 3)
            }
            __syncthreads();   // B2

            // ---- conv2 + RK4 epilogue (registers) ----
            {
                f32x4 a0, a1, a2, a3;
                CONV_MFMA(hp2, w2r)

                RK4_REG(a0, zr0, za0, ur0) RK4_REG(a1, zr1, za1, ur1)
                RK4_REG(a2, zr2, za2, ur2) RK4_REG(a3, zr3, za3, ur3)
                if (e == 3) {
                    zr0 = za0; zr1 = za1; zr2 = za2; zr3 = za3;
                    ur0 = zr0; ur1 = zr1; ur2 = zr2; ur3 = zr3;
                }
            }
        }
    }

    // ---- final GN(groups=32)+ReLU + mean-pool ----
    {
        float s = 0.f, s2 = 0.f;
        GN_ACCUM(zr0, 0) GN_ACCUM(zr1, 1) GN_ACCUM(zr2, 2) GN_ACCUM(zr3, 3)
        s += __shfl_xor(s, 16); s2 += __shfl_xor(s2, 16);
        s += __shfl_xor(s, 32); s2 += __shfl_xor(s2, 32);
        s += __shfl_xor(s, 1);  s2 += __shfl_xor(s2, 1);
        float mu = s * (1.f / 98.f);
        float r = rsqrtf(s2 * (1.f / 98.f) - mu * mu + 1e-5f);
        float sc = r * fgw[co], sh = fgb[co] - mu * sc;
        float ps = 0.f;
#pragma unroll
        for (int mm = 0; mm < 4; mm++) {
            f32x4 zz = (mm == 0) ? zr0 : (mm == 1) ? zr1 : (mm == 2) ? zr2 : zr3;
#pragma unroll
            for (int j = 0; j < 4; j++) {
                int p_ = mm * 16 + q * 4 + j;
                if (PVALID(p_)) ps += fmaxf(zz[j] * sc + sh, 0.f);
            }
        }
        ps += __shfl_xor(ps, 16);
        ps += __shfl_xor(ps, 32);
        if (q == 0) pooled[co] = ps * (1.f / 49.f);
    }
    __syncthreads();
    if (t < 10) {
        float a = fcb[t];
#pragma unroll
        for (int k = 0; k < 64; k++) a += pooled[k] * fcw[t * 64 + k];
        out[(size_t)n * 10 + t] = a;
    }
}

static inline int nblk(long long total) { return (int)((total + TPB - 1) / TPB); }

extern "C" void kernel_launch(void* const* d_in, const int* in_sizes, int n_in,
                              void* d_out, int out_size, void* d_ws, size_t ws_size,
                              hipStream_t stream) {
    const float* x       = (const float*)d_in[0];
    const float* conv1_w = (const float*)d_in[1];
    const float* conv1_b = (const float*)d_in[2];
    const float* r1_g1w  = (const float*)d_in[3];
    const float* r1_g1b  = (const float*)d_in[4];
    const float* r1_c1w  = (const float*)d_in[5];
    const float* r1_g2w  = (const float*)d_in[6];
    const float* r1_g2b  = (const float*)d_in[7];
    const float* r1_c2w  = (const float*)d_in[8];
    const float* r1_dw   = (const float*)d_in[9];
    const float* r2_g1w  = (const float*)d_in[10];
    const float* r2_g1b  = (const float*)d_in[11];
    const float* r2_c1w  = (const float*)d_in[12];
    const float* r2_g2w  = (const float*)d_in[13];
    const float* r2_g2b  = (const float*)d_in[14];
    const float* r2_c2w  = (const float*)d_in[15];
    const float* r2_dw   = (const float*)d_in[16];
    const float* o_g1w   = (const float*)d_in[17];
    const float* o_g1b   = (const float*)d_in[18];
    const float* o_c1w   = (const float*)d_in[19];
    const float* o_g2w   = (const float*)d_in[20];
    const float* o_g2b   = (const float*)d_in[21];
    const float* o_c2w   = (const float*)d_in[22];
    const float* fin_gw  = (const float*)d_in[23];
    const float* fin_gb  = (const float*)d_in[24];
    const float* fc_w    = (const float*)d_in[25];
    const float* fc_b    = (const float*)d_in[26];
    float* out = (float*)d_out;

    const int N = 512;
    const long long SZ26 = 512LL * 64 * 26 * 26;
    const long long SZ13 = 512LL * 64 * 13 * 13;
    const long long SZ7  = 512LL * 64 * 7 * 7;
    const long long WTS  = 64 * 64 * 12;
    const long long WBS  = 9 * 2 * 4 * 64 * 8;     // 36864 ushorts per table

    float* B26   = (float*)d_ws;
    float* A13   = B26 + SZ26;
    float* B13   = A13 + SZ13;
    float* Z7    = B13 + SZ13;
    float* U7    = Z7 + SZ7;
    float* MEAN  = U7 + SZ7;
    float* RSTD  = MEAN + 512 * 64;
    float* WTr11 = RSTD + 512 * 64;
    float* WTr21 = WTr11 + WTS;
    unsigned short* WB1h  = (unsigned short*)(WTr21 + WTS);
    unsigned short* WB2h  = WB1h + WBS;
    unsigned short* WB13h = WB2h + WBS;
    unsigned short* WR2h  = WB13h + WBS;

    auto gn = [&](const float* src, float* dst, int HW, int G,
                  const float* gw, const float* gb) {
        int waves = N * G;
        gn_stats_k<<<nblk((long long)waves * 64), TPB, 0, stream>>>(src, MEAN, RSTD, N, 64, HW, G);
        gn_apply_relu_k<<<nblk((long long)N * 64 * HW), TPB, 0, stream>>>(
            src, dst, MEAN, RSTD, gw, gb, N, 64, HW, G);
    };

    // ---- weight prep ----
    wprep_k<<<nblk(WTS), TPB, 0, stream>>>(r1_c1w, WTr11);
    wprep_k<<<nblk(WTS), TPB, 0, stream>>>(r2_c1w, WTr21);
    wsplit_k<<<nblk(WBS), TPB, 0, stream>>>(o_c1w, WB1h);
    wsplit_k<<<nblk(WBS), TPB, 0, stream>>>(o_c2w, WB2h);
    wsplit_k<<<nblk(WBS), TPB, 0, stream>>>(r1_c2w, WB13h);
    wsplit_k<<<nblk(WBS), TPB, 0, stream>>>(r2_c2w, WR2h);

    // ---- stage 0: conv1 ----
    conv1_k<<<nblk(SZ26), TPB, 0, stream>>>(x, conv1_w, conv1_b, B26);

    // ---- residual block 1: 26x26 -> 13x13 ----
    gn(B26, B26, 676, 32, r1_g1w, r1_g1b);
    conv_tile_k<2, true><<<512 * 4, 256, 0, stream>>>(B26, WTr11, r1_dw, nullptr,
                                                      A13, B13, 26, 26, 13, 13, 2, 2);
    gn(A13, A13, 169, 32, r1_g2w, r1_g2b);
    conv13_mfma_k<<<512, 256, 0, stream>>>(A13, WB13h, B13);   // B13 += conv(A13)

    // ---- residual block 2: 13x13 -> 7x7 (r2_c2 folded into ODE kernel) ----
    gn(B13, B13, 169, 32, r2_g1w, r2_g1b);
    conv_tile_k<2, true><<<512, 256, 0, stream>>>(B13, WTr21, r2_dw, nullptr,
                                                  U7, Z7, 13, 13, 7, 7, 1, 1);
    gn(U7, U7, 49, 32, r2_g2w, r2_g2b);

    // ---- fused: r2_c2 conv + skip + ODE RK4 + final GN + pool + FC ----
    ode_mfma_k<<<512, 256, 0, stream>>>(U7, Z7, WR2h, WB1h, WB2h,
                                        o_g1w, o_g1b, o_g2w, o_g2b,
                                        fin_gw, fin_gb, fc_w, fc_b, out);
}

// Round 13
// 872.024 us; speedup vs baseline: 2.6024x; 1.1152x over previous
//
#include <hip/hip_runtime.h>
#include <hip/hip_bf16.h>

#define TPB 256

typedef __attribute__((ext_vector_type(8))) short short8;
typedef __attribute__((ext_vector_type(4))) float f32x4;

__device__ __forceinline__ unsigned short f2bf(float x) {
    union { float f; unsigned int u; } c; c.f = x;
    unsigned int u = c.u;
    unsigned int r = (u + 0x7fffu + ((u >> 16) & 1u)) >> 16;
    return (unsigned short)r;
}

// ======================= small prologue kernels ==============================

__global__ void conv1_k(const float* __restrict__ x, const float* __restrict__ w,
                        const float* __restrict__ b, float* __restrict__ out) {
    int idx = blockIdx.x * TPB + threadIdx.x;
    const int total = 512 * 64 * 26 * 26;
    if (idx >= total) return;
    int ox = idx % 26; int t = idx / 26;
    int oy = t % 26;   t /= 26;
    int co = t % 64;   int n = t / 64;
    const float* xp = x + (size_t)n * 784 + oy * 28 + ox;
    const float* wp = w + co * 9;
    float s = b[co];
#pragma unroll
    for (int ky = 0; ky < 3; ky++)
#pragma unroll
        for (int kx = 0; kx < 3; kx++)
            s += xp[ky * 28 + kx] * wp[ky * 3 + kx];
    out[idx] = s;
}

__global__ void gn_stats_k(const float* __restrict__ x, float* __restrict__ mean,
                           float* __restrict__ rstd, int N, int C, int HW, int G) {
    int gid  = (blockIdx.x * blockDim.x + threadIdx.x) >> 6;
    int lane = threadIdx.x & 63;
    int total = N * G;
    if (gid >= total) return;
    int n = gid / G, g = gid % G;
    int cpg = C / G;
    int gsize = cpg * HW;
    const float* p = x + ((size_t)n * C + (size_t)g * cpg) * HW;
    float s = 0.f, s2 = 0.f;
    for (int i = lane; i < gsize; i += 64) { float v = p[i]; s += v; s2 += v * v; }
#pragma unroll
    for (int off = 32; off; off >>= 1) {
        s  += __shfl_down(s,  off);
        s2 += __shfl_down(s2, off);
    }
    if (lane == 0) {
        float m = s / gsize;
        float var = s2 / gsize - m * m;
        mean[gid] = m;
        rstd[gid] = rsqrtf(var + 1e-5f);
    }
}

// prologue weight transpose: w[co][ci][3][3] -> wT[wave][ci][col16][12]
__global__ void wprep_k(const float* __restrict__ w, float* __restrict__ wT) {
    int i = blockIdx.x * TPB + threadIdx.x;
    if (i >= 64 * 64 * 12) return;
    int k = i % 12; int r = i / 12;
    int col = r % 16; r /= 16;
    int ci = r % 64; int wave = r / 64;
    int co = wave * 16 + col;
    wT[i] = (k < 9) ? w[(co * 64 + ci) * 9 + k] : 0.f;
}

// bf16 B-frag table: layout [t:9][ks:2][nt:4][lane:64][8]
__global__ void wsplit_k(const float* __restrict__ w, unsigned short* __restrict__ hiT) {
    int i = blockIdx.x * TPB + threadIdx.x;
    if (i >= 9 * 2 * 4 * 64 * 8) return;
    int j = i & 7, l = (i >> 3) & 63, nt = (i >> 9) & 3, ks = (i >> 11) & 1, t = i >> 12;
    int co = nt * 16 + (l & 15);
    int ci = ks * 32 + (l >> 4) * 8 + j;
    hiT[i] = f2bf(w[(co * 64 + ci) * 9 + t]);
}

// ======================= tiled 3x3 conv (stride-2, GN fused in staging) ======

#define KC 2
#define WCHUNK (KC * 16 * 12)
#define WREGION (64 * 16 * 12)

template<int STRIDE, bool SKIP>
__global__ __launch_bounds__(256)
void conv_tile_k(const float* __restrict__ in, const float* __restrict__ wT,
                 const float* __restrict__ dw, const float* __restrict__ addend,
                 float* __restrict__ out, float* __restrict__ skipout,
                 const float* __restrict__ mean, const float* __restrict__ rstd,
                 const float* __restrict__ gnw, const float* __restrict__ gnb,
                 int H, int W, int OH, int OW, int TX, int TY) {
    constexpr int IHT = 6 * STRIDE + 3;
    constexpr int IWT = 6 * STRIDE + 3;
    constexpr int IPITCH = (STRIDE == 1) ? 12 : 16;
    constexpr int RSPAN = 4 * STRIDE + 2;

    __shared__ float sin_[64 * IHT * IPITCH];
    __shared__ float wl[4 * WCHUNK];

    int b = blockIdx.x;
    int tx = b % TX; b /= TX;
    int ty = b % TY; int n = b / TY;
    int oy0 = ty * 7, ox0 = tx * 7;
    int iy0 = oy0 * STRIDE - 1, ix0 = ox0 * STRIDE - 1;

    const int t = threadIdx.x;
    const int wave = t >> 6, lane = t & 63;
    const int cb = t >> 4, cbl = cb & 3, slot = t & 15;
    const int row = slot >> 1, half = slot & 1;
    const int crow = (row < 7) ? row : 0;
    const int co0 = cb * 4;
    float* wlw = wl + wave * WCHUNK;

    // ---- stage input tile with fused GN(affine from stats)+ReLU ----
    const float* ip = in + (size_t)n * 64 * H * W;
    for (int i = t; i < 64 * IHT * IPITCH; i += 256) {
        int c = i % IPITCH; int r = (i / IPITCH) % IHT; int ch = i / (IPITCH * IHT);
        int gy = iy0 + r, gx = ix0 + c;
        float v = 0.f;
        if (c < IWT && (unsigned)gy < (unsigned)H && (unsigned)gx < (unsigned)W) {
            float m = mean[n * 32 + (ch >> 1)], rs = rstd[n * 32 + (ch >> 1)];
            float raw = ip[(size_t)ch * H * W + gy * W + gx];
            v = fmaxf((raw - m) * rs * gnw[ch] + gnb[ch], 0.f);
        }
        sin_[i] = v;
    }
    __syncthreads();

    const float* wg = wT + (size_t)wave * WREGION;
    float acc[4][4];
#pragma unroll
    for (int j = 0; j < 4; j++)
#pragma unroll
        for (int px = 0; px < 4; px++) acc[j][px] = 0.f;

    float2 s0, s1, s2v;
    {
        const float2* gp = (const float2*)wg + lane * 3;
        s0 = gp[0]; s1 = gp[1]; s2v = gp[2];
    }
    for (int ch = 0; ch < 64 / KC; ch++) {
        {
            float2* wp = (float2*)wlw + lane * 3;
            wp[0] = s0; wp[1] = s1; wp[2] = s2v;
        }
        if (ch < 64 / KC - 1) {
            const float2* gp = (const float2*)(wg + (ch + 1) * WCHUNK) + lane * 3;
            s0 = gp[0]; s1 = gp[1]; s2v = gp[2];
        }
        float wr[KC][4][9];
#pragma unroll
        for (int c2 = 0; c2 < KC; c2++)
#pragma unroll
            for (int j = 0; j < 4; j++) {
                const float* wp2 = wlw + (c2 * 16 + cbl * 4 + j) * 12;
                float4 wa = *(const float4*)wp2;
                float4 wb = *(const float4*)(wp2 + 4);
                wr[c2][j][0] = wa.x; wr[c2][j][1] = wa.y; wr[c2][j][2] = wa.z;
                wr[c2][j][3] = wa.w; wr[c2][j][4] = wb.x; wr[c2][j][5] = wb.y;
                wr[c2][j][6] = wb.z; wr[c2][j][7] = wb.w; wr[c2][j][8] = wp2[8];
            }
#pragma unroll
        for (int c2 = 0; c2 < KC; c2++) {
            const float* hc = sin_ + ((ch * KC + c2) * IHT + crow * STRIDE) * IPITCH
                            + half * 4 * STRIDE;
            float rr[3][RSPAN];
#pragma unroll
            for (int ky = 0; ky < 3; ky++) {
                const float* bp = hc + ky * IPITCH;
                if constexpr (STRIDE == 1) {
                    float4 a = *(const float4*)bp; float2 bb = *(const float2*)(bp + 4);
                    rr[ky][0] = a.x; rr[ky][1] = a.y; rr[ky][2] = a.z; rr[ky][3] = a.w;
                    rr[ky][4] = bb.x; rr[ky][5] = bb.y;
                } else {
                    float4 a = *(const float4*)bp; float4 bb = *(const float4*)(bp + 4);
                    float2 cc = *(const float2*)(bp + 8);
                    rr[ky][0] = a.x; rr[ky][1] = a.y; rr[ky][2] = a.z; rr[ky][3] = a.w;
                    rr[ky][4] = bb.x; rr[ky][5] = bb.y; rr[ky][6] = bb.z; rr[ky][7] = bb.w;
                    rr[ky][8] = cc.x; rr[ky][9] = cc.y;
                }
            }
#pragma unroll
            for (int j = 0; j < 4; j++)
#pragma unroll
                for (int px = 0; px < 4; px++) {
                    float s = acc[j][px];
#pragma unroll
                    for (int ky = 0; ky < 3; ky++) {
                        s = fmaf(rr[ky][px * STRIDE + 0], wr[c2][j][ky * 3 + 0], s);
                        s = fmaf(rr[ky][px * STRIDE + 1], wr[c2][j][ky * 3 + 1], s);
                        s = fmaf(rr[ky][px * STRIDE + 2], wr[c2][j][ky * 3 + 2], s);
                    }
                    acc[j][px] = s;
                }
        }
    }

    if constexpr (SKIP) {
        if (slot < 14) {
            float sk[4][4];
#pragma unroll
            for (int j = 0; j < 4; j++)
#pragma unroll
                for (int px = 0; px < 4; px++) sk[j][px] = 0.f;
            for (int ci = 0; ci < 64; ci++) {
                const float* sp = sin_ + (ci * IHT + 2 * row + 1) * IPITCH + half * 8 + 1;
                float xv[4];
#pragma unroll
                for (int px = 0; px < 4; px++) xv[px] = sp[px * 2];
#pragma unroll
                for (int j = 0; j < 4; j++) {
                    float wv = dw[(co0 + j) * 64 + ci];
#pragma unroll
                    for (int px = 0; px < 4; px++) sk[j][px] = fmaf(xv[px], wv, sk[j][px]);
                }
            }
#pragma unroll
            for (int j = 0; j < 4; j++)
#pragma unroll
                for (int px = 0; px < 4; px++) {
                    int oy = oy0 + row, ox = ox0 + half * 4 + px;
                    if (oy < OH && ox < OW && half * 4 + px < 7)
                        skipout[(((size_t)n * 64 + co0 + j) * OH + oy) * OW + ox] = sk[j][px];
                }
        }
    }

    if (slot < 14) {
#pragma unroll
        for (int j = 0; j < 4; j++)
#pragma unroll
            for (int px = 0; px < 4; px++) {
                int oy = oy0 + row, ox = ox0 + half * 4 + px;
                if (oy < OH && ox < OW && half * 4 + px < 7) {
                    size_t idx = (((size_t)n * 64 + co0 + j) * OH + oy) * OW + ox;
                    float v = acc[j][px];
                    if (addend) v += addend[idx];
                    out[idx] = v;
                }
            }
    }
}

// ======================= 13x13 MFMA conv (r1_c2, GN fused) ===================

__global__ __launch_bounds__(256, 2)
void conv13_mfma_k(const float* __restrict__ in, const unsigned short* __restrict__ bhT,
                   float* __restrict__ io,
                   const float* __restrict__ mean, const float* __restrict__ rstd,
                   const float* __restrict__ gnw, const float* __restrict__ gnb) {
    __shared__ unsigned short hp[256 * 72];
    const int t = threadIdx.x;
    const int n = blockIdx.x;
    const int lane = t & 63;
    const int nt = t >> 6;
    const int colL = lane & 15, q = lane >> 4;
    const int co = nt * 16 + colL;
    const int kq0 = q * 8;

    short8 wr[18];
#pragma unroll
    for (int i = 0; i < 18; i++) wr[i] = ((const short8*)bhT)[(i * 4 + nt) * 64 + lane];

    for (int i = t; i < 256 * 72 / 2; i += 256) ((unsigned int*)hp)[i] = 0u;
    __syncthreads();
    const float* ip = in + (size_t)n * 64 * 169;
    for (int i = t; i < 64 * 169; i += 256) {
        int ch = i / 169, p = i - ch * 169;
        int y = p / 13, x = p - y * 13;
        float m = mean[n * 32 + (ch >> 1)], rs = rstd[n * 32 + (ch >> 1)];
        float v = fmaxf((ip[i] - m) * rs * gnw[ch] + gnb[ch], 0.f);
        hp[((y + 1) * 16 + (x + 1)) * 72 + ch] = f2bf(v);
    }
    __syncthreads();

    int hb[11];
#pragma unroll
    for (int m = 0; m < 11; m++) {
        int p = m * 16 + colL;
        int y = p / 13, x = p - y * 13;
        hb[m] = (y + 1) * 16 + (x + 1);
    }
    f32x4 acc[11];
#pragma unroll
    for (int m = 0; m < 11; m++) acc[m] = (f32x4){0.f, 0.f, 0.f, 0.f};

#pragma unroll
    for (int t9 = 0; t9 < 9; t9++) {
        const int toff = (t9 / 3) * 16 + (t9 % 3) - 17;
#pragma unroll
        for (int ks = 0; ks < 2; ks++) {
            short8 vb = wr[t9 * 2 + ks];
            int kq = ks * 32 + kq0;
#pragma unroll
            for (int m = 0; m < 11; m++) {
                short8 a_ = *(const short8*)(hp + (hb[m] + toff) * 72 + kq);
                acc[m] = __builtin_amdgcn_mfma_f32_16x16x32_bf16(a_, vb, acc[m], 0, 0, 0);
            }
        }
    }

    float* op = io + (size_t)n * 64 * 169 + (size_t)co * 169;
#pragma unroll
    for (int m = 0; m < 11; m++) {
        int p0 = m * 16 + q * 4;
#pragma unroll
        for (int j = 0; j < 4; j++) {
            int p = p0 + j;
            if (p < 169) op[p] += acc[m][j];
        }
    }
}

// ======================= ODE MFMA mega-kernel ================================
// R13: init staging applies r2_g2 GN (from stats) + ReLU on raw conv output.

#define HP_PITCH 72
#define HP_PLANE (100 * HP_PITCH)

#define PVALID(p) ((((p) & 7) < 7) && (((p) >> 3) < 7))
#define PSLOT(p)  (((((p) >> 3) + 1) * 10) + (((p) & 8 ? 8 : (p) & 7) + 1))
#undef PSLOT
#define PSLOT(p)  (((((p) >> 3) + 1) * 10) + (((p) & 7) + 1))

#define CONV_TAP(areg, hbase)                                                   \
    {                                                                           \
        short8 a_ = *(const short8*)(hp + ((hbase) + toff) * HP_PITCH + kq);    \
        areg = __builtin_amdgcn_mfma_f32_16x16x32_bf16(a_, vb, areg, 0, 0, 0);  \
    }

#define CONV_MFMA(hpsrc, wreg)                                                  \
    a0 = (f32x4){0.f, 0.f, 0.f, 0.f}; a1 = a0; a2 = a0; a3 = a0;                \
    {                                                                           \
        const unsigned short* hp = (hpsrc);                                     \
        _Pragma("unroll")                                                       \
        for (int t9 = 0; t9 < 9; t9++) {                                        \
            const int toff = (t9 / 3) * 10 + (t9 % 3) - 11;                     \
            _Pragma("unroll")                                                   \
            for (int ks = 0; ks < 2; ks++) {                                    \
                short8 vb = wreg[t9 * 2 + ks];                                  \
                int kq = ks * 32 + kq0;                                         \
                CONV_TAP(a0, h0)                                                \
                CONV_TAP(a1, h1)                                                \
                CONV_TAP(a2, h2)                                                \
                CONV_TAP(a3, h3)                                                \
            }                                                                   \
        }                                                                       \
    }

#define CONV_MFMA_G(hpsrc, bhT)                                                 \
    a0 = (f32x4){0.f, 0.f, 0.f, 0.f}; a1 = a0; a2 = a0; a3 = a0;                \
    {                                                                           \
        const unsigned short* hp = (hpsrc);                                     \
        const short8* bh_ = (const short8*)(bhT);                               \
        _Pragma("unroll")                                                       \
        for (int t9 = 0; t9 < 9; t9++) {                                        \
            const int toff = (t9 / 3) * 10 + (t9 % 3) - 11;                     \
            _Pragma("unroll")                                                   \
            for (int ks = 0; ks < 2; ks++) {                                    \
                short8 vb = bh_[((t9 * 2 + ks) * 4 + nt) * 64 + lane];          \
                int kq = ks * 32 + kq0;                                         \
                CONV_TAP(a0, h0)                                                \
                CONV_TAP(a1, h1)                                                \
                CONV_TAP(a2, h2)                                                \
                CONV_TAP(a3, h3)                                                \
            }                                                                   \
        }                                                                       \
    }

#define GN_ACCUM(areg, mm)                                                      \
    _Pragma("unroll")                                                           \
    for (int j = 0; j < 4; j++) {                                               \
        int p_ = (mm) * 16 + q * 4 + j;                                         \
        if (PVALID(p_)) { float x_ = areg[j]; s += x_; s2 += x_ * x_; }         \
    }

#define GN_STORE(dst, areg, mm)                                                 \
    _Pragma("unroll")                                                           \
    for (int j = 0; j < 4; j++) {                                               \
        int p_ = (mm) * 16 + q * 4 + j;                                         \
        if (PVALID(p_)) {                                                       \
            float y_ = fmaxf(areg[j] * sc + sh, 0.f);                           \
            (dst)[PSLOT(p_) * HP_PITCH + co] = f2bf(y_);                        \
        }                                                                       \
    }

#define RK4_REG(areg, zm, zam, um)                                              \
    {                                                                           \
        f32x4 kv = areg + um;                                                   \
        zam = (e == 0) ? (zm + ck * kv) : (zam + ck * kv);                      \
        if (e < 3) um = zm + cu * kv;                                           \
    }

__global__ __launch_bounds__(256, 2)
void ode_mfma_k(const float* __restrict__ u7raw, const float* __restrict__ z7,
                const float* __restrict__ mean, const float* __restrict__ rstd,
                const float* __restrict__ pgw, const float* __restrict__ pgb,
                const unsigned short* __restrict__ wr2h,
                const unsigned short* __restrict__ wb1h,
                const unsigned short* __restrict__ wb2h,
                const float* __restrict__ g1w, const float* __restrict__ g1b,
                const float* __restrict__ g2w, const float* __restrict__ g2b,
                const float* __restrict__ fgw, const float* __restrict__ fgb,
                const float* __restrict__ fcw, const float* __restrict__ fcb,
                float* __restrict__ out) {
    __shared__ unsigned short hp1[HP_PLANE], hp2[HP_PLANE];
    __shared__ float pooled[64];

    const int t = threadIdx.x;
    const int n = blockIdx.x;
    const int lane = t & 63;
    const int nt = t >> 6;
    const int colL = lane & 15, q = lane >> 4;
    const int co = nt * 16 + colL;

    const float g1wv = g1w[co], g1bv = g1b[co];
    const float g2wv = g2w[co], g2bv = g2b[co];

    const int h0 = PSLOT(colL);
    const int h1 = PSLOT(16 + colL);
    const int h2 = PSLOT(32 + colL);
    const int h3 = PSLOT(48 + colL);
    const int kq0 = q * 8;

    short8 w1r[18], w2r[18];
#pragma unroll
    for (int i = 0; i < 18; i++) {
        int fidx = (i * 4 + nt) * 64 + lane;
        w1r[i] = ((const short8*)wb1h)[fidx];
        w2r[i] = ((const short8*)wb2h)[fidx];
    }

    for (int i = t; i < HP_PLANE; i += 256) { hp1[i] = 0; hp2[i] = 0; }
    __syncthreads();

    // ---- stage raw U7 with fused r2_g2 GN + ReLU -> hp1 bf16 ----
    {
        const float* up = u7raw + (size_t)n * 3136;
        for (int i = t; i < 3136; i += 256) {
            int ch = i / 49, r = i - ch * 49;
            int y = r / 7, x = r - y * 7;
            float m = mean[n * 32 + (ch >> 1)], rs = rstd[n * 32 + (ch >> 1)];
            float v = fmaxf((up[i] - m) * rs * pgw[ch] + pgb[ch], 0.f);
            hp1[((y + 1) * 10 + (x + 1)) * HP_PITCH + ch] = f2bf(v);
        }
    }
    __syncthreads();

    // ---- folded r2_c2 conv + Z7 skip -> register state ----
    f32x4 zr0, zr1, zr2, zr3;
    f32x4 za0, za1, za2, za3;
    f32x4 ur0, ur1, ur2, ur3;
    {
        f32x4 a0, a1, a2, a3;
        CONV_MFMA_G(hp1, wr2h)
        const float* zb = z7 + (size_t)n * 3136 + (size_t)co * 49;
#define INITZ(zm, areg, mm)                                                     \
        _Pragma("unroll")                                                       \
        for (int j = 0; j < 4; j++) {                                           \
            int p_ = (mm) * 16 + q * 4 + j;                                     \
            zm[j] = PVALID(p_) ? (areg[j] + zb[(p_ >> 3) * 7 + (p_ & 7)]) : 0.f;\
        }
        INITZ(zr0, a0, 0) INITZ(zr1, a1, 1) INITZ(zr2, a2, 2) INITZ(zr3, a3, 3)
#undef INITZ
    }
    ur0 = zr0; ur1 = zr1; ur2 = zr2; ur3 = zr3;
    __syncthreads();

    const float dt = 0.5f;

#pragma unroll 1
    for (int step = 0; step < 12; step++) {
#pragma unroll 1
        for (int e = 0; e < 4; e++) {
            const float ck = (e == 0 || e == 3) ? dt / 6.f : dt / 3.f;
            const float cu = (e == 2) ? dt : 0.5f * dt;

            {
                float s = 0.f, s2 = 0.f;
                GN_ACCUM(ur0, 0) GN_ACCUM(ur1, 1) GN_ACCUM(ur2, 2) GN_ACCUM(ur3, 3)
                s += __shfl_xor(s, 16); s2 += __shfl_xor(s2, 16);
                s += __shfl_xor(s, 32); s2 += __shfl_xor(s2, 32);
                float mu = s * (1.f / 49.f);
                float r = rsqrtf(s2 * (1.f / 49.f) - mu * mu + 1e-5f);
                float sc = r * g1wv, sh = g1bv - mu * sc;
                GN_STORE(hp1, ur0, 0) GN_STORE(hp1, ur1, 1)
                GN_STORE(hp1, ur2, 2) GN_STORE(hp1, ur3, 3)
            }
            __syncthreads();   // B1

            {
                f32x4 a0, a1, a2, a3;
                CONV_MFMA(hp1, w1r)

                float s = 0.f, s2 = 0.f;
                GN_ACCUM(a0, 0) GN_ACCUM(a1, 1) GN_ACCUM(a2, 2) GN_ACCUM(a3, 3)
                s += __shfl_xor(s, 16); s2 += __shfl_xor(s2, 16);
                s += __shfl_xor(s, 32); s2 += __shfl_xor(s2, 32);
                float mu = s * (1.f / 49.f);
                float r = rsqrtf(s2 * (1.f / 49.f) - mu * mu + 1e-5f);
                float sc = r * g2wv, sh = g2bv - mu * sc;
                GN_STORE(hp2, a0, 0) GN_STORE(hp2, a1, 1)
                GN_STORE(hp2, a2, 2) GN_STORE(hp2, a3, 3)
            }
            __syncthreads();   // B2

            {
                f32x4 a0, a1, a2, a3;
                CONV_MFMA(hp2, w2r)

                RK4_REG(a0, zr0, za0, ur0) RK4_REG(a1, zr1, za1, ur1)
                RK4_REG(a2, zr2, za2, ur2) RK4_REG(a3, zr3, za3, ur3)
                if (e == 3) {
                    zr0 = za0; zr1 = za1; zr2 = za2; zr3 = za3;
                    ur0 = zr0; ur1 = zr1; ur2 = zr2; ur3 = zr3;
                }
            }
        }
    }

    // ---- final GN(groups=32)+ReLU + mean-pool ----
    {
        float s = 0.f, s2 = 0.f;
        GN_ACCUM(zr0, 0) GN_ACCUM(zr1, 1) GN_ACCUM(zr2, 2) GN_ACCUM(zr3, 3)
        s += __shfl_xor(s, 16); s2 += __shfl_xor(s2, 16);
        s += __shfl_xor(s, 32); s2 += __shfl_xor(s2, 32);
        s += __shfl_xor(s, 1);  s2 += __shfl_xor(s2, 1);
        float mu = s * (1.f / 98.f);
        float r = rsqrtf(s2 * (1.f / 98.f) - mu * mu + 1e-5f);
        float sc = r * fgw[co], sh = fgb[co] - mu * sc;
        float ps = 0.f;
#pragma unroll
        for (int mm = 0; mm < 4; mm++) {
            f32x4 zz = (mm == 0) ? zr0 : (mm == 1) ? zr1 : (mm == 2) ? zr2 : zr3;
#pragma unroll
            for (int j = 0; j < 4; j++) {
                int p_ = mm * 16 + q * 4 + j;
                if (PVALID(p_)) ps += fmaxf(zz[j] * sc + sh, 0.f);
            }
        }
        ps += __shfl_xor(ps, 16);
        ps += __shfl_xor(ps, 32);
        if (q == 0) pooled[co] = ps * (1.f / 49.f);
    }
    __syncthreads();
    if (t < 10) {
        float a = fcb[t];
#pragma unroll
        for (int k = 0; k < 64; k++) a += pooled[k] * fcw[t * 64 + k];
        out[(size_t)n * 10 + t] = a;
    }
}

static inline int nblk(long long total) { return (int)((total + TPB - 1) / TPB); }

extern "C" void kernel_launch(void* const* d_in, const int* in_sizes, int n_in,
                              void* d_out, int out_size, void* d_ws, size_t ws_size,
                              hipStream_t stream) {
    const float* x       = (const float*)d_in[0];
    const float* conv1_w = (const float*)d_in[1];
    const float* conv1_b = (const float*)d_in[2];
    const float* r1_g1w  = (const float*)d_in[3];
    const float* r1_g1b  = (const float*)d_in[4];
    const float* r1_c1w  = (const float*)d_in[5];
    const float* r1_g2w  = (const float*)d_in[6];
    const float* r1_g2b  = (const float*)d_in[7];
    const float* r1_c2w  = (const float*)d_in[8];
    const float* r1_dw   = (const float*)d_in[9];
    const float* r2_g1w  = (const float*)d_in[10];
    const float* r2_g1b  = (const float*)d_in[11];
    const float* r2_c1w  = (const float*)d_in[12];
    const float* r2_g2w  = (const float*)d_in[13];
    const float* r2_g2b  = (const float*)d_in[14];
    const float* r2_c2w  = (const float*)d_in[15];
    const float* r2_dw   = (const float*)d_in[16];
    const float* o_g1w   = (const float*)d_in[17];
    const float* o_g1b   = (const float*)d_in[18];
    const float* o_c1w   = (const float*)d_in[19];
    const float* o_g2w   = (const float*)d_in[20];
    const float* o_g2b   = (const float*)d_in[21];
    const float* o_c2w   = (const float*)d_in[22];
    const float* fin_gw  = (const float*)d_in[23];
    const float* fin_gb  = (const float*)d_in[24];
    const float* fc_w    = (const float*)d_in[25];
    const float* fc_b    = (const float*)d_in[26];
    float* out = (float*)d_out;

    const int N = 512;
    const long long SZ26 = 512LL * 64 * 26 * 26;
    const long long SZ13 = 512LL * 64 * 13 * 13;
    const long long SZ7  = 512LL * 64 * 7 * 7;
    const long long WTS  = 64 * 64 * 12;
    const long long WBS  = 9 * 2 * 4 * 64 * 8;

    float* B26   = (float*)d_ws;
    float* A13   = B26 + SZ26;
    float* B13   = A13 + SZ13;
    float* Z7    = B13 + SZ13;
    float* U7    = Z7 + SZ7;
    float* MEAN  = U7 + SZ7;
    float* RSTD  = MEAN + 512 * 32;
    float* WTr11 = RSTD + 512 * 32;
    float* WTr21 = WTr11 + WTS;
    unsigned short* WB1h  = (unsigned short*)(WTr21 + WTS);
    unsigned short* WB2h  = WB1h + WBS;
    unsigned short* WB13h = WB2h + WBS;
    unsigned short* WR2h  = WB13h + WBS;

    // ---- weight prep ----
    wprep_k<<<nblk(WTS), TPB, 0, stream>>>(r1_c1w, WTr11);
    wprep_k<<<nblk(WTS), TPB, 0, stream>>>(r2_c1w, WTr21);
    wsplit_k<<<nblk(WBS), TPB, 0, stream>>>(o_c1w, WB1h);
    wsplit_k<<<nblk(WBS), TPB, 0, stream>>>(o_c2w, WB2h);
    wsplit_k<<<nblk(WBS), TPB, 0, stream>>>(r1_c2w, WB13h);
    wsplit_k<<<nblk(WBS), TPB, 0, stream>>>(r2_c2w, WR2h);

    // ---- stage 0: conv1 ----
    conv1_k<<<nblk(SZ26), TPB, 0, stream>>>(x, conv1_w, conv1_b, B26);

    // ---- residual block 1: 26x26 -> 13x13 (GN applied in staging) ----
    gn_stats_k<<<nblk(512LL * 32 * 64), TPB, 0, stream>>>(B26, MEAN, RSTD, N, 64, 676, 32);
    conv_tile_k<2, true><<<512 * 4, 256, 0, stream>>>(B26, WTr11, r1_dw, nullptr,
                                                      A13, B13, MEAN, RSTD, r1_g1w, r1_g1b,
                                                      26, 26, 13, 13, 2, 2);
    gn_stats_k<<<nblk(512LL * 32 * 64), TPB, 0, stream>>>(A13, MEAN, RSTD, N, 64, 169, 32);
    conv13_mfma_k<<<512, 256, 0, stream>>>(A13, WB13h, B13, MEAN, RSTD, r1_g2w, r1_g2b);

    // ---- residual block 2: 13x13 -> 7x7 ----
    gn_stats_k<<<nblk(512LL * 32 * 64), TPB, 0, stream>>>(B13, MEAN, RSTD, N, 64, 169, 32);
    conv_tile_k<2, true><<<512, 256, 0, stream>>>(B13, WTr21, r2_dw, nullptr,
                                                  U7, Z7, MEAN, RSTD, r2_g1w, r2_g1b,
                                                  13, 13, 7, 7, 1, 1);
    gn_stats_k<<<nblk(512LL * 32 * 64), TPB, 0, stream>>>(U7, MEAN, RSTD, N, 64, 49, 32);

    // ---- fused: GN + r2_c2 conv + skip + ODE RK4 + final GN + pool + FC ----
    ode_mfma_k<<<512, 256, 0, stream>>>(U7, Z7, MEAN, RSTD, r2_g2w, r2_g2b,
                                        WR2h, WB1h, WB2h,
                                        o_g1w, o_g1b, o_g2w, o_g2b,
                                        fin_gw, fin_gb, fc_w, fc_b, out);
}

// Round 14
// 632.561 us; speedup vs baseline: 3.5876x; 1.3786x over previous
//
#include <hip/hip_runtime.h>
#include <hip/hip_bf16.h>

#define TPB 256

typedef __attribute__((ext_vector_type(8))) short short8;
typedef __attribute__((ext_vector_type(4))) float f32x4;

__device__ __forceinline__ unsigned short f2bf(float x) {
    union { float f; unsigned int u; } c; c.f = x;
    unsigned int u = c.u;
    unsigned int r = (u + 0x7fffu + ((u >> 16) & 1u)) >> 16;
    return (unsigned short)r;
}

// ======================= small prologue kernels ==============================

__global__ void conv1_k(const float* __restrict__ x, const float* __restrict__ w,
                        const float* __restrict__ b, float* __restrict__ out) {
    int idx = blockIdx.x * TPB + threadIdx.x;
    const int total = 512 * 64 * 26 * 26;
    if (idx >= total) return;
    int ox = idx % 26; int t = idx / 26;
    int oy = t % 26;   t /= 26;
    int co = t % 64;   int n = t / 64;
    const float* xp = x + (size_t)n * 784 + oy * 28 + ox;
    const float* wp = w + co * 9;
    float s = b[co];
#pragma unroll
    for (int ky = 0; ky < 3; ky++)
#pragma unroll
        for (int kx = 0; kx < 3; kx++)
            s += xp[ky * 28 + kx] * wp[ky * 3 + kx];
    out[idx] = s;
}

__global__ void gn_stats_k(const float* __restrict__ x, float* __restrict__ mean,
                           float* __restrict__ rstd, int N, int C, int HW, int G) {
    int gid  = (blockIdx.x * blockDim.x + threadIdx.x) >> 6;
    int lane = threadIdx.x & 63;
    int total = N * G;
    if (gid >= total) return;
    int n = gid / G, g = gid % G;
    int cpg = C / G;
    int gsize = cpg * HW;
    const float* p = x + ((size_t)n * C + (size_t)g * cpg) * HW;
    float s = 0.f, s2 = 0.f;
    for (int i = lane; i < gsize; i += 64) { float v = p[i]; s += v; s2 += v * v; }
#pragma unroll
    for (int off = 32; off; off >>= 1) {
        s  += __shfl_down(s,  off);
        s2 += __shfl_down(s2, off);
    }
    if (lane == 0) {
        float m = s / gsize;
        float var = s2 / gsize - m * m;
        mean[gid] = m;
        rstd[gid] = rsqrtf(var + 1e-5f);
    }
}

// 3x3 bf16 B-frag table: [t:9][ks:2][nt:4][lane:64][8]
// lane holds B[k=ks*32+(l>>4)*8+j][co=nt*16+(l&15)]
__global__ void wsplit_k(const float* __restrict__ w, unsigned short* __restrict__ hiT) {
    int i = blockIdx.x * TPB + threadIdx.x;
    if (i >= 9 * 2 * 4 * 64 * 8) return;
    int j = i & 7, l = (i >> 3) & 63, nt = (i >> 9) & 3, ks = (i >> 11) & 1, t = i >> 12;
    int co = nt * 16 + (l & 15);
    int ci = ks * 32 + (l >> 4) * 8 + j;
    hiT[i] = f2bf(w[(co * 64 + ci) * 9 + t]);
}

// 1x1 bf16 B-frag table: [ks:2][nt:4][lane:64][8]
__global__ void wsplit1_k(const float* __restrict__ w, unsigned short* __restrict__ hiT) {
    int i = blockIdx.x * TPB + threadIdx.x;
    if (i >= 2 * 4 * 64 * 8) return;
    int j = i & 7, l = (i >> 3) & 63, nt = (i >> 9) & 3, ks = (i >> 11) & 1;
    int co = nt * 16 + (l & 15);
    int ci = ks * 32 + (l >> 4) * 8 + j;
    hiT[i] = f2bf(w[co * 64 + ci]);
}

// ======================= stride-2 MFMA conv (+fused GN, +1x1 skip) ===========
// Block = (image, output 7x7 tile). Input staged column-PHASE-SPLIT so each
// 3x3 tap (and the 1x1 skip tap) is a constant slot offset and the wave's 16
// lanes read consecutive slots (2 lanes/bank-quad = free):
//   row r = iy-(2*oy0-1) in [0,15); even-ix cols at slots 0..7 (ix=2ox0+2c),
//   odd-ix at 8..15 (ix=2ox0-1+2(c-8)). Pixel base slot = (2oy)*16+ox.
//   Tap (ky,kx): +ky*16 + {8,0,9}[kx].  Skip (1x1,s2): +16.
// GN (G=32, from stats) + ReLU fused into staging. Weights bf16 in registers.

__global__ __launch_bounds__(256, 2)
void conv_s2_mfma_k(const float* __restrict__ in,
                    const unsigned short* __restrict__ bhT,
                    const unsigned short* __restrict__ dwT,
                    float* __restrict__ out, float* __restrict__ skipout,
                    const float* __restrict__ mean, const float* __restrict__ rstd,
                    const float* __restrict__ gnw, const float* __restrict__ gnb,
                    int H, int W, int OH, int OW, int TX, int TY) {
    __shared__ unsigned short hp[256 * 72];

    int b = blockIdx.x;
    int tx = b % TX; b /= TX;
    int ty = b % TY; int n = b / TY;
    int oy0 = ty * 7, ox0 = tx * 7;

    const int t = threadIdx.x;
    const int lane = t & 63, nt = t >> 6;
    const int colL = lane & 15, q = lane >> 4;
    const int co = nt * 16 + colL;
    const int kq0 = q * 8;

    // weights in registers
    short8 wr[18], dr[2];
#pragma unroll
    for (int i = 0; i < 18; i++) wr[i] = ((const short8*)bhT)[(i * 4 + nt) * 64 + lane];
    dr[0] = ((const short8*)dwT)[(0 * 4 + nt) * 64 + lane];
    dr[1] = ((const short8*)dwT)[(1 * 4 + nt) * 64 + lane];

    for (int i = t; i < 256 * 72 / 2; i += 256) ((unsigned int*)hp)[i] = 0u;
    __syncthreads();

    // ---- stage 15x16 phase-split tile with fused GN+ReLU ----
    const float* ip = in + (size_t)n * 64 * H * W;
    for (int i = t; i < 64 * 240; i += 256) {
        int ch = i / 240; int rc = i - ch * 240;
        int r = rc >> 4, c = rc & 15;
        int iy = 2 * oy0 - 1 + r;
        int ix = (c < 8) ? (2 * ox0 + 2 * c) : (2 * ox0 - 1 + 2 * (c - 8));
        if ((unsigned)iy < (unsigned)H && (unsigned)ix < (unsigned)W) {
            float m = mean[n * 32 + (ch >> 1)], rs = rstd[n * 32 + (ch >> 1)];
            float raw = ip[(size_t)ch * H * W + iy * W + ix];
            float v = fmaxf((raw - m) * rs * gnw[ch] + gnb[ch], 0.f);
            hp[(r * 16 + c) * 72 + ch] = f2bf(v);
        }
    }
    __syncthreads();

    // per-m base slots (invalid pixels -> slot 0; results masked at write)
    int bs0, bs1, bs2, bs3;
    {
#define BSLOT(dst, mm)                                                          \
        {                                                                       \
            int p_ = (mm) * 16 + colL;                                          \
            int oy_ = p_ >> 3, ox_ = p_ & 7;                                    \
            dst = (ox_ < 7 && oy_ < 7) ? ((2 * oy_) * 16 + ox_) : 0;            \
        }
        BSLOT(bs0, 0) BSLOT(bs1, 1) BSLOT(bs2, 2) BSLOT(bs3, 3)
#undef BSLOT
    }

    f32x4 a0, a1, a2, a3, k0, k1, k2, k3;
    a0 = (f32x4){0.f, 0.f, 0.f, 0.f}; a1 = a0; a2 = a0; a3 = a0;
    k0 = a0; k1 = a0; k2 = a0; k3 = a0;

#pragma unroll
    for (int t9 = 0; t9 < 9; t9++) {
        const int kx = t9 % 3;
        const int toff = (t9 / 3) * 16 + (kx == 0 ? 8 : (kx == 1 ? 0 : 9));
#pragma unroll
        for (int ks = 0; ks < 2; ks++) {
            short8 vb = wr[t9 * 2 + ks];
            int kq = ks * 32 + kq0;
#define TAP(areg, bs)                                                           \
            {                                                                   \
                short8 av = *(const short8*)(hp + ((bs) + toff) * 72 + kq);     \
                areg = __builtin_amdgcn_mfma_f32_16x16x32_bf16(av, vb, areg, 0, 0, 0); \
            }
            TAP(a0, bs0) TAP(a1, bs1) TAP(a2, bs2) TAP(a3, bs3)
#undef TAP
        }
    }
    // ---- 1x1 stride-2 skip: single tap at bslot+16 ----
#pragma unroll
    for (int ks = 0; ks < 2; ks++) {
        short8 vb = dr[ks];
        int kq = ks * 32 + kq0;
#define TAP(areg, bs)                                                           \
        {                                                                       \
            short8 av = *(const short8*)(hp + ((bs) + 16) * 72 + kq);           \
            areg = __builtin_amdgcn_mfma_f32_16x16x32_bf16(av, vb, areg, 0, 0, 0); \
        }
        TAP(k0, bs0) TAP(k1, bs1) TAP(k2, bs2) TAP(k3, bs3)
#undef TAP
    }

    // ---- write (mask invalid + tile-boundary pixels) ----
#define WB(areg, kreg, mm)                                                      \
    _Pragma("unroll")                                                           \
    for (int j = 0; j < 4; j++) {                                               \
        int p_ = (mm) * 16 + q * 4 + j;                                         \
        int oy_ = p_ >> 3, ox_ = p_ & 7;                                        \
        if (ox_ < 7 && oy_ < 7 && oy0 + oy_ < OH && ox0 + ox_ < OW) {           \
            size_t idx = (((size_t)n * 64 + co) * OH + oy0 + oy_) * OW + ox0 + ox_; \
            out[idx] = areg[j];                                                 \
            skipout[idx] = kreg[j];                                             \
        }                                                                       \
    }
    WB(a0, k0, 0) WB(a1, k1, 1) WB(a2, k2, 2) WB(a3, k3, 3)
#undef WB
}

// ======================= 13x13 MFMA conv (r1_c2, GN fused) ===================

__global__ __launch_bounds__(256, 2)
void conv13_mfma_k(const float* __restrict__ in, const unsigned short* __restrict__ bhT,
                   float* __restrict__ io,
                   const float* __restrict__ mean, const float* __restrict__ rstd,
                   const float* __restrict__ gnw, const float* __restrict__ gnb) {
    __shared__ unsigned short hp[256 * 72];
    const int t = threadIdx.x;
    const int n = blockIdx.x;
    const int lane = t & 63;
    const int nt = t >> 6;
    const int colL = lane & 15, q = lane >> 4;
    const int co = nt * 16 + colL;
    const int kq0 = q * 8;

    short8 wr[18];
#pragma unroll
    for (int i = 0; i < 18; i++) wr[i] = ((const short8*)bhT)[(i * 4 + nt) * 64 + lane];

    for (int i = t; i < 256 * 72 / 2; i += 256) ((unsigned int*)hp)[i] = 0u;
    __syncthreads();
    const float* ip = in + (size_t)n * 64 * 169;
    for (int i = t; i < 64 * 169; i += 256) {
        int ch = i / 169, p = i - ch * 169;
        int y = p / 13, x = p - y * 13;
        float m = mean[n * 32 + (ch >> 1)], rs = rstd[n * 32 + (ch >> 1)];
        float v = fmaxf((ip[i] - m) * rs * gnw[ch] + gnb[ch], 0.f);
        hp[((y + 1) * 16 + (x + 1)) * 72 + ch] = f2bf(v);
    }
    __syncthreads();

    int hb[11];
#pragma unroll
    for (int m = 0; m < 11; m++) {
        int p = m * 16 + colL;
        int y = p / 13, x = p - y * 13;
        hb[m] = (y + 1) * 16 + (x + 1);
    }
    f32x4 acc[11];
#pragma unroll
    for (int m = 0; m < 11; m++) acc[m] = (f32x4){0.f, 0.f, 0.f, 0.f};

#pragma unroll
    for (int t9 = 0; t9 < 9; t9++) {
        const int toff = (t9 / 3) * 16 + (t9 % 3) - 17;
#pragma unroll
        for (int ks = 0; ks < 2; ks++) {
            short8 vb = wr[t9 * 2 + ks];
            int kq = ks * 32 + kq0;
#pragma unroll
            for (int m = 0; m < 11; m++) {
                short8 a_ = *(const short8*)(hp + (hb[m] + toff) * 72 + kq);
                acc[m] = __builtin_amdgcn_mfma_f32_16x16x32_bf16(a_, vb, acc[m], 0, 0, 0);
            }
        }
    }

    float* op = io + (size_t)n * 64 * 169 + (size_t)co * 169;
#pragma unroll
    for (int m = 0; m < 11; m++) {
        int p0 = m * 16 + q * 4;
#pragma unroll
        for (int j = 0; j < 4; j++) {
            int p = p0 + j;
            if (p < 169) op[p] += acc[m][j];
        }
    }
}

// ======================= ODE MFMA mega-kernel ================================

#define HP_PITCH 72
#define HP_PLANE (100 * HP_PITCH)

#define PVALID(p) ((((p) & 7) < 7) && (((p) >> 3) < 7))
#define PSLOT(p)  (((((p) >> 3) + 1) * 10) + (((p) & 7) + 1))

#define CONV_TAP(areg, hbase)                                                   \
    {                                                                           \
        short8 a_ = *(const short8*)(hp + ((hbase) + toff) * HP_PITCH + kq);    \
        areg = __builtin_amdgcn_mfma_f32_16x16x32_bf16(a_, vb, areg, 0, 0, 0);  \
    }

#define CONV_MFMA(hpsrc, wreg)                                                  \
    a0 = (f32x4){0.f, 0.f, 0.f, 0.f}; a1 = a0; a2 = a0; a3 = a0;                \
    {                                                                           \
        const unsigned short* hp = (hpsrc);                                     \
        _Pragma("unroll")                                                       \
        for (int t9 = 0; t9 < 9; t9++) {                                        \
            const int toff = (t9 / 3) * 10 + (t9 % 3) - 11;                     \
            _Pragma("unroll")                                                   \
            for (int ks = 0; ks < 2; ks++) {                                    \
                short8 vb = wreg[t9 * 2 + ks];                                  \
                int kq = ks * 32 + kq0;                                         \
                CONV_TAP(a0, h0)                                                \
                CONV_TAP(a1, h1)                                                \
                CONV_TAP(a2, h2)                                                \
                CONV_TAP(a3, h3)                                                \
            }                                                                   \
        }                                                                       \
    }

#define CONV_MFMA_G(hpsrc, bhT)                                                 \
    a0 = (f32x4){0.f, 0.f, 0.f, 0.f}; a1 = a0; a2 = a0; a3 = a0;                \
    {                                                                           \
        const unsigned short* hp = (hpsrc);                                     \
        const short8* bh_ = (const short8*)(bhT);                               \
        _Pragma("unroll")                                                       \
        for (int t9 = 0; t9 < 9; t9++) {                                        \
            const int toff = (t9 / 3) * 10 + (t9 % 3) - 11;                     \
            _Pragma("unroll")                                                   \
            for (int ks = 0; ks < 2; ks++) {                                    \
                short8 vb = bh_[((t9 * 2 + ks) * 4 + nt) * 64 + lane];          \
                int kq = ks * 32 + kq0;                                         \
                CONV_TAP(a0, h0)                                                \
                CONV_TAP(a1, h1)                                                \
                CONV_TAP(a2, h2)                                                \
                CONV_TAP(a3, h3)                                                \
            }                                                                   \
        }                                                                       \
    }

#define GN_ACCUM(areg, mm)                                                      \
    _Pragma("unroll")                                                           \
    for (int j = 0; j < 4; j++) {                                               \
        int p_ = (mm) * 16 + q * 4 + j;                                         \
        if (PVALID(p_)) { float x_ = areg[j]; s += x_; s2 += x_ * x_; }         \
    }

#define GN_STORE(dst, areg, mm)                                                 \
    _Pragma("unroll")                                                           \
    for (int j = 0; j < 4; j++) {                                               \
        int p_ = (mm) * 16 + q * 4 + j;                                         \
        if (PVALID(p_)) {                                                       \
            float y_ = fmaxf(areg[j] * sc + sh, 0.f);                           \
            (dst)[PSLOT(p_) * HP_PITCH + co] = f2bf(y_);                        \
        }                                                                       \
    }

#define RK4_REG(areg, zm, zam, um)                                              \
    {                                                                           \
        f32x4 kv = areg + um;                                                   \
        zam = (e == 0) ? (zm + ck * kv) : (zam + ck * kv);                      \
        if (e < 3) um = zm + cu * kv;                                           \
    }

__global__ __launch_bounds__(256, 2)
void ode_mfma_k(const float* __restrict__ u7raw, const float* __restrict__ z7,
                const float* __restrict__ mean, const float* __restrict__ rstd,
                const float* __restrict__ pgw, const float* __restrict__ pgb,
                const unsigned short* __restrict__ wr2h,
                const unsigned short* __restrict__ wb1h,
                const unsigned short* __restrict__ wb2h,
                const float* __restrict__ g1w, const float* __restrict__ g1b,
                const float* __restrict__ g2w, const float* __restrict__ g2b,
                const float* __restrict__ fgw, const float* __restrict__ fgb,
                const float* __restrict__ fcw, const float* __restrict__ fcb,
                float* __restrict__ out) {
    __shared__ unsigned short hp1[HP_PLANE], hp2[HP_PLANE];
    __shared__ float pooled[64];

    const int t = threadIdx.x;
    const int n = blockIdx.x;
    const int lane = t & 63;
    const int nt = t >> 6;
    const int colL = lane & 15, q = lane >> 4;
    const int co = nt * 16 + colL;

    const float g1wv = g1w[co], g1bv = g1b[co];
    const float g2wv = g2w[co], g2bv = g2b[co];

    const int h0 = PSLOT(colL);
    const int h1 = PSLOT(16 + colL);
    const int h2 = PSLOT(32 + colL);
    const int h3 = PSLOT(48 + colL);
    const int kq0 = q * 8;

    short8 w1r[18], w2r[18];
#pragma unroll
    for (int i = 0; i < 18; i++) {
        int fidx = (i * 4 + nt) * 64 + lane;
        w1r[i] = ((const short8*)wb1h)[fidx];
        w2r[i] = ((const short8*)wb2h)[fidx];
    }

    for (int i = t; i < HP_PLANE; i += 256) { hp1[i] = 0; hp2[i] = 0; }
    __syncthreads();

    // ---- stage raw U7 with fused r2_g2 GN + ReLU -> hp1 bf16 ----
    {
        const float* up = u7raw + (size_t)n * 3136;
        for (int i = t; i < 3136; i += 256) {
            int ch = i / 49, r = i - ch * 49;
            int y = r / 7, x = r - y * 7;
            float m = mean[n * 32 + (ch >> 1)], rs = rstd[n * 32 + (ch >> 1)];
            float v = fmaxf((up[i] - m) * rs * pgw[ch] + pgb[ch], 0.f);
            hp1[((y + 1) * 10 + (x + 1)) * HP_PITCH + ch] = f2bf(v);
        }
    }
    __syncthreads();

    // ---- folded r2_c2 conv + Z7 skip -> register state ----
    f32x4 zr0, zr1, zr2, zr3;
    f32x4 za0, za1, za2, za3;
    f32x4 ur0, ur1, ur2, ur3;
    {
        f32x4 a0, a1, a2, a3;
        CONV_MFMA_G(hp1, wr2h)
        const float* zb = z7 + (size_t)n * 3136 + (size_t)co * 49;
#define INITZ(zm, areg, mm)                                                     \
        _Pragma("unroll")                                                       \
        for (int j = 0; j < 4; j++) {                                           \
            int p_ = (mm) * 16 + q * 4 + j;                                     \
            zm[j] = PVALID(p_) ? (areg[j] + zb[(p_ >> 3) * 7 + (p_ & 7)]) : 0.f;\
        }
        INITZ(zr0, a0, 0) INITZ(zr1, a1, 1) INITZ(zr2, a2, 2) INITZ(zr3, a3, 3)
#undef INITZ
    }
    ur0 = zr0; ur1 = zr1; ur2 = zr2; ur3 = zr3;
    __syncthreads();

    const float dt = 0.5f;

#pragma unroll 1
    for (int step = 0; step < 12; step++) {
#pragma unroll 1
        for (int e = 0; e < 4; e++) {
            const float ck = (e == 0 || e == 3) ? dt / 6.f : dt / 3.f;
            const float cu = (e == 2) ? dt : 0.5f * dt;

            {
                float s = 0.f, s2 = 0.f;
                GN_ACCUM(ur0, 0) GN_ACCUM(ur1, 1) GN_ACCUM(ur2, 2) GN_ACCUM(ur3, 3)
                s += __shfl_xor(s, 16); s2 += __shfl_xor(s2, 16);
                s += __shfl_xor(s, 32); s2 += __shfl_xor(s2, 32);
                float mu = s * (1.f / 49.f);
                float r = rsqrtf(s2 * (1.f / 49.f) - mu * mu + 1e-5f);
                float sc = r * g1wv, sh = g1bv - mu * sc;
                GN_STORE(hp1, ur0, 0) GN_STORE(hp1, ur1, 1)
                GN_STORE(hp1, ur2, 2) GN_STORE(hp1, ur3, 3)
            }
            __syncthreads();   // B1

            {
                f32x4 a0, a1, a2, a3;
                CONV_MFMA(hp1, w1r)

                float s = 0.f, s2 = 0.f;
                GN_ACCUM(a0, 0) GN_ACCUM(a1, 1) GN_ACCUM(a2, 2) GN_ACCUM(a3, 3)
                s += __shfl_xor(s, 16); s2 += __shfl_xor(s2, 16);
                s += __shfl_xor(s, 32); s2 += __shfl_xor(s2, 32);
                float mu = s * (1.f / 49.f);
                float r = rsqrtf(s2 * (1.f / 49.f) - mu * mu + 1e-5f);
                float sc = r * g2wv, sh = g2bv - mu * sc;
                GN_STORE(hp2, a0, 0) GN_STORE(hp2, a1, 1)
                GN_STORE(hp2, a2, 2) GN_STORE(hp2, a3, 3)
            }
            __syncthreads();   // B2

            {
                f32x4 a0, a1, a2, a3;
                CONV_MFMA(hp2, w2r)

                RK4_REG(a0, zr0, za0, ur0) RK4_REG(a1, zr1, za1, ur1)
                RK4_REG(a2, zr2, za2, ur2) RK4_REG(a3, zr3, za3, ur3)
                if (e == 3) {
                    zr0 = za0; zr1 = za1; zr2 = za2; zr3 = za3;
                    ur0 = zr0; ur1 = zr1; ur2 = zr2; ur3 = zr3;
                }
            }
        }
    }

    // ---- final GN(groups=32)+ReLU + mean-pool ----
    {
        float s = 0.f, s2 = 0.f;
        GN_ACCUM(zr0, 0) GN_ACCUM(zr1, 1) GN_ACCUM(zr2, 2) GN_ACCUM(zr3, 3)
        s += __shfl_xor(s, 16); s2 += __shfl_xor(s2, 16);
        s += __shfl_xor(s, 32); s2 += __shfl_xor(s2, 32);
        s += __shfl_xor(s, 1);  s2 += __shfl_xor(s2, 1);
        float mu = s * (1.f / 98.f);
        float r = rsqrtf(s2 * (1.f / 98.f) - mu * mu + 1e-5f);
        float sc = r * fgw[co], sh = fgb[co] - mu * sc;
        float ps = 0.f;
#pragma unroll
        for (int mm = 0; mm < 4; mm++) {
            f32x4 zz = (mm == 0) ? zr0 : (mm == 1) ? zr1 : (mm == 2) ? zr2 : zr3;
#pragma unroll
            for (int j = 0; j < 4; j++) {
                int p_ = mm * 16 + q * 4 + j;
                if (PVALID(p_)) ps += fmaxf(zz[j] * sc + sh, 0.f);
            }
        }
        ps += __shfl_xor(ps, 16);
        ps += __shfl_xor(ps, 32);
        if (q == 0) pooled[co] = ps * (1.f / 49.f);
    }
    __syncthreads();
    if (t < 10) {
        float a = fcb[t];
#pragma unroll
        for (int k = 0; k < 64; k++) a += pooled[k] * fcw[t * 64 + k];
        out[(size_t)n * 10 + t] = a;
    }
}

static inline int nblk(long long total) { return (int)((total + TPB - 1) / TPB); }

extern "C" void kernel_launch(void* const* d_in, const int* in_sizes, int n_in,
                              void* d_out, int out_size, void* d_ws, size_t ws_size,
                              hipStream_t stream) {
    const float* x       = (const float*)d_in[0];
    const float* conv1_w = (const float*)d_in[1];
    const float* conv1_b = (const float*)d_in[2];
    const float* r1_g1w  = (const float*)d_in[3];
    const float* r1_g1b  = (const float*)d_in[4];
    const float* r1_c1w  = (const float*)d_in[5];
    const float* r1_g2w  = (const float*)d_in[6];
    const float* r1_g2b  = (const float*)d_in[7];
    const float* r1_c2w  = (const float*)d_in[8];
    const float* r1_dw   = (const float*)d_in[9];
    const float* r2_g1w  = (const float*)d_in[10];
    const float* r2_g1b  = (const float*)d_in[11];
    const float* r2_c1w  = (const float*)d_in[12];
    const float* r2_g2w  = (const float*)d_in[13];
    const float* r2_g2b  = (const float*)d_in[14];
    const float* r2_c2w  = (const float*)d_in[15];
    const float* r2_dw   = (const float*)d_in[16];
    const float* o_g1w   = (const float*)d_in[17];
    const float* o_g1b   = (const float*)d_in[18];
    const float* o_c1w   = (const float*)d_in[19];
    const float* o_g2w   = (const float*)d_in[20];
    const float* o_g2b   = (const float*)d_in[21];
    const float* o_c2w   = (const float*)d_in[22];
    const float* fin_gw  = (const float*)d_in[23];
    const float* fin_gb  = (const float*)d_in[24];
    const float* fc_w    = (const float*)d_in[25];
    const float* fc_b    = (const float*)d_in[26];
    float* out = (float*)d_out;

    const int N = 512;
    const long long SZ26 = 512LL * 64 * 26 * 26;
    const long long SZ13 = 512LL * 64 * 13 * 13;
    const long long SZ7  = 512LL * 64 * 7 * 7;
    const long long WBS  = 9 * 2 * 4 * 64 * 8;
    const long long WBS1 = 2 * 4 * 64 * 8;

    float* B26   = (float*)d_ws;
    float* A13   = B26 + SZ26;
    float* B13   = A13 + SZ13;
    float* Z7    = B13 + SZ13;
    float* U7    = Z7 + SZ7;
    float* MEAN  = U7 + SZ7;
    float* RSTD  = MEAN + 512 * 32;
    unsigned short* WB1h  = (unsigned short*)(RSTD + 512 * 32);
    unsigned short* WB2h  = WB1h + WBS;
    unsigned short* WB13h = WB2h + WBS;
    unsigned short* WR2h  = WB13h + WBS;
    unsigned short* WR11h = WR2h + WBS;
    unsigned short* WR21h = WR11h + WBS;
    unsigned short* WD1h  = WR21h + WBS;
    unsigned short* WD2h  = WD1h + WBS1;

    // ---- weight prep ----
    wsplit_k<<<nblk(WBS), TPB, 0, stream>>>(o_c1w, WB1h);
    wsplit_k<<<nblk(WBS), TPB, 0, stream>>>(o_c2w, WB2h);
    wsplit_k<<<nblk(WBS), TPB, 0, stream>>>(r1_c2w, WB13h);
    wsplit_k<<<nblk(WBS), TPB, 0, stream>>>(r2_c2w, WR2h);
    wsplit_k<<<nblk(WBS), TPB, 0, stream>>>(r1_c1w, WR11h);
    wsplit_k<<<nblk(WBS), TPB, 0, stream>>>(r2_c1w, WR21h);
    wsplit1_k<<<nblk(WBS1), TPB, 0, stream>>>(r1_dw, WD1h);
    wsplit1_k<<<nblk(WBS1), TPB, 0, stream>>>(r2_dw, WD2h);

    // ---- stage 0: conv1 ----
    conv1_k<<<nblk(SZ26), TPB, 0, stream>>>(x, conv1_w, conv1_b, B26);

    // ---- residual block 1: 26x26 -> 13x13 ----
    gn_stats_k<<<nblk(512LL * 32 * 64), TPB, 0, stream>>>(B26, MEAN, RSTD, N, 64, 676, 32);
    conv_s2_mfma_k<<<512 * 4, 256, 0, stream>>>(B26, WR11h, WD1h, A13, B13,
                                                MEAN, RSTD, r1_g1w, r1_g1b,
                                                26, 26, 13, 13, 2, 2);
    gn_stats_k<<<nblk(512LL * 32 * 64), TPB, 0, stream>>>(A13, MEAN, RSTD, N, 64, 169, 32);
    conv13_mfma_k<<<512, 256, 0, stream>>>(A13, WB13h, B13, MEAN, RSTD, r1_g2w, r1_g2b);

    // ---- residual block 2: 13x13 -> 7x7 ----
    gn_stats_k<<<nblk(512LL * 32 * 64), TPB, 0, stream>>>(B13, MEAN, RSTD, N, 64, 169, 32);
    conv_s2_mfma_k<<<512, 256, 0, stream>>>(B13, WR21h, WD2h, U7, Z7,
                                            MEAN, RSTD, r2_g1w, r2_g1b,
                                            13, 13, 7, 7, 1, 1);
    gn_stats_k<<<nblk(512LL * 32 * 64), TPB, 0, stream>>>(U7, MEAN, RSTD, N, 64, 49, 32);

    // ---- fused: GN + r2_c2 conv + skip + ODE RK4 + final GN + pool + FC ----
    ode_mfma_k<<<512, 256, 0, stream>>>(U7, Z7, MEAN, RSTD, r2_g2w, r2_g2b,
                                        WR2h, WB1h, WB2h,
                                        o_g1w, o_g1b, o_g2w, o_g2b,
                                        fin_gw, fin_gb, fc_w, fc_b, out);
}